// Round 11
// baseline (314.577 us; speedup 1.0000x reference)
//
#include <hip/hip_runtime.h>
#include <hip/hip_bf16.h>
#include <string.h>

namespace {

constexpr int Bc  = 2;
constexpr int Nc  = 16384;
constexpr int Rc  = 2048;
constexpr int CAc = 128;
constexpr int CSc = 256;
constexpr int CPc = 16;
constexpr int Hc  = 4;
constexpr int WQc = 32;
constexpr int WKc = 128;
constexpr int NWc = 512;
constexpr float EPSf     = 1e-5f;
constexpr float NEG_INF  = -1e8f;
constexpr float QK_SCALE = 0.17677669529663687f;  // 1/sqrt(32)

constexpr int VT_STRIDE = 16512;          // 64 pad + 16384 + 64 pad
constexpr int VT_BATCH  = 128 * VT_STRIDE;

typedef short bf16x8 __attribute__((ext_vector_type(8)));
typedef float f32x4 __attribute__((ext_vector_type(4)));
typedef unsigned int u32x4 __attribute__((ext_vector_type(4)));

__device__ __forceinline__ float wsum(float v) {
#pragma unroll
  for (int m = 1; m < 64; m <<= 1) v += __shfl_xor(v, m, 64);
  return v;
}
__device__ __forceinline__ float sigm(float x) { return 1.0f / (1.0f + __expf(-x)); }
__device__ __forceinline__ float f4c(const float4& v, int i) {
  return i == 0 ? v.x : i == 1 ? v.y : i == 2 ? v.z : v.w;
}
__device__ __forceinline__ unsigned short bfx(float v) {
  __hip_bfloat16 h = __float2bfloat16(v);
  unsigned short u;
  memcpy(&u, &h, 2);
  return u;
}
__device__ __forceinline__ unsigned pk2(float a, float b) {
  return (unsigned)bfx(a) | ((unsigned)bfx(b) << 16);
}
__device__ __forceinline__ float ubf(unsigned us) {
  unsigned v = us << 16;
  float f;
  memcpy(&f, &v, 4);
  return f;
}
__device__ __forceinline__ bf16x8 ldfrag(const ushort* p) {
  return __builtin_bit_cast(bf16x8, *(const u32x4*)p);
}

// ---------------- K0: pack weights to bf16 W^T layouts + zero vT pads ------
__global__ void k_pack(const float* __restrict__ q_W, const float* __restrict__ kv_W,
                       const float* __restrict__ t_W1, const float* __restrict__ t_W2,
                       const float* __restrict__ t_Wo,
                       ushort* __restrict__ qWt, ushort* __restrict__ kvWt,
                       ushort* __restrict__ midWt, ushort* __restrict__ WoT,
                       ushort* __restrict__ vT) {
  const int i = blockIdx.x * 256 + threadIdx.x;
  if (i < 16384) {
    const int n = i >> 7, k = i & 127;
    qWt[i] = bfx(q_W[k * 128 + n]);
  } else if (i < 49152) {
    const int i2 = i - 16384;
    const int n = i2 >> 7, k = i2 & 127;
    kvWt[i2] = bfx(kv_W[k * 256 + n]);
  } else if (i < 114688) {
    const int i3 = i - 49152;
    const int n = i3 >> 7, k = i3 & 127;
    midWt[i3] = bfx(n < 256 ? t_W1[k * 256 + n] : t_W2[k * 256 + (n - 256)]);
  } else if (i < 147456) {
    const int i4 = i - 114688;
    const int n = i4 >> 8, k = i4 & 255;
    WoT[i4] = bfx(t_Wo[k * 128 + n]);
  } else if (i < 180224) {
    const int j = i - 147456;           // vT edge pads -> 0
    const int b = j >> 14, rem = j & 16383;
    const int d = rem >> 7, p = rem & 127;
    const int col = (p < 64) ? p : (16384 + p);
    vT[(size_t)b * VT_BATCH + (size_t)d * VT_STRIDE + col] = 0;
  }
}

// ---------------- K1a: per-res LN (two weighted variants) ----------------
__global__ void k_res_ln(const float* __restrict__ res, const float* __restrict__ a_ln_w,
                         const float* __restrict__ t_ln_w, float* __restrict__ lnA,
                         float* __restrict__ lnT) {
  const int wid = threadIdx.x >> 6, lane = threadIdx.x & 63;
  const int row = blockIdx.x * 4 + wid;  // B*R rows
  const float* r = res + (size_t)row * CSc;
  float x[4], s = 0.f, sq = 0.f;
#pragma unroll
  for (int i = 0; i < 4; ++i) { x[i] = r[lane + 64 * i]; s += x[i]; sq += x[i] * x[i]; }
  s = wsum(s); sq = wsum(sq);
  const float mn = s * (1.0f / CSc);
  const float var = sq * (1.0f / CSc) - mn * mn;
  const float rs = rsqrtf(var + EPSf);
#pragma unroll
  for (int i = 0; i < 4; ++i) {
    const int c = lane + 64 * i;
    const float y = (x[i] - mn) * rs;
    lnA[(size_t)row * CSc + c] = y * a_ln_w[c];
    lnT[(size_t)row * CSc + c] = y * t_ln_w[c];
  }
}

// ---------------- K1b: 6 res GEMMs (K=256 -> 128 cols), gates sigmoid'd ----
__global__ void k_res_gemm(const float* __restrict__ lnA, const float* __restrict__ lnT,
                           const float* __restrict__ res,
                           const float* __restrict__ a_Wg, const float* __restrict__ a_bg,
                           const float* __restrict__ a_Wb,
                           const float* __restrict__ t_Wg, const float* __restrict__ t_bg,
                           const float* __restrict__ t_Wb,
                           const float* __restrict__ sg_W, const float* __restrict__ sg_b,
                           const float* __restrict__ t_Wc, const float* __restrict__ t_bc,
                           float* __restrict__ Ag, float* __restrict__ Ab,
                           float* __restrict__ Tg, float* __restrict__ Tb,
                           float* __restrict__ Sg, float* __restrict__ Tc) {
  __shared__ float tile[32 * CSc];
  const int m = blockIdx.y;
  const float* in = (m < 2) ? lnA : (m < 4) ? lnT : res;
  const float* W  = (m == 0) ? a_Wg : (m == 1) ? a_Wb : (m == 2) ? t_Wg
                  : (m == 3) ? t_Wb : (m == 4) ? sg_W : t_Wc;
  const float* bias = (m == 0) ? a_bg : (m == 2) ? t_bg : (m == 4) ? sg_b
                    : (m == 5) ? t_bc : nullptr;
  const bool sig = (m == 0) || (m == 2) || (m == 4) || (m == 5);
  float* out = (m == 0) ? Ag : (m == 1) ? Ab : (m == 2) ? Tg
             : (m == 3) ? Tb : (m == 4) ? Sg : Tc;
  const int row0 = blockIdx.x * 32;
  const float4* src = (const float4*)(in + (size_t)row0 * CSc);
  float4* dst = (float4*)tile;
#pragma unroll
  for (int k = 0; k < 8; ++k) dst[threadIdx.x + 256 * k] = src[threadIdx.x + 256 * k];
  __syncthreads();
  const int c0 = (threadIdx.x & 31) * 4;
  const int r0 = (threadIdx.x >> 5) * 4;
  float acc[4][4] = {};
  for (int j = 0; j < CSc; j += 4) {
    float4 a[4];
#pragma unroll
    for (int r = 0; r < 4; ++r) a[r] = *(const float4*)&tile[(r0 + r) * CSc + j];
#pragma unroll
    for (int jj = 0; jj < 4; ++jj) {
      const float4 w = *(const float4*)&W[(size_t)(j + jj) * CAc + c0];
#pragma unroll
      for (int r = 0; r < 4; ++r) {
        const float av = f4c(a[r], jj);
        acc[r][0] += av * w.x; acc[r][1] += av * w.y;
        acc[r][2] += av * w.z; acc[r][3] += av * w.w;
      }
    }
  }
  float4 bv = make_float4(0.f, 0.f, 0.f, 0.f);
  if (bias) bv = *(const float4*)&bias[c0];
#pragma unroll
  for (int r = 0; r < 4; ++r) {
    float4 o;
    o.x = acc[r][0] + bv.x; o.y = acc[r][1] + bv.y;
    o.z = acc[r][2] + bv.z; o.w = acc[r][3] + bv.w;
    if (sig) { o.x = sigm(o.x); o.y = sigm(o.y); o.z = sigm(o.z); o.w = sigm(o.w); }
    *(float4*)&out[(size_t)(row0 + r0 + r) * CAc + c0] = o;
  }
}

// ---------------- K2/K5: adaLN over atoms -> bf16 out ----------------------
__global__ void k_adaln16(const float* __restrict__ in, const int* __restrict__ idxG,
                          const float* __restrict__ G, const float* __restrict__ Bb,
                          unsigned* __restrict__ out32) {
  const int wid = threadIdx.x >> 6, lane = threadIdx.x & 63;
  const int row = blockIdx.x * 4 + wid;  // B*N rows
  const int b = row >> 14;
  const float* r = in + (size_t)row * CAc;
  const float2 xp = *(const float2*)&r[2 * lane];
  const float s = wsum(xp.x + xp.y);
  const float sq = wsum(xp.x * xp.x + xp.y * xp.y);
  const float mn = s * (1.0f / CAc);
  const float var = sq * (1.0f / CAc) - mn * mn;
  const float rs = rsqrtf(var + EPSf);
  const int base = (b * Rc + idxG[row]) * CAc;
  const float2 g2 = *(const float2*)&G[base + 2 * lane];
  const float2 b2 = *(const float2*)&Bb[base + 2 * lane];
  const float y0 = (xp.x - mn) * rs * g2.x + b2.x;
  const float y1 = (xp.y - mn) * rs * g2.y + b2.y;
  out32[(size_t)row * 64 + lane] = pk2(y0, y1);
}

// ---------------- K3: qkv GEMM via MFMA (M=32768, K=128) -------------------
// blockIdx.y: 0 -> q16, 1 -> K -> k16[m][128], 2 -> V -> vT via LDS transpose
__global__ __launch_bounds__(256) void k_gemm_qkv(
    const ushort* __restrict__ act16, const ushort* __restrict__ qWt,
    const ushort* __restrict__ kvWt, const float* __restrict__ q_b,
    ushort* __restrict__ q16, ushort* __restrict__ k16, ushort* __restrict__ vT) {
  __shared__ ushort vtile[128][72];  // 18.4 KB; stride 144B keeps b128 aligned
  const int ny = blockIdx.y;
  const int wid = threadIdx.x >> 6, lane = threadIdx.x & 63;
  const int c = lane & 15, s = lane >> 4;
  const int wm = wid & 1, wn = wid >> 1;
  const int base = blockIdx.x * 64;
  const int m0 = base + wm * 32;
  const int nb = wn * 64;
  const ushort* Wt = (ny == 0) ? qWt : kvWt + (ny == 2 ? 128 * 128 : 0);
  f32x4 acc[4][2];
#pragma unroll
  for (int nt = 0; nt < 4; ++nt)
#pragma unroll
    for (int mt = 0; mt < 2; ++mt) { acc[nt][mt][0]=0.f; acc[nt][mt][1]=0.f; acc[nt][mt][2]=0.f; acc[nt][mt][3]=0.f; }
#pragma unroll
  for (int kk = 0; kk < 4; ++kk) {
    const int k0 = kk * 32 + 8 * s;
    bf16x8 bA[2];
#pragma unroll
    for (int mt = 0; mt < 2; ++mt)
      bA[mt] = ldfrag(&act16[(size_t)(m0 + mt * 16 + c) * 128 + k0]);
#pragma unroll
    for (int nt = 0; nt < 4; ++nt) {
      const bf16x8 aW = ldfrag(&Wt[(size_t)(nb + nt * 16 + c) * 128 + k0]);
#pragma unroll
      for (int mt = 0; mt < 2; ++mt)
        acc[nt][mt] = __builtin_amdgcn_mfma_f32_16x16x32_bf16(aW, bA[mt], acc[nt][mt], 0, 0, 0);
    }
  }
#pragma unroll
  for (int nt = 0; nt < 4; ++nt) {
    const int colb = nb + nt * 16 + 4 * s;
    float4 qb4 = make_float4(0.f, 0.f, 0.f, 0.f);
    if (ny == 0) qb4 = *(const float4*)&q_b[colb];
#pragma unroll
    for (int mt = 0; mt < 2; ++mt) {
      const int m = m0 + mt * 16 + c;
      const f32x4 a = acc[nt][mt];
      if (ny == 0) {
        ushort4 u4;
        u4.x = bfx((a[0] + qb4.x) * QK_SCALE); u4.y = bfx((a[1] + qb4.y) * QK_SCALE);
        u4.z = bfx((a[2] + qb4.z) * QK_SCALE); u4.w = bfx((a[3] + qb4.w) * QK_SCALE);
        *(ushort4*)&q16[(size_t)m * 128 + colb] = u4;
      } else if (ny == 1) {
        ushort4 u4;
        u4.x = bfx(a[0]); u4.y = bfx(a[1]); u4.z = bfx(a[2]); u4.w = bfx(a[3]);
        *(ushort4*)&k16[(size_t)m * 128 + colb] = u4;
      } else {
        const int rowl = wm * 32 + mt * 16 + c;  // row within block tile
#pragma unroll
        for (int r = 0; r < 4; ++r)
          vtile[colb + r][rowl] = bfx(a[r]);
      }
    }
  }
  if (ny == 2) {
    __syncthreads();
    const int bb = base >> 14, nn0 = base & 16383;
    const int t = threadIdx.x;
    const int d = t >> 1, half = t & 1;
    ushort* dst = vT + (size_t)bb * VT_BATCH + (size_t)d * VT_STRIDE + 64 + nn0 + half * 32;
    const ushort* srcl = &vtile[d][half * 32];
#pragma unroll
    for (int u = 0; u < 4; ++u)
      *(uint4*)(dst + u * 8) = *(const uint4*)(srcl + u * 8);
  }
}

// ---------------- K6: transition mid GEMM (W1||W2 paired, silu-mul) --------
__global__ __launch_bounds__(256) void k_gemm_mid(
    const ushort* __restrict__ act16, const ushort* __restrict__ midWt,
    ushort* __restrict__ bmid16) {
  const int wid = threadIdx.x >> 6, lane = threadIdx.x & 63;
  const int c = lane & 15, s = lane >> 4;
  const int wm = wid & 1, wn = wid >> 1;
  const int m0 = blockIdx.x * 64 + wm * 32;
  const int nb = blockIdx.y * 64 + wn * 32;
  f32x4 acc1[2][2], acc2[2][2];
#pragma unroll
  for (int nt = 0; nt < 2; ++nt)
#pragma unroll
    for (int mt = 0; mt < 2; ++mt) {
      acc1[nt][mt][0]=0.f; acc1[nt][mt][1]=0.f; acc1[nt][mt][2]=0.f; acc1[nt][mt][3]=0.f;
      acc2[nt][mt][0]=0.f; acc2[nt][mt][1]=0.f; acc2[nt][mt][2]=0.f; acc2[nt][mt][3]=0.f;
    }
#pragma unroll
  for (int kk = 0; kk < 4; ++kk) {
    const int k0 = kk * 32 + 8 * s;
    bf16x8 bA[2];
#pragma unroll
    for (int mt = 0; mt < 2; ++mt)
      bA[mt] = ldfrag(&act16[(size_t)(m0 + mt * 16 + c) * 128 + k0]);
#pragma unroll
    for (int nt = 0; nt < 2; ++nt) {
      const bf16x8 aW1 = ldfrag(&midWt[(size_t)(nb + nt * 16 + c) * 128 + k0]);
      const bf16x8 aW2 = ldfrag(&midWt[(size_t)(256 + nb + nt * 16 + c) * 128 + k0]);
#pragma unroll
      for (int mt = 0; mt < 2; ++mt) {
        acc1[nt][mt] = __builtin_amdgcn_mfma_f32_16x16x32_bf16(aW1, bA[mt], acc1[nt][mt], 0, 0, 0);
        acc2[nt][mt] = __builtin_amdgcn_mfma_f32_16x16x32_bf16(aW2, bA[mt], acc2[nt][mt], 0, 0, 0);
      }
    }
  }
#pragma unroll
  for (int nt = 0; nt < 2; ++nt) {
    const int colb = nb + nt * 16 + 4 * s;
#pragma unroll
    for (int mt = 0; mt < 2; ++mt) {
      const int m = m0 + mt * 16 + c;
      ushort4 u4;
#pragma unroll
      for (int r = 0; r < 4; ++r) {
        const float a1 = acc1[nt][mt][r];
        const float v = a1 * sigm(a1) * acc2[nt][mt][r];
        ((unsigned short*)&u4)[r] = bfx(v);
      }
      *(ushort4*)&bmid16[(size_t)m * 256 + colb] = u4;
    }
  }
}

// ---------------- K7: out GEMM (K=256) + gated residual --------------------
// Re-tiled 32x64 per block, grid (1024,2) -> 8 waves/SIMD for BW.
__global__ __launch_bounds__(256) void k_gemm_out(
    const ushort* __restrict__ bmid16, const ushort* __restrict__ WoT,
    const float* __restrict__ atomw, const int* __restrict__ idxG,
    const float* __restrict__ TcG, const float* __restrict__ pmask,
    float* __restrict__ outG) {
  const int wid = threadIdx.x >> 6, lane = threadIdx.x & 63;
  const int c = lane & 15, s = lane >> 4;
  const int wm = wid & 1, wn = wid >> 1;
  const int m0 = blockIdx.x * 32 + wm * 16;
  const int nby = blockIdx.y * 64 + wn * 32;
  f32x4 acc[2];
  acc[0][0]=0.f; acc[0][1]=0.f; acc[0][2]=0.f; acc[0][3]=0.f;
  acc[1][0]=0.f; acc[1][1]=0.f; acc[1][2]=0.f; acc[1][3]=0.f;
#pragma unroll
  for (int kk = 0; kk < 8; ++kk) {
    const int k0 = kk * 32 + 8 * s;
    const bf16x8 bA = ldfrag(&bmid16[(size_t)(m0 + c) * 256 + k0]);
#pragma unroll
    for (int nt = 0; nt < 2; ++nt) {
      const bf16x8 aW = ldfrag(&WoT[(size_t)(nby + nt * 16 + c) * 256 + k0]);
      acc[nt] = __builtin_amdgcn_mfma_f32_16x16x32_bf16(aW, bA, acc[nt], 0, 0, 0);
    }
  }
  const int m = m0 + c;
  const int b = m >> 14;
  const int idx = idxG[m];
  const float pm = pmask[m];
  const size_t tcb = ((size_t)(b * Rc) + idx) * CAc;
#pragma unroll
  for (int nt = 0; nt < 2; ++nt) {
    const int colb = nby + nt * 16 + 4 * s;
    const float4 tc = *(const float4*)&TcG[tcb + colb];
    const float4 at = *(const float4*)&atomw[(size_t)m * CAc + colb];
    float4 o;
    o.x = at.x + tc.x * acc[nt][0] * pm;
    o.y = at.y + tc.y * acc[nt][1] * pm;
    o.z = at.z + tc.z * acc[nt][2] * pm;
    o.w = at.w + tc.w * acc[nt][3] * pm;
    *(float4*)&outG[(size_t)m * CAc + colb] = o;
  }
}

// ---------------- K4a: atompair LN+bias -> bf16 MFMA-layout buffer ---------
// 512 threads/block (8 waves) -> 8 waves/SIMD to saturate the 268 MB stream.
__global__ __launch_bounds__(512) void k_bias(
    const float* __restrict__ ap, const float* __restrict__ bw,
    const float* __restrict__ bb, const float* __restrict__ bW,
    ushort* __restrict__ bias16g) {
  __shared__ ushort bias16[4 * 4096];  // 32 KB
  __shared__ float cws[CPc], cbs[CPc], cWs[CPc * Hc];
  const int tid = threadIdx.x;
  const int bwid = blockIdx.x;
  const int w = bwid & 511;
  if (tid < CPc) { cws[tid] = bw[tid]; cbs[tid] = bb[tid]; }
  if (tid >= 64 && tid < 64 + CPc * Hc) cWs[tid - 64] = bW[tid - 64];
  __syncthreads();

  const float* apw = ap + (size_t)bwid * (WQc * WKc * CPc);
#pragma unroll
  for (int u = 0; u < 8; ++u) {
    const int p = tid + 512 * u;
    const int qq = p >> 7, kk = p & 127;
    const float* src = apw + (size_t)p * CPc;
    float x[16];
    float sum = 0.f, sq = 0.f;
#pragma unroll
    for (int t = 0; t < 4; ++t) {
      const float4 v4 = *(const float4*)&src[t * 4];
      x[4 * t] = v4.x; x[4 * t + 1] = v4.y; x[4 * t + 2] = v4.z; x[4 * t + 3] = v4.w;
      sum += v4.x + v4.y + v4.z + v4.w;
      sq += v4.x * v4.x + v4.y * v4.y + v4.z * v4.z + v4.w * v4.w;
    }
    const float mn = sum * 0.0625f;
    const float var = sq * 0.0625f - mn * mn;
    const float rs = rsqrtf(var + EPSf);
    float b0 = 0.f, b1 = 0.f, b2 = 0.f, b3 = 0.f;
#pragma unroll
    for (int cp = 0; cp < 16; ++cp) {
      const float yv = (x[cp] - mn) * rs * cws[cp] + cbs[cp];
      b0 += yv * cWs[cp * 4 + 0]; b1 += yv * cWs[cp * 4 + 1];
      b2 += yv * cWs[cp * 4 + 2]; b3 += yv * cWs[cp * 4 + 3];
    }
    const int gk = w * 32 - 48 + kk;
    const float maskt = (gk >= 0 && gk < Nc) ? 0.f : NEG_INF;
    const int mt = kk >> 4, s_ = (kk >> 2) & 3, r_ = kk & 3;
    const int ntq = qq >> 4, c_ = qq & 15;
    const int col = s_ * 16 + (c_ ^ ((mt & 3) << 2) ^ s_);
    const int base = ((mt * 2 + ntq) << 8) + col * 4 + r_;
    bias16[base]         = bfx(b0 + maskt);
    bias16[base + 4096]  = bfx(b1 + maskt);
    bias16[base + 8192]  = bfx(b2 + maskt);
    bias16[base + 12288] = bfx(b3 + maskt);
  }
  __syncthreads();
  const uint4* s4 = (const uint4*)bias16;
  uint4* d4 = (uint4*)(bias16g + (size_t)bwid * 16384);
#pragma unroll
  for (int u = 0; u < 4; ++u) d4[tid + 512 * u] = s4[tid + 512 * u];
}

// ---------------- K4b: MFMA windowed attention, wave-per-block, no LDS -----
// XCD-chunked block swizzle: consecutive windows land on the same XCD's L2
// so the 4x-overlapped K/V reads become L2 hits (T1; 4096 % 8 == 0).
__global__ __launch_bounds__(64) void k_attn6(
    const ushort* __restrict__ qG, const ushort* __restrict__ kG,
    const ushort* __restrict__ vT, const ushort* __restrict__ bias16g,
    const int* __restrict__ idxG, const float* __restrict__ SgG,
    const float* __restrict__ pmask, const float* __restrict__ atomF,
    float* __restrict__ atomO) {
  const int lb = (blockIdx.x & 7) * 512 + (blockIdx.x >> 3);
  const int bwid = lb >> 2;
  const int h = lb & 3;
  const int lane = threadIdx.x;
  const int c = lane & 15, s = lane >> 4;
  const int b = bwid >> 9, w = bwid & 511;
  const size_t bN = (size_t)b * Nc;

  f32x4 acc[8][2];
  {
    const ushort* bh = bias16g + (size_t)bwid * 16384 + h * 4096;
#pragma unroll
    for (int mt = 0; mt < 8; ++mt) {
      const int col = s * 16 + (c ^ ((mt & 3) << 2) ^ s);
#pragma unroll
      for (int ntq = 0; ntq < 2; ++ntq) {
        const uint2 pk = *(const uint2*)&bh[((mt * 2 + ntq) << 8) + col * 4];
        acc[mt][ntq][0] = ubf(pk.x & 0xffff);
        acc[mt][ntq][1] = ubf(pk.x >> 16);
        acc[mt][ntq][2] = ubf(pk.y & 0xffff);
        acc[mt][ntq][3] = ubf(pk.y >> 16);
      }
    }
  }

  bf16x8 bfragQ[2];
#pragma unroll
  for (int ntq = 0; ntq < 2; ++ntq) {
    const int qq = w * 32 + ntq * 16 + c;
    bfragQ[ntq] = ldfrag(&qG[(bN + qq) * CAc + h * 32 + 8 * s]);
  }
#pragma unroll
  for (int mt = 0; mt < 8; ++mt) {
    int gk = w * 32 - 48 + mt * 16 + c;
    gk = min(max(gk, 0), Nc - 1);
    const bf16x8 afragK = ldfrag(&kG[(bN + gk) * CAc + h * 32 + 8 * s]);
#pragma unroll
    for (int ntq = 0; ntq < 2; ++ntq)
      acc[mt][ntq] = __builtin_amdgcn_mfma_f32_16x16x32_bf16(afragK, bfragQ[ntq],
                                                             acc[mt][ntq], 0, 0, 0);
  }

  int ppk[8][2][2];
#pragma unroll
  for (int ntq = 0; ntq < 2; ++ntq) {
    float mx = -3e38f;
#pragma unroll
    for (int mt = 0; mt < 8; ++mt)
#pragma unroll
      for (int r = 0; r < 4; ++r) mx = fmaxf(mx, acc[mt][ntq][r]);
    mx = fmaxf(mx, __shfl_xor(mx, 16, 64));
    mx = fmaxf(mx, __shfl_xor(mx, 32, 64));
    float sm = 0.f;
#pragma unroll
    for (int mt = 0; mt < 8; ++mt)
#pragma unroll
      for (int r = 0; r < 4; ++r) {
        const float e = __expf(acc[mt][ntq][r] - mx);
        acc[mt][ntq][r] = e;
        sm += e;
      }
    sm += __shfl_xor(sm, 16, 64);
    sm += __shfl_xor(sm, 32, 64);
    const float inv = 1.0f / sm;
#pragma unroll
    for (int mt = 0; mt < 8; ++mt) {
      ppk[mt][ntq][0] = (int)pk2(acc[mt][ntq][0] * inv, acc[mt][ntq][1] * inv);
      ppk[mt][ntq][1] = (int)pk2(acc[mt][ntq][2] * inv, acc[mt][ntq][3] * inv);
    }
  }

  f32x4 opv[2][2];
#pragma unroll
  for (int i = 0; i < 2; ++i)
#pragma unroll
    for (int j = 0; j < 2; ++j) { opv[i][j][0]=0.f; opv[i][j][1]=0.f; opv[i][j][2]=0.f; opv[i][j][3]=0.f; }
  const int idxA = 4 * ((((2 * s) & 3) << 4) | c);
  const int idxB = 4 * ((((2 * s + 1) & 3) << 4) | c);
  const ushort* vTb = vT + (size_t)b * VT_BATCH;
#pragma unroll
  for (int ks = 0; ks < 4; ++ks) {
    const int vbase = 64 + w * 32 - 48 + ks * 32 + 8 * s;
    bf16x8 bV[2];
#pragma unroll
    for (int ntd = 0; ntd < 2; ++ntd) {
      const int d = h * 32 + ntd * 16 + c;
      bV[ntd] = ldfrag(&vTb[(size_t)d * VT_STRIDE + vbase]);
    }
#pragma unroll
    for (int mtp = 0; mtp < 2; ++mtp) {
      int atv[4];
      {
        const int a0 = __builtin_amdgcn_ds_bpermute(idxA, ppk[2 * ks][mtp][0]);
        const int b0 = __builtin_amdgcn_ds_bpermute(idxA, ppk[2 * ks + 1][mtp][0]);
        atv[0] = (s < 2) ? a0 : b0;
        const int a1 = __builtin_amdgcn_ds_bpermute(idxA, ppk[2 * ks][mtp][1]);
        const int b1 = __builtin_amdgcn_ds_bpermute(idxA, ppk[2 * ks + 1][mtp][1]);
        atv[1] = (s < 2) ? a1 : b1;
        const int a2 = __builtin_amdgcn_ds_bpermute(idxB, ppk[2 * ks][mtp][0]);
        const int b2 = __builtin_amdgcn_ds_bpermute(idxB, ppk[2 * ks + 1][mtp][0]);
        atv[2] = (s < 2) ? a2 : b2;
        const int a3 = __builtin_amdgcn_ds_bpermute(idxB, ppk[2 * ks][mtp][1]);
        const int b3 = __builtin_amdgcn_ds_bpermute(idxB, ppk[2 * ks + 1][mtp][1]);
        atv[3] = (s < 2) ? a3 : b3;
      }
      const bf16x8 afragP = __builtin_bit_cast(bf16x8, *(const u32x4*)atv);
#pragma unroll
      for (int ntd = 0; ntd < 2; ++ntd)
        opv[mtp][ntd] = __builtin_amdgcn_mfma_f32_16x16x32_bf16(
            afragP, bV[ntd], opv[mtp][ntd], 0, 0, 0);
    }
  }

#pragma unroll
  for (int mtp = 0; mtp < 2; ++mtp) {
#pragma unroll
    for (int r = 0; r < 4; ++r) {
      const int qq = w * 32 + mtp * 16 + 4 * s + r;
      const size_t rowg = bN + qq;
      const int residx = idxG[rowg];
      const float pm = pmask[rowg];
      const size_t gbase = ((size_t)b * Rc + residx) * CAc;
#pragma unroll
      for (int ntd = 0; ntd < 2; ++ntd) {
        const int d = h * 32 + ntd * 16 + c;
        const float g = SgG[gbase + d];
        const float af = atomF[rowg * CAc + d];
        atomO[rowg * CAc + d] = af + opv[mtp][ntd][r] * g * pm;
      }
    }
  }
}

}  // namespace

extern "C" void kernel_launch(void* const* d_in, const int* in_sizes, int n_in,
                              void* d_out, int out_size, void* d_ws, size_t ws_size,
                              hipStream_t stream) {
  (void)in_sizes; (void)n_in; (void)out_size; (void)ws_size;
  const float* atomF   = (const float*)d_in[0];
  const float* resF    = (const float*)d_in[1];
  const float* apF     = (const float*)d_in[2];
  const int*   idx     = (const int*)d_in[3];
  const float* pmask   = (const float*)d_in[4];
  const float* a_ln_w  = (const float*)d_in[6];
  const float* a_Wg    = (const float*)d_in[7];
  const float* a_bg    = (const float*)d_in[8];
  const float* a_Wb    = (const float*)d_in[9];
  const float* q_W     = (const float*)d_in[10];
  const float* q_b     = (const float*)d_in[11];
  const float* kv_W    = (const float*)d_in[12];
  const float* bij_ln_w= (const float*)d_in[13];
  const float* bij_ln_b= (const float*)d_in[14];
  const float* bij_W   = (const float*)d_in[15];
  const float* sg_W    = (const float*)d_in[16];
  const float* sg_b    = (const float*)d_in[17];
  const float* t_ln_w  = (const float*)d_in[18];
  const float* t_Wg    = (const float*)d_in[19];
  const float* t_bg    = (const float*)d_in[20];
  const float* t_Wb    = (const float*)d_in[21];
  const float* t_W1    = (const float*)d_in[22];
  const float* t_W2    = (const float*)d_in[23];
  const float* t_Wc    = (const float*)d_in[24];
  const float* t_bc    = (const float*)d_in[25];
  const float* t_Wo    = (const float*)d_in[26];

  float* ws = (float*)d_ws;
  float* Ag    = ws;                          // 6 x 524288
  float* Ab    = Ag + 524288;
  float* Tg    = Ab + 524288;
  float* Tb    = Tg + 524288;
  float* Sg    = Tb + 524288;
  float* Tc    = Sg + 524288;
  float* lnA   = Tc + 524288;                 // 1048576
  float* lnT   = lnA + 1048576;               // 1048576
  ushort* act16  = (ushort*)(lnT + 1048576);  // 4194304 ushorts (s, then t)
  ushort* q16    = act16 + 4194304;           // 4194304 ushorts
  ushort* k16    = q16 + 4194304;             // 4194304 ushorts
  ushort* bias16g= k16 + 4194304;             // 16777216 ushorts
  ushort* bmid16 = bias16g + 16777216;        // 8388608 ushorts
  float* atomw   = (float*)(bmid16 + 8388608);// 4194304 floats
  ushort* qWt    = (ushort*)(atomw + 4194304);// 16384
  ushort* kvWt   = qWt + 16384;               // 32768
  ushort* midWt  = kvWt + 32768;              // 65536
  ushort* WoT    = midWt + 65536;             // 32768
  ushort* vT     = WoT + 32768;               // 2 x 128 x 16512 = 4227072 ushorts

  k_pack<<<dim3(704), dim3(256), 0, stream>>>(q_W, kv_W, t_W1, t_W2, t_Wo,
                                              qWt, kvWt, midWt, WoT, vT);
  k_res_ln<<<dim3(Bc * Rc / 4), dim3(256), 0, stream>>>(resF, a_ln_w, t_ln_w, lnA, lnT);
  k_res_gemm<<<dim3(Bc * Rc / 32, 6), dim3(256), 0, stream>>>(
      lnA, lnT, resF, a_Wg, a_bg, a_Wb, t_Wg, t_bg, t_Wb, sg_W, sg_b, t_Wc, t_bc,
      Ag, Ab, Tg, Tb, Sg, Tc);
  k_adaln16<<<dim3(Bc * Nc / 4), dim3(256), 0, stream>>>(atomF, idx, Ag, Ab,
                                                         (unsigned*)act16);
  k_gemm_qkv<<<dim3(Bc * Nc / 64, 3), dim3(256), 0, stream>>>(act16, qWt, kvWt, q_b,
                                                              q16, k16, vT);
  k_bias<<<dim3(Bc * NWc), dim3(512), 0, stream>>>(apF, bij_ln_w, bij_ln_b, bij_W,
                                                   bias16g);
  k_attn6<<<dim3(Bc * NWc * 4), dim3(64), 0, stream>>>(q16, k16, vT, bias16g, idx, Sg,
                                                       pmask, atomF, atomw);
  k_adaln16<<<dim3(Bc * Nc / 4), dim3(256), 0, stream>>>(atomw, idx, Tg, Tb,
                                                         (unsigned*)act16);
  k_gemm_mid<<<dim3(Bc * Nc / 64, 4), dim3(256), 0, stream>>>(act16, midWt, bmid16);
  k_gemm_out<<<dim3(Bc * Nc / 32, 2), dim3(256), 0, stream>>>(bmid16, WoT, atomw, idx,
                                                              Tc, pmask, (float*)d_out);
}

// Round 12
// 237.870 us; speedup vs baseline: 1.3225x; 1.3225x over previous
//
#include <hip/hip_runtime.h>
#include <hip/hip_bf16.h>
#include <string.h>

namespace {

constexpr int Bc  = 2;
constexpr int Nc  = 16384;
constexpr int Rc  = 2048;
constexpr int CAc = 128;
constexpr int CSc = 256;
constexpr int CPc = 16;
constexpr int Hc  = 4;
constexpr int WQc = 32;
constexpr int WKc = 128;
constexpr int NWc = 512;
constexpr float EPSf     = 1e-5f;
constexpr float NEG_INF  = -1e8f;
constexpr float QK_SCALE = 0.17677669529663687f;  // 1/sqrt(32)

constexpr int VT_STRIDE = 16512;          // 64 pad + 16384 + 64 pad
constexpr int VT_BATCH  = 128 * VT_STRIDE;

typedef short bf16x8 __attribute__((ext_vector_type(8)));
typedef float f32x4 __attribute__((ext_vector_type(4)));
typedef unsigned int u32x4 __attribute__((ext_vector_type(4)));

__device__ __forceinline__ float wsum(float v) {
#pragma unroll
  for (int m = 1; m < 64; m <<= 1) v += __shfl_xor(v, m, 64);
  return v;
}
__device__ __forceinline__ float sigm(float x) { return 1.0f / (1.0f + __expf(-x)); }
__device__ __forceinline__ float f4c(const float4& v, int i) {
  return i == 0 ? v.x : i == 1 ? v.y : i == 2 ? v.z : v.w;
}
__device__ __forceinline__ unsigned short bfx(float v) {
  __hip_bfloat16 h = __float2bfloat16(v);
  unsigned short u;
  memcpy(&u, &h, 2);
  return u;
}
__device__ __forceinline__ unsigned pk2(float a, float b) {
  return (unsigned)bfx(a) | ((unsigned)bfx(b) << 16);
}
__device__ __forceinline__ float ubf(unsigned us) {
  unsigned v = us << 16;
  float f;
  memcpy(&f, &v, 4);
  return f;
}
__device__ __forceinline__ bf16x8 ldfrag(const ushort* p) {
  return __builtin_bit_cast(bf16x8, *(const u32x4*)p);
}

// ---------------- K0: pack weights to bf16 W^T layouts + zero vT pads ------
__global__ void k_pack(const float* __restrict__ q_W, const float* __restrict__ kv_W,
                       const float* __restrict__ t_W1, const float* __restrict__ t_W2,
                       const float* __restrict__ t_Wo,
                       ushort* __restrict__ qWt, ushort* __restrict__ kvWt,
                       ushort* __restrict__ midWt, ushort* __restrict__ WoT,
                       ushort* __restrict__ vT) {
  const int i = blockIdx.x * 256 + threadIdx.x;
  if (i < 16384) {
    const int n = i >> 7, k = i & 127;
    qWt[i] = bfx(q_W[k * 128 + n]);
  } else if (i < 49152) {
    const int i2 = i - 16384;
    const int n = i2 >> 7, k = i2 & 127;
    kvWt[i2] = bfx(kv_W[k * 256 + n]);
  } else if (i < 114688) {
    const int i3 = i - 49152;
    const int n = i3 >> 7, k = i3 & 127;
    midWt[i3] = bfx(n < 256 ? t_W1[k * 256 + n] : t_W2[k * 256 + (n - 256)]);
  } else if (i < 147456) {
    const int i4 = i - 114688;
    const int n = i4 >> 8, k = i4 & 255;
    WoT[i4] = bfx(t_Wo[k * 128 + n]);
  } else if (i < 180224) {
    const int j = i - 147456;           // vT edge pads -> 0
    const int b = j >> 14, rem = j & 16383;
    const int d = rem >> 7, p = rem & 127;
    const int col = (p < 64) ? p : (16384 + p);
    vT[(size_t)b * VT_BATCH + (size_t)d * VT_STRIDE + col] = 0;
  }
}

// ---------------- K1a: per-res LN (two weighted variants) ----------------
__global__ void k_res_ln(const float* __restrict__ res, const float* __restrict__ a_ln_w,
                         const float* __restrict__ t_ln_w, float* __restrict__ lnA,
                         float* __restrict__ lnT) {
  const int wid = threadIdx.x >> 6, lane = threadIdx.x & 63;
  const int row = blockIdx.x * 4 + wid;  // B*R rows
  const float* r = res + (size_t)row * CSc;
  float x[4], s = 0.f, sq = 0.f;
#pragma unroll
  for (int i = 0; i < 4; ++i) { x[i] = r[lane + 64 * i]; s += x[i]; sq += x[i] * x[i]; }
  s = wsum(s); sq = wsum(sq);
  const float mn = s * (1.0f / CSc);
  const float var = sq * (1.0f / CSc) - mn * mn;
  const float rs = rsqrtf(var + EPSf);
#pragma unroll
  for (int i = 0; i < 4; ++i) {
    const int c = lane + 64 * i;
    const float y = (x[i] - mn) * rs;
    lnA[(size_t)row * CSc + c] = y * a_ln_w[c];
    lnT[(size_t)row * CSc + c] = y * t_ln_w[c];
  }
}

// ---------------- K1b: 6 res GEMMs (K=256 -> 128 cols), gates sigmoid'd ----
__global__ void k_res_gemm(const float* __restrict__ lnA, const float* __restrict__ lnT,
                           const float* __restrict__ res,
                           const float* __restrict__ a_Wg, const float* __restrict__ a_bg,
                           const float* __restrict__ a_Wb,
                           const float* __restrict__ t_Wg, const float* __restrict__ t_bg,
                           const float* __restrict__ t_Wb,
                           const float* __restrict__ sg_W, const float* __restrict__ sg_b,
                           const float* __restrict__ t_Wc, const float* __restrict__ t_bc,
                           float* __restrict__ Ag, float* __restrict__ Ab,
                           float* __restrict__ Tg, float* __restrict__ Tb,
                           float* __restrict__ Sg, float* __restrict__ Tc) {
  __shared__ float tile[32 * CSc];
  const int m = blockIdx.y;
  const float* in = (m < 2) ? lnA : (m < 4) ? lnT : res;
  const float* W  = (m == 0) ? a_Wg : (m == 1) ? a_Wb : (m == 2) ? t_Wg
                  : (m == 3) ? t_Wb : (m == 4) ? sg_W : t_Wc;
  const float* bias = (m == 0) ? a_bg : (m == 2) ? t_bg : (m == 4) ? sg_b
                    : (m == 5) ? t_bc : nullptr;
  const bool sig = (m == 0) || (m == 2) || (m == 4) || (m == 5);
  float* out = (m == 0) ? Ag : (m == 1) ? Ab : (m == 2) ? Tg
             : (m == 3) ? Tb : (m == 4) ? Sg : Tc;
  const int row0 = blockIdx.x * 32;
  const float4* src = (const float4*)(in + (size_t)row0 * CSc);
  float4* dst = (float4*)tile;
#pragma unroll
  for (int k = 0; k < 8; ++k) dst[threadIdx.x + 256 * k] = src[threadIdx.x + 256 * k];
  __syncthreads();
  const int c0 = (threadIdx.x & 31) * 4;
  const int r0 = (threadIdx.x >> 5) * 4;
  float acc[4][4] = {};
  for (int j = 0; j < CSc; j += 4) {
    float4 a[4];
#pragma unroll
    for (int r = 0; r < 4; ++r) a[r] = *(const float4*)&tile[(r0 + r) * CSc + j];
#pragma unroll
    for (int jj = 0; jj < 4; ++jj) {
      const float4 w = *(const float4*)&W[(size_t)(j + jj) * CAc + c0];
#pragma unroll
      for (int r = 0; r < 4; ++r) {
        const float av = f4c(a[r], jj);
        acc[r][0] += av * w.x; acc[r][1] += av * w.y;
        acc[r][2] += av * w.z; acc[r][3] += av * w.w;
      }
    }
  }
  float4 bv = make_float4(0.f, 0.f, 0.f, 0.f);
  if (bias) bv = *(const float4*)&bias[c0];
#pragma unroll
  for (int r = 0; r < 4; ++r) {
    float4 o;
    o.x = acc[r][0] + bv.x; o.y = acc[r][1] + bv.y;
    o.z = acc[r][2] + bv.z; o.w = acc[r][3] + bv.w;
    if (sig) { o.x = sigm(o.x); o.y = sigm(o.y); o.z = sigm(o.z); o.w = sigm(o.w); }
    *(float4*)&out[(size_t)(row0 + r0 + r) * CAc + c0] = o;
  }
}

// ---------------- K2/K5: adaLN over atoms -> bf16 out ----------------------
__global__ void k_adaln16(const float* __restrict__ in, const int* __restrict__ idxG,
                          const float* __restrict__ G, const float* __restrict__ Bb,
                          unsigned* __restrict__ out32) {
  const int wid = threadIdx.x >> 6, lane = threadIdx.x & 63;
  const int row = blockIdx.x * 4 + wid;  // B*N rows
  const int b = row >> 14;
  const float* r = in + (size_t)row * CAc;
  const float2 xp = *(const float2*)&r[2 * lane];
  const float s = wsum(xp.x + xp.y);
  const float sq = wsum(xp.x * xp.x + xp.y * xp.y);
  const float mn = s * (1.0f / CAc);
  const float var = sq * (1.0f / CAc) - mn * mn;
  const float rs = rsqrtf(var + EPSf);
  const int base = (b * Rc + idxG[row]) * CAc;
  const float2 g2 = *(const float2*)&G[base + 2 * lane];
  const float2 b2 = *(const float2*)&Bb[base + 2 * lane];
  const float y0 = (xp.x - mn) * rs * g2.x + b2.x;
  const float y1 = (xp.y - mn) * rs * g2.y + b2.y;
  out32[(size_t)row * 64 + lane] = pk2(y0, y1);
}

// ---------------- K3: qkv GEMM via MFMA (M=32768, K=128) -------------------
__global__ __launch_bounds__(256) void k_gemm_qkv(
    const ushort* __restrict__ act16, const ushort* __restrict__ qWt,
    const ushort* __restrict__ kvWt, const float* __restrict__ q_b,
    ushort* __restrict__ q16, ushort* __restrict__ k16, ushort* __restrict__ vT) {
  __shared__ ushort vtile[128][72];  // 18.4 KB; stride 144B keeps b128 aligned
  const int ny = blockIdx.y;
  const int wid = threadIdx.x >> 6, lane = threadIdx.x & 63;
  const int c = lane & 15, s = lane >> 4;
  const int wm = wid & 1, wn = wid >> 1;
  const int base = blockIdx.x * 64;
  const int m0 = base + wm * 32;
  const int nb = wn * 64;
  const ushort* Wt = (ny == 0) ? qWt : kvWt + (ny == 2 ? 128 * 128 : 0);
  f32x4 acc[4][2];
#pragma unroll
  for (int nt = 0; nt < 4; ++nt)
#pragma unroll
    for (int mt = 0; mt < 2; ++mt) { acc[nt][mt][0]=0.f; acc[nt][mt][1]=0.f; acc[nt][mt][2]=0.f; acc[nt][mt][3]=0.f; }
#pragma unroll
  for (int kk = 0; kk < 4; ++kk) {
    const int k0 = kk * 32 + 8 * s;
    bf16x8 bA[2];
#pragma unroll
    for (int mt = 0; mt < 2; ++mt)
      bA[mt] = ldfrag(&act16[(size_t)(m0 + mt * 16 + c) * 128 + k0]);
#pragma unroll
    for (int nt = 0; nt < 4; ++nt) {
      const bf16x8 aW = ldfrag(&Wt[(size_t)(nb + nt * 16 + c) * 128 + k0]);
#pragma unroll
      for (int mt = 0; mt < 2; ++mt)
        acc[nt][mt] = __builtin_amdgcn_mfma_f32_16x16x32_bf16(aW, bA[mt], acc[nt][mt], 0, 0, 0);
    }
  }
#pragma unroll
  for (int nt = 0; nt < 4; ++nt) {
    const int colb = nb + nt * 16 + 4 * s;
    float4 qb4 = make_float4(0.f, 0.f, 0.f, 0.f);
    if (ny == 0) qb4 = *(const float4*)&q_b[colb];
#pragma unroll
    for (int mt = 0; mt < 2; ++mt) {
      const int m = m0 + mt * 16 + c;
      const f32x4 a = acc[nt][mt];
      if (ny == 0) {
        ushort4 u4;
        u4.x = bfx((a[0] + qb4.x) * QK_SCALE); u4.y = bfx((a[1] + qb4.y) * QK_SCALE);
        u4.z = bfx((a[2] + qb4.z) * QK_SCALE); u4.w = bfx((a[3] + qb4.w) * QK_SCALE);
        *(ushort4*)&q16[(size_t)m * 128 + colb] = u4;
      } else if (ny == 1) {
        ushort4 u4;
        u4.x = bfx(a[0]); u4.y = bfx(a[1]); u4.z = bfx(a[2]); u4.w = bfx(a[3]);
        *(ushort4*)&k16[(size_t)m * 128 + colb] = u4;
      } else {
        const int rowl = wm * 32 + mt * 16 + c;  // row within block tile
#pragma unroll
        for (int r = 0; r < 4; ++r)
          vtile[colb + r][rowl] = bfx(a[r]);
      }
    }
  }
  if (ny == 2) {
    __syncthreads();
    const int bb = base >> 14, nn0 = base & 16383;
    const int t = threadIdx.x;
    const int d = t >> 1, half = t & 1;
    ushort* dst = vT + (size_t)bb * VT_BATCH + (size_t)d * VT_STRIDE + 64 + nn0 + half * 32;
    const ushort* srcl = &vtile[d][half * 32];
#pragma unroll
    for (int u = 0; u < 4; ++u)
      *(uint4*)(dst + u * 8) = *(const uint4*)(srcl + u * 8);
  }
}

// ---------------- K6: transition mid GEMM (W1||W2 paired, silu-mul) --------
__global__ __launch_bounds__(256) void k_gemm_mid(
    const ushort* __restrict__ act16, const ushort* __restrict__ midWt,
    ushort* __restrict__ bmid16) {
  const int wid = threadIdx.x >> 6, lane = threadIdx.x & 63;
  const int c = lane & 15, s = lane >> 4;
  const int wm = wid & 1, wn = wid >> 1;
  const int m0 = blockIdx.x * 64 + wm * 32;
  const int nb = blockIdx.y * 64 + wn * 32;
  f32x4 acc1[2][2], acc2[2][2];
#pragma unroll
  for (int nt = 0; nt < 2; ++nt)
#pragma unroll
    for (int mt = 0; mt < 2; ++mt) {
      acc1[nt][mt][0]=0.f; acc1[nt][mt][1]=0.f; acc1[nt][mt][2]=0.f; acc1[nt][mt][3]=0.f;
      acc2[nt][mt][0]=0.f; acc2[nt][mt][1]=0.f; acc2[nt][mt][2]=0.f; acc2[nt][mt][3]=0.f;
    }
#pragma unroll
  for (int kk = 0; kk < 4; ++kk) {
    const int k0 = kk * 32 + 8 * s;
    bf16x8 bA[2];
#pragma unroll
    for (int mt = 0; mt < 2; ++mt)
      bA[mt] = ldfrag(&act16[(size_t)(m0 + mt * 16 + c) * 128 + k0]);
#pragma unroll
    for (int nt = 0; nt < 2; ++nt) {
      const bf16x8 aW1 = ldfrag(&midWt[(size_t)(nb + nt * 16 + c) * 128 + k0]);
      const bf16x8 aW2 = ldfrag(&midWt[(size_t)(256 + nb + nt * 16 + c) * 128 + k0]);
#pragma unroll
      for (int mt = 0; mt < 2; ++mt) {
        acc1[nt][mt] = __builtin_amdgcn_mfma_f32_16x16x32_bf16(aW1, bA[mt], acc1[nt][mt], 0, 0, 0);
        acc2[nt][mt] = __builtin_amdgcn_mfma_f32_16x16x32_bf16(aW2, bA[mt], acc2[nt][mt], 0, 0, 0);
      }
    }
  }
#pragma unroll
  for (int nt = 0; nt < 2; ++nt) {
    const int colb = nb + nt * 16 + 4 * s;
#pragma unroll
    for (int mt = 0; mt < 2; ++mt) {
      const int m = m0 + mt * 16 + c;
      ushort4 u4;
#pragma unroll
      for (int r = 0; r < 4; ++r) {
        const float a1 = acc1[nt][mt][r];
        const float v = a1 * sigm(a1) * acc2[nt][mt][r];
        ((unsigned short*)&u4)[r] = bfx(v);
      }
      *(ushort4*)&bmid16[(size_t)m * 256 + colb] = u4;
    }
  }
}

// ---------------- K7: out GEMM (K=256) + gated residual (R9 form) ----------
__global__ __launch_bounds__(256) void k_gemm_out(
    const ushort* __restrict__ bmid16, const ushort* __restrict__ WoT,
    const float* __restrict__ atomw, const int* __restrict__ idxG,
    const float* __restrict__ TcG, const float* __restrict__ pmask,
    float* __restrict__ outG) {
  const int wid = threadIdx.x >> 6, lane = threadIdx.x & 63;
  const int c = lane & 15, s = lane >> 4;
  const int wm = wid & 1, wn = wid >> 1;
  const int m0 = blockIdx.x * 64 + wm * 32;
  const int nb = wn * 64;
  f32x4 acc[4][2];
#pragma unroll
  for (int nt = 0; nt < 4; ++nt)
#pragma unroll
    for (int mt = 0; mt < 2; ++mt) { acc[nt][mt][0]=0.f; acc[nt][mt][1]=0.f; acc[nt][mt][2]=0.f; acc[nt][mt][3]=0.f; }
#pragma unroll
  for (int kk = 0; kk < 8; ++kk) {
    const int k0 = kk * 32 + 8 * s;
    bf16x8 bA[2];
#pragma unroll
    for (int mt = 0; mt < 2; ++mt)
      bA[mt] = ldfrag(&bmid16[(size_t)(m0 + mt * 16 + c) * 256 + k0]);
#pragma unroll
    for (int nt = 0; nt < 4; ++nt) {
      const bf16x8 aW = ldfrag(&WoT[(size_t)(nb + nt * 16 + c) * 256 + k0]);
#pragma unroll
      for (int mt = 0; mt < 2; ++mt)
        acc[nt][mt] = __builtin_amdgcn_mfma_f32_16x16x32_bf16(aW, bA[mt], acc[nt][mt], 0, 0, 0);
    }
  }
#pragma unroll
  for (int mt = 0; mt < 2; ++mt) {
    const int m = m0 + mt * 16 + c;
    const int b = m >> 14;
    const int idx = idxG[m];
    const float pm = pmask[m];
    const size_t tcb = ((size_t)(b * Rc) + idx) * CAc;
#pragma unroll
    for (int nt = 0; nt < 4; ++nt) {
      const int colb = nb + nt * 16 + 4 * s;
      const float4 tc = *(const float4*)&TcG[tcb + colb];
      const float4 at = *(const float4*)&atomw[(size_t)m * CAc + colb];
      float4 o;
      o.x = at.x + tc.x * acc[nt][mt][0] * pm;
      o.y = at.y + tc.y * acc[nt][mt][1] * pm;
      o.z = at.z + tc.z * acc[nt][mt][2] * pm;
      o.w = at.w + tc.w * acc[nt][mt][3] * pm;
      *(float4*)&outG[(size_t)m * CAc + colb] = o;
    }
  }
}

// ---------------- K4a v2: atompair LN+bias, folded math, half-window -------
// Folded LN (no x[16] array -> ~64 VGPR): bias_h = rs*(dot_h - mn*W2s_h)+Cb_h.
// grid = 2048 (2 blocks/window), 256 threads, 16.5 KB LDS -> high occupancy.
__global__ __launch_bounds__(256) void k_bias2(
    const float* __restrict__ ap, const float* __restrict__ bw,
    const float* __restrict__ bb, const float* __restrict__ bW,
    ushort* __restrict__ bias16g) {
  __shared__ ushort biasL[8192];       // 16 KB  [h][mt][col][r] for this half
  __shared__ float w2s[64], W2sh[4], Cbh[4];
  const int tid = threadIdx.x;
  const int bwid = blockIdx.x >> 1;
  const int half = blockIdx.x & 1;     // ntq of this block
  const int w = bwid & 511;
  if (tid < 64) w2s[tid] = bw[tid >> 2] * bW[tid];
  __syncthreads();
  if (tid < 4) {
    float a = 0.f, b2 = 0.f;
#pragma unroll
    for (int cp = 0; cp < 16; ++cp) { a += w2s[cp * 4 + tid]; b2 += bb[cp] * bW[cp * 4 + tid]; }
    W2sh[tid] = a; Cbh[tid] = b2;
  }
  __syncthreads();

  const float* apw = ap + (size_t)bwid * (WQc * WKc * CPc) + (size_t)half * (16 * 128 * CPc);
#pragma unroll
  for (int u = 0; u < 8; ++u) {
    const int p = tid + 256 * u;         // 2048 pairs (16 q x 128 k)
    const int qql = p >> 7, kk = p & 127;
    const float* src = apw + (size_t)p * CPc;
    float sum = 0.f, sq = 0.f, d0 = 0.f, d1 = 0.f, d2 = 0.f, d3 = 0.f;
#pragma unroll
    for (int t = 0; t < 4; ++t) {
      const float4 v4 = *(const float4*)&src[t * 4];
#pragma unroll
      for (int e = 0; e < 4; ++e) {
        const float x = f4c(v4, e);
        const float4 wv = *(const float4*)&w2s[(4 * t + e) * 4];
        sum += x; sq += x * x;
        d0 += x * wv.x; d1 += x * wv.y; d2 += x * wv.z; d3 += x * wv.w;
      }
    }
    const float mn = sum * 0.0625f;
    const float var = sq * 0.0625f - mn * mn;
    const float rs = rsqrtf(var + EPSf);
    const int gk = w * 32 - 48 + kk;
    const float maskt = (gk >= 0 && gk < Nc) ? 0.f : NEG_INF;
    const int mt = kk >> 4, s_ = (kk >> 2) & 3, r_ = kk & 3;
    const int col = s_ * 16 + (qql ^ ((mt & 3) << 2) ^ s_);
    const int base = mt * 256 + col * 4 + r_;
    biasL[base]        = bfx(rs * (d0 - mn * W2sh[0]) + Cbh[0] + maskt);
    biasL[base + 2048] = bfx(rs * (d1 - mn * W2sh[1]) + Cbh[1] + maskt);
    biasL[base + 4096] = bfx(rs * (d2 - mn * W2sh[2]) + Cbh[2] + maskt);
    biasL[base + 6144] = bfx(rs * (d3 - mn * W2sh[3]) + Cbh[3] + maskt);
  }
  __syncthreads();
  // dump: 32 chunks of 512B; chunk (h, mt) -> global h*4096 + (mt*2+half)*256
  uint4* dw = (uint4*)(bias16g + (size_t)bwid * 16384);
  const uint4* sl = (const uint4*)biasL;
#pragma unroll
  for (int u = 0; u < 4; ++u) {
    const int idx = tid + 256 * u;       // 1024 uint4
    const int chunk = idx >> 5, within = idx & 31;
    const int h = chunk >> 3, mt = chunk & 7;
    dw[h * 512 + (mt * 2 + half) * 32 + within] = sl[idx];
  }
}

// ---------------- K4b: MFMA windowed attention (R9 form, no swizzle) -------
__global__ __launch_bounds__(64) void k_attn6(
    const ushort* __restrict__ qG, const ushort* __restrict__ kG,
    const ushort* __restrict__ vT, const ushort* __restrict__ bias16g,
    const int* __restrict__ idxG, const float* __restrict__ SgG,
    const float* __restrict__ pmask, const float* __restrict__ atomF,
    float* __restrict__ atomO) {
  const int bwid = blockIdx.x >> 2;
  const int h = blockIdx.x & 3;
  const int lane = threadIdx.x;
  const int c = lane & 15, s = lane >> 4;
  const int b = bwid >> 9, w = bwid & 511;
  const size_t bN = (size_t)b * Nc;

  f32x4 acc[8][2];
  {
    const ushort* bh = bias16g + (size_t)bwid * 16384 + h * 4096;
#pragma unroll
    for (int mt = 0; mt < 8; ++mt) {
      const int col = s * 16 + (c ^ ((mt & 3) << 2) ^ s);
#pragma unroll
      for (int ntq = 0; ntq < 2; ++ntq) {
        const uint2 pk = *(const uint2*)&bh[((mt * 2 + ntq) << 8) + col * 4];
        acc[mt][ntq][0] = ubf(pk.x & 0xffff);
        acc[mt][ntq][1] = ubf(pk.x >> 16);
        acc[mt][ntq][2] = ubf(pk.y & 0xffff);
        acc[mt][ntq][3] = ubf(pk.y >> 16);
      }
    }
  }

  bf16x8 bfragQ[2];
#pragma unroll
  for (int ntq = 0; ntq < 2; ++ntq) {
    const int qq = w * 32 + ntq * 16 + c;
    bfragQ[ntq] = ldfrag(&qG[(bN + qq) * CAc + h * 32 + 8 * s]);
  }
#pragma unroll
  for (int mt = 0; mt < 8; ++mt) {
    int gk = w * 32 - 48 + mt * 16 + c;
    gk = min(max(gk, 0), Nc - 1);
    const bf16x8 afragK = ldfrag(&kG[(bN + gk) * CAc + h * 32 + 8 * s]);
#pragma unroll
    for (int ntq = 0; ntq < 2; ++ntq)
      acc[mt][ntq] = __builtin_amdgcn_mfma_f32_16x16x32_bf16(afragK, bfragQ[ntq],
                                                             acc[mt][ntq], 0, 0, 0);
  }

  int ppk[8][2][2];
#pragma unroll
  for (int ntq = 0; ntq < 2; ++ntq) {
    float mx = -3e38f;
#pragma unroll
    for (int mt = 0; mt < 8; ++mt)
#pragma unroll
      for (int r = 0; r < 4; ++r) mx = fmaxf(mx, acc[mt][ntq][r]);
    mx = fmaxf(mx, __shfl_xor(mx, 16, 64));
    mx = fmaxf(mx, __shfl_xor(mx, 32, 64));
    float sm = 0.f;
#pragma unroll
    for (int mt = 0; mt < 8; ++mt)
#pragma unroll
      for (int r = 0; r < 4; ++r) {
        const float e = __expf(acc[mt][ntq][r] - mx);
        acc[mt][ntq][r] = e;
        sm += e;
      }
    sm += __shfl_xor(sm, 16, 64);
    sm += __shfl_xor(sm, 32, 64);
    const float inv = 1.0f / sm;
#pragma unroll
    for (int mt = 0; mt < 8; ++mt) {
      ppk[mt][ntq][0] = (int)pk2(acc[mt][ntq][0] * inv, acc[mt][ntq][1] * inv);
      ppk[mt][ntq][1] = (int)pk2(acc[mt][ntq][2] * inv, acc[mt][ntq][3] * inv);
    }
  }

  f32x4 opv[2][2];
#pragma unroll
  for (int i = 0; i < 2; ++i)
#pragma unroll
    for (int j = 0; j < 2; ++j) { opv[i][j][0]=0.f; opv[i][j][1]=0.f; opv[i][j][2]=0.f; opv[i][j][3]=0.f; }
  const int idxA = 4 * ((((2 * s) & 3) << 4) | c);
  const int idxB = 4 * ((((2 * s + 1) & 3) << 4) | c);
  const ushort* vTb = vT + (size_t)b * VT_BATCH;
#pragma unroll
  for (int ks = 0; ks < 4; ++ks) {
    const int vbase = 64 + w * 32 - 48 + ks * 32 + 8 * s;
    bf16x8 bV[2];
#pragma unroll
    for (int ntd = 0; ntd < 2; ++ntd) {
      const int d = h * 32 + ntd * 16 + c;
      bV[ntd] = ldfrag(&vTb[(size_t)d * VT_STRIDE + vbase]);
    }
#pragma unroll
    for (int mtp = 0; mtp < 2; ++mtp) {
      int atv[4];
      {
        const int a0 = __builtin_amdgcn_ds_bpermute(idxA, ppk[2 * ks][mtp][0]);
        const int b0 = __builtin_amdgcn_ds_bpermute(idxA, ppk[2 * ks + 1][mtp][0]);
        atv[0] = (s < 2) ? a0 : b0;
        const int a1 = __builtin_amdgcn_ds_bpermute(idxA, ppk[2 * ks][mtp][1]);
        const int b1 = __builtin_amdgcn_ds_bpermute(idxA, ppk[2 * ks + 1][mtp][1]);
        atv[1] = (s < 2) ? a1 : b1;
        const int a2 = __builtin_amdgcn_ds_bpermute(idxB, ppk[2 * ks][mtp][0]);
        const int b2 = __builtin_amdgcn_ds_bpermute(idxB, ppk[2 * ks + 1][mtp][0]);
        atv[2] = (s < 2) ? a2 : b2;
        const int a3 = __builtin_amdgcn_ds_bpermute(idxB, ppk[2 * ks][mtp][1]);
        const int b3 = __builtin_amdgcn_ds_bpermute(idxB, ppk[2 * ks + 1][mtp][1]);
        atv[3] = (s < 2) ? a3 : b3;
      }
      const bf16x8 afragP = __builtin_bit_cast(bf16x8, *(const u32x4*)atv);
#pragma unroll
      for (int ntd = 0; ntd < 2; ++ntd)
        opv[mtp][ntd] = __builtin_amdgcn_mfma_f32_16x16x32_bf16(
            afragP, bV[ntd], opv[mtp][ntd], 0, 0, 0);
    }
  }

#pragma unroll
  for (int mtp = 0; mtp < 2; ++mtp) {
#pragma unroll
    for (int r = 0; r < 4; ++r) {
      const int qq = w * 32 + mtp * 16 + 4 * s + r;
      const size_t rowg = bN + qq;
      const int residx = idxG[rowg];
      const float pm = pmask[rowg];
      const size_t gbase = ((size_t)b * Rc + residx) * CAc;
#pragma unroll
      for (int ntd = 0; ntd < 2; ++ntd) {
        const int d = h * 32 + ntd * 16 + c;
        const float g = SgG[gbase + d];
        const float af = atomF[rowg * CAc + d];
        atomO[rowg * CAc + d] = af + opv[mtp][ntd][r] * g * pm;
      }
    }
  }
}

}  // namespace

extern "C" void kernel_launch(void* const* d_in, const int* in_sizes, int n_in,
                              void* d_out, int out_size, void* d_ws, size_t ws_size,
                              hipStream_t stream) {
  (void)in_sizes; (void)n_in; (void)out_size; (void)ws_size;
  const float* atomF   = (const float*)d_in[0];
  const float* resF    = (const float*)d_in[1];
  const float* apF     = (const float*)d_in[2];
  const int*   idx     = (const int*)d_in[3];
  const float* pmask   = (const float*)d_in[4];
  const float* a_ln_w  = (const float*)d_in[6];
  const float* a_Wg    = (const float*)d_in[7];
  const float* a_bg    = (const float*)d_in[8];
  const float* a_Wb    = (const float*)d_in[9];
  const float* q_W     = (const float*)d_in[10];
  const float* q_b     = (const float*)d_in[11];
  const float* kv_W    = (const float*)d_in[12];
  const float* bij_ln_w= (const float*)d_in[13];
  const float* bij_ln_b= (const float*)d_in[14];
  const float* bij_W   = (const float*)d_in[15];
  const float* sg_W    = (const float*)d_in[16];
  const float* sg_b    = (const float*)d_in[17];
  const float* t_ln_w  = (const float*)d_in[18];
  const float* t_Wg    = (const float*)d_in[19];
  const float* t_bg    = (const float*)d_in[20];
  const float* t_Wb    = (const float*)d_in[21];
  const float* t_W1    = (const float*)d_in[22];
  const float* t_W2    = (const float*)d_in[23];
  const float* t_Wc    = (const float*)d_in[24];
  const float* t_bc    = (const float*)d_in[25];
  const float* t_Wo    = (const float*)d_in[26];

  float* ws = (float*)d_ws;
  float* Ag    = ws;                          // 6 x 524288
  float* Ab    = Ag + 524288;
  float* Tg    = Ab + 524288;
  float* Tb    = Tg + 524288;
  float* Sg    = Tb + 524288;
  float* Tc    = Sg + 524288;
  float* lnA   = Tc + 524288;                 // 1048576
  float* lnT   = lnA + 1048576;               // 1048576
  ushort* act16  = (ushort*)(lnT + 1048576);  // 4194304 ushorts (s, then t)
  ushort* q16    = act16 + 4194304;           // 4194304 ushorts
  ushort* k16    = q16 + 4194304;             // 4194304 ushorts
  ushort* bias16g= k16 + 4194304;             // 16777216 ushorts
  ushort* bmid16 = bias16g + 16777216;        // 8388608 ushorts
  float* atomw   = (float*)(bmid16 + 8388608);// 4194304 floats
  ushort* qWt    = (ushort*)(atomw + 4194304);// 16384
  ushort* kvWt   = qWt + 16384;               // 32768
  ushort* midWt  = kvWt + 32768;              // 65536
  ushort* WoT    = midWt + 65536;             // 32768
  ushort* vT     = WoT + 32768;               // 2 x 128 x 16512 = 4227072 ushorts

  k_pack<<<dim3(704), dim3(256), 0, stream>>>(q_W, kv_W, t_W1, t_W2, t_Wo,
                                              qWt, kvWt, midWt, WoT, vT);
  k_res_ln<<<dim3(Bc * Rc / 4), dim3(256), 0, stream>>>(resF, a_ln_w, t_ln_w, lnA, lnT);
  k_res_gemm<<<dim3(Bc * Rc / 32, 6), dim3(256), 0, stream>>>(
      lnA, lnT, resF, a_Wg, a_bg, a_Wb, t_Wg, t_bg, t_Wb, sg_W, sg_b, t_Wc, t_bc,
      Ag, Ab, Tg, Tb, Sg, Tc);
  k_adaln16<<<dim3(Bc * Nc / 4), dim3(256), 0, stream>>>(atomF, idx, Ag, Ab,
                                                         (unsigned*)act16);
  k_gemm_qkv<<<dim3(Bc * Nc / 64, 3), dim3(256), 0, stream>>>(act16, qWt, kvWt, q_b,
                                                              q16, k16, vT);
  k_bias2<<<dim3(Bc * NWc * 2), dim3(256), 0, stream>>>(apF, bij_ln_w, bij_ln_b, bij_W,
                                                        bias16g);
  k_attn6<<<dim3(Bc * NWc * 4), dim3(64), 0, stream>>>(q16, k16, vT, bias16g, idx, Sg,
                                                       pmask, atomF, atomw);
  k_adaln16<<<dim3(Bc * Nc / 4), dim3(256), 0, stream>>>(atomw, idx, Tg, Tb,
                                                         (unsigned*)act16);
  k_gemm_mid<<<dim3(Bc * Nc / 64, 4), dim3(256), 0, stream>>>(act16, midWt, bmid16);
  k_gemm_out<<<dim3(Bc * Nc / 64), dim3(256), 0, stream>>>(bmid16, WoT, atomw, idx, Tc,
                                                           pmask, (float*)d_out);
}

// Round 13
// 222.429 us; speedup vs baseline: 1.4143x; 1.0694x over previous
//
#include <hip/hip_runtime.h>
#include <hip/hip_bf16.h>
#include <string.h>

namespace {

constexpr int Bc  = 2;
constexpr int Nc  = 16384;
constexpr int Rc  = 2048;
constexpr int CAc = 128;
constexpr int CSc = 256;
constexpr int CPc = 16;
constexpr int Hc  = 4;
constexpr int WQc = 32;
constexpr int WKc = 128;
constexpr int NWc = 512;
constexpr float EPSf     = 1e-5f;
constexpr float NEG_INF  = -1e8f;
constexpr float QK_SCALE = 0.17677669529663687f;  // 1/sqrt(32)

constexpr int VT_STRIDE = 16512;          // 64 pad + 16384 + 64 pad
constexpr int VT_BATCH  = 128 * VT_STRIDE;

typedef short bf16x8 __attribute__((ext_vector_type(8)));
typedef float f32x4 __attribute__((ext_vector_type(4)));
typedef unsigned int u32x4 __attribute__((ext_vector_type(4)));

__device__ __forceinline__ float wsum(float v) {
#pragma unroll
  for (int m = 1; m < 64; m <<= 1) v += __shfl_xor(v, m, 64);
  return v;
}
__device__ __forceinline__ float sigm(float x) { return 1.0f / (1.0f + __expf(-x)); }
__device__ __forceinline__ float f4c(const float4& v, int i) {
  return i == 0 ? v.x : i == 1 ? v.y : i == 2 ? v.z : v.w;
}
__device__ __forceinline__ unsigned short bfx(float v) {
  __hip_bfloat16 h = __float2bfloat16(v);
  unsigned short u;
  memcpy(&u, &h, 2);
  return u;
}
__device__ __forceinline__ unsigned pk2(float a, float b) {
  return (unsigned)bfx(a) | ((unsigned)bfx(b) << 16);
}
__device__ __forceinline__ float ubf(unsigned us) {
  unsigned v = us << 16;
  float f;
  memcpy(&f, &v, 4);
  return f;
}
__device__ __forceinline__ bf16x8 ldfrag(const ushort* p) {
  return __builtin_bit_cast(bf16x8, *(const u32x4*)p);
}

// ---------------- K0+K1a merged: weight pack (+vT pads) | res LN -----------
__global__ void k_pack_resln(const float* __restrict__ q_W, const float* __restrict__ kv_W,
                             const float* __restrict__ t_W1, const float* __restrict__ t_W2,
                             const float* __restrict__ t_Wo,
                             ushort* __restrict__ qWt, ushort* __restrict__ kvWt,
                             ushort* __restrict__ midWt, ushort* __restrict__ WoT,
                             ushort* __restrict__ vT,
                             const float* __restrict__ res, const float* __restrict__ a_ln_w,
                             const float* __restrict__ t_ln_w, float* __restrict__ lnA,
                             float* __restrict__ lnT) {
  if (blockIdx.x < 704) {
    const int i = blockIdx.x * 256 + threadIdx.x;
    if (i < 16384) {
      const int n = i >> 7, k = i & 127;
      qWt[i] = bfx(q_W[k * 128 + n]);
    } else if (i < 49152) {
      const int i2 = i - 16384;
      const int n = i2 >> 7, k = i2 & 127;
      kvWt[i2] = bfx(kv_W[k * 256 + n]);
    } else if (i < 114688) {
      const int i3 = i - 49152;
      const int n = i3 >> 7, k = i3 & 127;
      midWt[i3] = bfx(n < 256 ? t_W1[k * 256 + n] : t_W2[k * 256 + (n - 256)]);
    } else if (i < 147456) {
      const int i4 = i - 114688;
      const int n = i4 >> 8, k = i4 & 255;
      WoT[i4] = bfx(t_Wo[k * 128 + n]);
    } else if (i < 180224) {
      const int j = i - 147456;           // vT edge pads -> 0
      const int b = j >> 14, rem = j & 16383;
      const int d = rem >> 7, p = rem & 127;
      const int col = (p < 64) ? p : (16384 + p);
      vT[(size_t)b * VT_BATCH + (size_t)d * VT_STRIDE + col] = 0;
    }
  } else {
    const int wid = threadIdx.x >> 6, lane = threadIdx.x & 63;
    const int row = (blockIdx.x - 704) * 4 + wid;  // B*R rows
    const float* r = res + (size_t)row * CSc;
    float x[4], s = 0.f, sq = 0.f;
#pragma unroll
    for (int i = 0; i < 4; ++i) { x[i] = r[lane + 64 * i]; s += x[i]; sq += x[i] * x[i]; }
    s = wsum(s); sq = wsum(sq);
    const float mn = s * (1.0f / CSc);
    const float var = sq * (1.0f / CSc) - mn * mn;
    const float rs = rsqrtf(var + EPSf);
#pragma unroll
    for (int i = 0; i < 4; ++i) {
      const int c = lane + 64 * i;
      const float y = (x[i] - mn) * rs;
      lnA[(size_t)row * CSc + c] = y * a_ln_w[c];
      lnT[(size_t)row * CSc + c] = y * t_ln_w[c];
    }
  }
}

// ---------------- K1b: 6 res GEMMs (K=256 -> 128 cols), gates sigmoid'd ----
__global__ void k_res_gemm(const float* __restrict__ lnA, const float* __restrict__ lnT,
                           const float* __restrict__ res,
                           const float* __restrict__ a_Wg, const float* __restrict__ a_bg,
                           const float* __restrict__ a_Wb,
                           const float* __restrict__ t_Wg, const float* __restrict__ t_bg,
                           const float* __restrict__ t_Wb,
                           const float* __restrict__ sg_W, const float* __restrict__ sg_b,
                           const float* __restrict__ t_Wc, const float* __restrict__ t_bc,
                           float* __restrict__ Ag, float* __restrict__ Ab,
                           float* __restrict__ Tg, float* __restrict__ Tb,
                           float* __restrict__ Sg, float* __restrict__ Tc) {
  __shared__ float tile[32 * CSc];
  const int m = blockIdx.y;
  const float* in = (m < 2) ? lnA : (m < 4) ? lnT : res;
  const float* W  = (m == 0) ? a_Wg : (m == 1) ? a_Wb : (m == 2) ? t_Wg
                  : (m == 3) ? t_Wb : (m == 4) ? sg_W : t_Wc;
  const float* bias = (m == 0) ? a_bg : (m == 2) ? t_bg : (m == 4) ? sg_b
                    : (m == 5) ? t_bc : nullptr;
  const bool sig = (m == 0) || (m == 2) || (m == 4) || (m == 5);
  float* out = (m == 0) ? Ag : (m == 1) ? Ab : (m == 2) ? Tg
             : (m == 3) ? Tb : (m == 4) ? Sg : Tc;
  const int row0 = blockIdx.x * 32;
  const float4* src = (const float4*)(in + (size_t)row0 * CSc);
  float4* dst = (float4*)tile;
#pragma unroll
  for (int k = 0; k < 8; ++k) dst[threadIdx.x + 256 * k] = src[threadIdx.x + 256 * k];
  __syncthreads();
  const int c0 = (threadIdx.x & 31) * 4;
  const int r0 = (threadIdx.x >> 5) * 4;
  float acc[4][4] = {};
  for (int j = 0; j < CSc; j += 4) {
    float4 a[4];
#pragma unroll
    for (int r = 0; r < 4; ++r) a[r] = *(const float4*)&tile[(r0 + r) * CSc + j];
#pragma unroll
    for (int jj = 0; jj < 4; ++jj) {
      const float4 w = *(const float4*)&W[(size_t)(j + jj) * CAc + c0];
#pragma unroll
      for (int r = 0; r < 4; ++r) {
        const float av = f4c(a[r], jj);
        acc[r][0] += av * w.x; acc[r][1] += av * w.y;
        acc[r][2] += av * w.z; acc[r][3] += av * w.w;
      }
    }
  }
  float4 bv = make_float4(0.f, 0.f, 0.f, 0.f);
  if (bias) bv = *(const float4*)&bias[c0];
#pragma unroll
  for (int r = 0; r < 4; ++r) {
    float4 o;
    o.x = acc[r][0] + bv.x; o.y = acc[r][1] + bv.y;
    o.z = acc[r][2] + bv.z; o.w = acc[r][3] + bv.w;
    if (sig) { o.x = sigm(o.x); o.y = sigm(o.y); o.z = sigm(o.z); o.w = sigm(o.w); }
    *(float4*)&out[(size_t)(row0 + r0 + r) * CAc + c0] = o;
  }
}

// ---------------- K2/K5: adaLN over atoms -> bf16 out ----------------------
__global__ void k_adaln16(const float* __restrict__ in, const int* __restrict__ idxG,
                          const float* __restrict__ G, const float* __restrict__ Bb,
                          unsigned* __restrict__ out32) {
  const int wid = threadIdx.x >> 6, lane = threadIdx.x & 63;
  const int row = blockIdx.x * 4 + wid;  // B*N rows
  const int b = row >> 14;
  const float* r = in + (size_t)row * CAc;
  const float2 xp = *(const float2*)&r[2 * lane];
  const float s = wsum(xp.x + xp.y);
  const float sq = wsum(xp.x * xp.x + xp.y * xp.y);
  const float mn = s * (1.0f / CAc);
  const float var = sq * (1.0f / CAc) - mn * mn;
  const float rs = rsqrtf(var + EPSf);
  const int base = (b * Rc + idxG[row]) * CAc;
  const float2 g2 = *(const float2*)&G[base + 2 * lane];
  const float2 b2 = *(const float2*)&Bb[base + 2 * lane];
  const float y0 = (xp.x - mn) * rs * g2.x + b2.x;
  const float y1 = (xp.y - mn) * rs * g2.y + b2.y;
  out32[(size_t)row * 64 + lane] = pk2(y0, y1);
}

// ---------------- K3+K4a merged: bias (blocks 0..2047) | qkv GEMM ----------
// bias blocks dispatched first: the 268 MB apF stream starts immediately and
// qkv's MFMA blocks fill in behind it.
__global__ __launch_bounds__(256) void k_qkv_bias(
    const ushort* __restrict__ act16, const ushort* __restrict__ qWt,
    const ushort* __restrict__ kvWt, const float* __restrict__ q_b,
    ushort* __restrict__ q16, ushort* __restrict__ k16, ushort* __restrict__ vT,
    const float* __restrict__ ap, const float* __restrict__ bw,
    const float* __restrict__ bb, const float* __restrict__ bW,
    ushort* __restrict__ bias16g) {
  __shared__ ushort smem[9216];        // union: biasL[8192] | vtile[128][72]
  __shared__ float w2s[64], W2sh[4], Cbh[4];
  const int tid = threadIdx.x;
  if (blockIdx.x < 2048) {
    // ---- bias path (k_bias2, folded LN, capped unroll) ----
    ushort* biasL = smem;
    const int bwid = blockIdx.x >> 1;
    const int half = blockIdx.x & 1;
    const int w = bwid & 511;
    if (tid < 64) w2s[tid] = bw[tid >> 2] * bW[tid];
    __syncthreads();
    if (tid < 4) {
      float a = 0.f, b2 = 0.f;
#pragma unroll
      for (int cp = 0; cp < 16; ++cp) { a += w2s[cp * 4 + tid]; b2 += bb[cp] * bW[cp * 4 + tid]; }
      W2sh[tid] = a; Cbh[tid] = b2;
    }
    __syncthreads();

    const float* apw = ap + (size_t)bwid * (WQc * WKc * CPc) + (size_t)half * (16 * 128 * CPc);
#pragma unroll 2
    for (int u = 0; u < 8; ++u) {
      const int p = tid + 256 * u;         // 2048 pairs (16 q x 128 k)
      const int qql = p >> 7, kk = p & 127;
      const float* src = apw + (size_t)p * CPc;
      float sum = 0.f, sq = 0.f, d0 = 0.f, d1 = 0.f, d2 = 0.f, d3 = 0.f;
#pragma unroll
      for (int t = 0; t < 4; ++t) {
        const float4 v4 = *(const float4*)&src[t * 4];
#pragma unroll
        for (int e = 0; e < 4; ++e) {
          const float x = f4c(v4, e);
          const float4 wv = *(const float4*)&w2s[(4 * t + e) * 4];
          sum += x; sq += x * x;
          d0 += x * wv.x; d1 += x * wv.y; d2 += x * wv.z; d3 += x * wv.w;
        }
      }
      const float mn = sum * 0.0625f;
      const float var = sq * 0.0625f - mn * mn;
      const float rs = rsqrtf(var + EPSf);
      const int gk = w * 32 - 48 + kk;
      const float maskt = (gk >= 0 && gk < Nc) ? 0.f : NEG_INF;
      const int mt = kk >> 4, s_ = (kk >> 2) & 3, r_ = kk & 3;
      const int col = s_ * 16 + (qql ^ ((mt & 3) << 2) ^ s_);
      const int base = mt * 256 + col * 4 + r_;
      biasL[base]        = bfx(rs * (d0 - mn * W2sh[0]) + Cbh[0] + maskt);
      biasL[base + 2048] = bfx(rs * (d1 - mn * W2sh[1]) + Cbh[1] + maskt);
      biasL[base + 4096] = bfx(rs * (d2 - mn * W2sh[2]) + Cbh[2] + maskt);
      biasL[base + 6144] = bfx(rs * (d3 - mn * W2sh[3]) + Cbh[3] + maskt);
    }
    __syncthreads();
    uint4* dw = (uint4*)(bias16g + (size_t)bwid * 16384);
    const uint4* sl = (const uint4*)biasL;
#pragma unroll
    for (int u = 0; u < 4; ++u) {
      const int idx = tid + 256 * u;       // 1024 uint4
      const int chunk = idx >> 5, within = idx & 31;
      const int h = chunk >> 3, mt = chunk & 7;
      dw[h * 512 + (mt * 2 + half) * 32 + within] = sl[idx];
    }
  } else {
    // ---- qkv path (k_gemm_qkv) ----
    ushort (*vtile)[72] = (ushort(*)[72])smem;
    const int idx = blockIdx.x - 2048;
    const int ny = idx >> 9;             // 0: q, 1: K, 2: V
    const int bx = idx & 511;
    const int wid = tid >> 6, lane = tid & 63;
    const int c = lane & 15, s = lane >> 4;
    const int wm = wid & 1, wn = wid >> 1;
    const int base = bx * 64;
    const int m0 = base + wm * 32;
    const int nb = wn * 64;
    const ushort* Wt = (ny == 0) ? qWt : kvWt + (ny == 2 ? 128 * 128 : 0);
    f32x4 acc[4][2];
#pragma unroll
    for (int nt = 0; nt < 4; ++nt)
#pragma unroll
      for (int mt = 0; mt < 2; ++mt) { acc[nt][mt][0]=0.f; acc[nt][mt][1]=0.f; acc[nt][mt][2]=0.f; acc[nt][mt][3]=0.f; }
#pragma unroll
    for (int kk = 0; kk < 4; ++kk) {
      const int k0 = kk * 32 + 8 * s;
      bf16x8 bA[2];
#pragma unroll
      for (int mt = 0; mt < 2; ++mt)
        bA[mt] = ldfrag(&act16[(size_t)(m0 + mt * 16 + c) * 128 + k0]);
#pragma unroll
      for (int nt = 0; nt < 4; ++nt) {
        const bf16x8 aW = ldfrag(&Wt[(size_t)(nb + nt * 16 + c) * 128 + k0]);
#pragma unroll
        for (int mt = 0; mt < 2; ++mt)
          acc[nt][mt] = __builtin_amdgcn_mfma_f32_16x16x32_bf16(aW, bA[mt], acc[nt][mt], 0, 0, 0);
      }
    }
#pragma unroll
    for (int nt = 0; nt < 4; ++nt) {
      const int colb = nb + nt * 16 + 4 * s;
      float4 qb4 = make_float4(0.f, 0.f, 0.f, 0.f);
      if (ny == 0) qb4 = *(const float4*)&q_b[colb];
#pragma unroll
      for (int mt = 0; mt < 2; ++mt) {
        const int m = m0 + mt * 16 + c;
        const f32x4 a = acc[nt][mt];
        if (ny == 0) {
          ushort4 u4;
          u4.x = bfx((a[0] + qb4.x) * QK_SCALE); u4.y = bfx((a[1] + qb4.y) * QK_SCALE);
          u4.z = bfx((a[2] + qb4.z) * QK_SCALE); u4.w = bfx((a[3] + qb4.w) * QK_SCALE);
          *(ushort4*)&q16[(size_t)m * 128 + colb] = u4;
        } else if (ny == 1) {
          ushort4 u4;
          u4.x = bfx(a[0]); u4.y = bfx(a[1]); u4.z = bfx(a[2]); u4.w = bfx(a[3]);
          *(ushort4*)&k16[(size_t)m * 128 + colb] = u4;
        } else {
          const int rowl = wm * 32 + mt * 16 + c;
#pragma unroll
          for (int r = 0; r < 4; ++r)
            vtile[colb + r][rowl] = bfx(a[r]);
        }
      }
    }
    if (ny == 2) {
      __syncthreads();
      const int bb2 = base >> 14, nn0 = base & 16383;
      const int d = tid >> 1, half = tid & 1;
      ushort* dst = vT + (size_t)bb2 * VT_BATCH + (size_t)d * VT_STRIDE + 64 + nn0 + half * 32;
      const ushort* srcl = &vtile[d][half * 32];
#pragma unroll
      for (int u = 0; u < 4; ++u)
        *(uint4*)(dst + u * 8) = *(const uint4*)(srcl + u * 8);
    }
  }
}

// ---------------- K6: transition mid GEMM (W1||W2 paired, silu-mul) --------
__global__ __launch_bounds__(256) void k_gemm_mid(
    const ushort* __restrict__ act16, const ushort* __restrict__ midWt,
    ushort* __restrict__ bmid16) {
  const int wid = threadIdx.x >> 6, lane = threadIdx.x & 63;
  const int c = lane & 15, s = lane >> 4;
  const int wm = wid & 1, wn = wid >> 1;
  const int m0 = blockIdx.x * 64 + wm * 32;
  const int nb = blockIdx.y * 64 + wn * 32;
  f32x4 acc1[2][2], acc2[2][2];
#pragma unroll
  for (int nt = 0; nt < 2; ++nt)
#pragma unroll
    for (int mt = 0; mt < 2; ++mt) {
      acc1[nt][mt][0]=0.f; acc1[nt][mt][1]=0.f; acc1[nt][mt][2]=0.f; acc1[nt][mt][3]=0.f;
      acc2[nt][mt][0]=0.f; acc2[nt][mt][1]=0.f; acc2[nt][mt][2]=0.f; acc2[nt][mt][3]=0.f;
    }
#pragma unroll
  for (int kk = 0; kk < 4; ++kk) {
    const int k0 = kk * 32 + 8 * s;
    bf16x8 bA[2];
#pragma unroll
    for (int mt = 0; mt < 2; ++mt)
      bA[mt] = ldfrag(&act16[(size_t)(m0 + mt * 16 + c) * 128 + k0]);
#pragma unroll
    for (int nt = 0; nt < 2; ++nt) {
      const bf16x8 aW1 = ldfrag(&midWt[(size_t)(nb + nt * 16 + c) * 128 + k0]);
      const bf16x8 aW2 = ldfrag(&midWt[(size_t)(256 + nb + nt * 16 + c) * 128 + k0]);
#pragma unroll
      for (int mt = 0; mt < 2; ++mt) {
        acc1[nt][mt] = __builtin_amdgcn_mfma_f32_16x16x32_bf16(aW1, bA[mt], acc1[nt][mt], 0, 0, 0);
        acc2[nt][mt] = __builtin_amdgcn_mfma_f32_16x16x32_bf16(aW2, bA[mt], acc2[nt][mt], 0, 0, 0);
      }
    }
  }
#pragma unroll
  for (int nt = 0; nt < 2; ++nt) {
    const int colb = nb + nt * 16 + 4 * s;
#pragma unroll
    for (int mt = 0; mt < 2; ++mt) {
      const int m = m0 + mt * 16 + c;
      ushort4 u4;
#pragma unroll
      for (int r = 0; r < 4; ++r) {
        const float a1 = acc1[nt][mt][r];
        const float v = a1 * sigm(a1) * acc2[nt][mt][r];
        ((unsigned short*)&u4)[r] = bfx(v);
      }
      *(ushort4*)&bmid16[(size_t)m * 256 + colb] = u4;
    }
  }
}

// ---------------- K7: out GEMM (K=256) + gated residual --------------------
__global__ __launch_bounds__(256) void k_gemm_out(
    const ushort* __restrict__ bmid16, const ushort* __restrict__ WoT,
    const float* __restrict__ atomw, const int* __restrict__ idxG,
    const float* __restrict__ TcG, const float* __restrict__ pmask,
    float* __restrict__ outG) {
  const int wid = threadIdx.x >> 6, lane = threadIdx.x & 63;
  const int c = lane & 15, s = lane >> 4;
  const int wm = wid & 1, wn = wid >> 1;
  const int m0 = blockIdx.x * 64 + wm * 32;
  const int nb = wn * 64;
  f32x4 acc[4][2];
#pragma unroll
  for (int nt = 0; nt < 4; ++nt)
#pragma unroll
    for (int mt = 0; mt < 2; ++mt) { acc[nt][mt][0]=0.f; acc[nt][mt][1]=0.f; acc[nt][mt][2]=0.f; acc[nt][mt][3]=0.f; }
#pragma unroll
  for (int kk = 0; kk < 8; ++kk) {
    const int k0 = kk * 32 + 8 * s;
    bf16x8 bA[2];
#pragma unroll
    for (int mt = 0; mt < 2; ++mt)
      bA[mt] = ldfrag(&bmid16[(size_t)(m0 + mt * 16 + c) * 256 + k0]);
#pragma unroll
    for (int nt = 0; nt < 4; ++nt) {
      const bf16x8 aW = ldfrag(&WoT[(size_t)(nb + nt * 16 + c) * 256 + k0]);
#pragma unroll
      for (int mt = 0; mt < 2; ++mt)
        acc[nt][mt] = __builtin_amdgcn_mfma_f32_16x16x32_bf16(aW, bA[mt], acc[nt][mt], 0, 0, 0);
    }
  }
#pragma unroll
  for (int mt = 0; mt < 2; ++mt) {
    const int m = m0 + mt * 16 + c;
    const int b = m >> 14;
    const int idx = idxG[m];
    const float pm = pmask[m];
    const size_t tcb = ((size_t)(b * Rc) + idx) * CAc;
#pragma unroll
    for (int nt = 0; nt < 4; ++nt) {
      const int colb = nb + nt * 16 + 4 * s;
      const float4 tc = *(const float4*)&TcG[tcb + colb];
      const float4 at = *(const float4*)&atomw[(size_t)m * CAc + colb];
      float4 o;
      o.x = at.x + tc.x * acc[nt][mt][0] * pm;
      o.y = at.y + tc.y * acc[nt][mt][1] * pm;
      o.z = at.z + tc.z * acc[nt][mt][2] * pm;
      o.w = at.w + tc.w * acc[nt][mt][3] * pm;
      *(float4*)&outG[(size_t)m * CAc + colb] = o;
    }
  }
}

// ---------------- K4b: MFMA windowed attention, wave-per-block, no LDS -----
__global__ __launch_bounds__(64) void k_attn6(
    const ushort* __restrict__ qG, const ushort* __restrict__ kG,
    const ushort* __restrict__ vT, const ushort* __restrict__ bias16g,
    const int* __restrict__ idxG, const float* __restrict__ SgG,
    const float* __restrict__ pmask, const float* __restrict__ atomF,
    float* __restrict__ atomO) {
  const int bwid = blockIdx.x >> 2;
  const int h = blockIdx.x & 3;
  const int lane = threadIdx.x;
  const int c = lane & 15, s = lane >> 4;
  const int b = bwid >> 9, w = bwid & 511;
  const size_t bN = (size_t)b * Nc;

  f32x4 acc[8][2];
  {
    const ushort* bh = bias16g + (size_t)bwid * 16384 + h * 4096;
#pragma unroll
    for (int mt = 0; mt < 8; ++mt) {
      const int col = s * 16 + (c ^ ((mt & 3) << 2) ^ s);
#pragma unroll
      for (int ntq = 0; ntq < 2; ++ntq) {
        const uint2 pk = *(const uint2*)&bh[((mt * 2 + ntq) << 8) + col * 4];
        acc[mt][ntq][0] = ubf(pk.x & 0xffff);
        acc[mt][ntq][1] = ubf(pk.x >> 16);
        acc[mt][ntq][2] = ubf(pk.y & 0xffff);
        acc[mt][ntq][3] = ubf(pk.y >> 16);
      }
    }
  }

  bf16x8 bfragQ[2];
#pragma unroll
  for (int ntq = 0; ntq < 2; ++ntq) {
    const int qq = w * 32 + ntq * 16 + c;
    bfragQ[ntq] = ldfrag(&qG[(bN + qq) * CAc + h * 32 + 8 * s]);
  }
#pragma unroll
  for (int mt = 0; mt < 8; ++mt) {
    int gk = w * 32 - 48 + mt * 16 + c;
    gk = min(max(gk, 0), Nc - 1);
    const bf16x8 afragK = ldfrag(&kG[(bN + gk) * CAc + h * 32 + 8 * s]);
#pragma unroll
    for (int ntq = 0; ntq < 2; ++ntq)
      acc[mt][ntq] = __builtin_amdgcn_mfma_f32_16x16x32_bf16(afragK, bfragQ[ntq],
                                                             acc[mt][ntq], 0, 0, 0);
  }

  int ppk[8][2][2];
#pragma unroll
  for (int ntq = 0; ntq < 2; ++ntq) {
    float mx = -3e38f;
#pragma unroll
    for (int mt = 0; mt < 8; ++mt)
#pragma unroll
      for (int r = 0; r < 4; ++r) mx = fmaxf(mx, acc[mt][ntq][r]);
    mx = fmaxf(mx, __shfl_xor(mx, 16, 64));
    mx = fmaxf(mx, __shfl_xor(mx, 32, 64));
    float sm = 0.f;
#pragma unroll
    for (int mt = 0; mt < 8; ++mt)
#pragma unroll
      for (int r = 0; r < 4; ++r) {
        const float e = __expf(acc[mt][ntq][r] - mx);
        acc[mt][ntq][r] = e;
        sm += e;
      }
    sm += __shfl_xor(sm, 16, 64);
    sm += __shfl_xor(sm, 32, 64);
    const float inv = 1.0f / sm;
#pragma unroll
    for (int mt = 0; mt < 8; ++mt) {
      ppk[mt][ntq][0] = (int)pk2(acc[mt][ntq][0] * inv, acc[mt][ntq][1] * inv);
      ppk[mt][ntq][1] = (int)pk2(acc[mt][ntq][2] * inv, acc[mt][ntq][3] * inv);
    }
  }

  f32x4 opv[2][2];
#pragma unroll
  for (int i = 0; i < 2; ++i)
#pragma unroll
    for (int j = 0; j < 2; ++j) { opv[i][j][0]=0.f; opv[i][j][1]=0.f; opv[i][j][2]=0.f; opv[i][j][3]=0.f; }
  const int idxA = 4 * ((((2 * s) & 3) << 4) | c);
  const int idxB = 4 * ((((2 * s + 1) & 3) << 4) | c);
  const ushort* vTb = vT + (size_t)b * VT_BATCH;
#pragma unroll
  for (int ks = 0; ks < 4; ++ks) {
    const int vbase = 64 + w * 32 - 48 + ks * 32 + 8 * s;
    bf16x8 bV[2];
#pragma unroll
    for (int ntd = 0; ntd < 2; ++ntd) {
      const int d = h * 32 + ntd * 16 + c;
      bV[ntd] = ldfrag(&vTb[(size_t)d * VT_STRIDE + vbase]);
    }
#pragma unroll
    for (int mtp = 0; mtp < 2; ++mtp) {
      int atv[4];
      {
        const int a0 = __builtin_amdgcn_ds_bpermute(idxA, ppk[2 * ks][mtp][0]);
        const int b0 = __builtin_amdgcn_ds_bpermute(idxA, ppk[2 * ks + 1][mtp][0]);
        atv[0] = (s < 2) ? a0 : b0;
        const int a1 = __builtin_amdgcn_ds_bpermute(idxA, ppk[2 * ks][mtp][1]);
        const int b1 = __builtin_amdgcn_ds_bpermute(idxA, ppk[2 * ks + 1][mtp][1]);
        atv[1] = (s < 2) ? a1 : b1;
        const int a2 = __builtin_amdgcn_ds_bpermute(idxB, ppk[2 * ks][mtp][0]);
        const int b2 = __builtin_amdgcn_ds_bpermute(idxB, ppk[2 * ks + 1][mtp][0]);
        atv[2] = (s < 2) ? a2 : b2;
        const int a3 = __builtin_amdgcn_ds_bpermute(idxB, ppk[2 * ks][mtp][1]);
        const int b3 = __builtin_amdgcn_ds_bpermute(idxB, ppk[2 * ks + 1][mtp][1]);
        atv[3] = (s < 2) ? a3 : b3;
      }
      const bf16x8 afragP = __builtin_bit_cast(bf16x8, *(const u32x4*)atv);
#pragma unroll
      for (int ntd = 0; ntd < 2; ++ntd)
        opv[mtp][ntd] = __builtin_amdgcn_mfma_f32_16x16x32_bf16(
            afragP, bV[ntd], opv[mtp][ntd], 0, 0, 0);
    }
  }

#pragma unroll
  for (int mtp = 0; mtp < 2; ++mtp) {
#pragma unroll
    for (int r = 0; r < 4; ++r) {
      const int qq = w * 32 + mtp * 16 + 4 * s + r;
      const size_t rowg = bN + qq;
      const int residx = idxG[rowg];
      const float pm = pmask[rowg];
      const size_t gbase = ((size_t)b * Rc + residx) * CAc;
#pragma unroll
      for (int ntd = 0; ntd < 2; ++ntd) {
        const int d = h * 32 + ntd * 16 + c;
        const float g = SgG[gbase + d];
        const float af = atomF[rowg * CAc + d];
        atomO[rowg * CAc + d] = af + opv[mtp][ntd][r] * g * pm;
      }
    }
  }
}

}  // namespace

extern "C" void kernel_launch(void* const* d_in, const int* in_sizes, int n_in,
                              void* d_out, int out_size, void* d_ws, size_t ws_size,
                              hipStream_t stream) {
  (void)in_sizes; (void)n_in; (void)out_size; (void)ws_size;
  const float* atomF   = (const float*)d_in[0];
  const float* resF    = (const float*)d_in[1];
  const float* apF     = (const float*)d_in[2];
  const int*   idx     = (const int*)d_in[3];
  const float* pmask   = (const float*)d_in[4];
  const float* a_ln_w  = (const float*)d_in[6];
  const float* a_Wg    = (const float*)d_in[7];
  const float* a_bg    = (const float*)d_in[8];
  const float* a_Wb    = (const float*)d_in[9];
  const float* q_W     = (const float*)d_in[10];
  const float* q_b     = (const float*)d_in[11];
  const float* kv_W    = (const float*)d_in[12];
  const float* bij_ln_w= (const float*)d_in[13];
  const float* bij_ln_b= (const float*)d_in[14];
  const float* bij_W   = (const float*)d_in[15];
  const float* sg_W    = (const float*)d_in[16];
  const float* sg_b    = (const float*)d_in[17];
  const float* t_ln_w  = (const float*)d_in[18];
  const float* t_Wg    = (const float*)d_in[19];
  const float* t_bg    = (const float*)d_in[20];
  const float* t_Wb    = (const float*)d_in[21];
  const float* t_W1    = (const float*)d_in[22];
  const float* t_W2    = (const float*)d_in[23];
  const float* t_Wc    = (const float*)d_in[24];
  const float* t_bc    = (const float*)d_in[25];
  const float* t_Wo    = (const float*)d_in[26];

  float* ws = (float*)d_ws;
  float* Ag    = ws;                          // 6 x 524288
  float* Ab    = Ag + 524288;
  float* Tg    = Ab + 524288;
  float* Tb    = Tg + 524288;
  float* Sg    = Tb + 524288;
  float* Tc    = Sg + 524288;
  float* lnA   = Tc + 524288;                 // 1048576
  float* lnT   = lnA + 1048576;               // 1048576
  ushort* act16  = (ushort*)(lnT + 1048576);  // 4194304 ushorts (s, then t)
  ushort* q16    = act16 + 4194304;           // 4194304 ushorts
  ushort* k16    = q16 + 4194304;             // 4194304 ushorts
  ushort* bias16g= k16 + 4194304;             // 16777216 ushorts
  ushort* bmid16 = bias16g + 16777216;        // 8388608 ushorts
  float* atomw   = (float*)(bmid16 + 8388608);// 4194304 floats
  ushort* qWt    = (ushort*)(atomw + 4194304);// 16384
  ushort* kvWt   = qWt + 16384;               // 32768
  ushort* midWt  = kvWt + 32768;              // 65536
  ushort* WoT    = midWt + 65536;             // 32768
  ushort* vT     = WoT + 32768;               // 2 x 128 x 16512 = 4227072 ushorts

  k_pack_resln<<<dim3(1728), dim3(256), 0, stream>>>(
      q_W, kv_W, t_W1, t_W2, t_Wo, qWt, kvWt, midWt, WoT, vT,
      resF, a_ln_w, t_ln_w, lnA, lnT);
  k_res_gemm<<<dim3(Bc * Rc / 32, 6), dim3(256), 0, stream>>>(
      lnA, lnT, resF, a_Wg, a_bg, a_Wb, t_Wg, t_bg, t_Wb, sg_W, sg_b, t_Wc, t_bc,
      Ag, Ab, Tg, Tb, Sg, Tc);
  k_adaln16<<<dim3(Bc * Nc / 4), dim3(256), 0, stream>>>(atomF, idx, Ag, Ab,
                                                         (unsigned*)act16);
  k_qkv_bias<<<dim3(2048 + 1536), dim3(256), 0, stream>>>(
      act16, qWt, kvWt, q_b, q16, k16, vT,
      apF, bij_ln_w, bij_ln_b, bij_W, bias16g);
  k_attn6<<<dim3(Bc * NWc * 4), dim3(64), 0, stream>>>(q16, k16, vT, bias16g, idx, Sg,
                                                       pmask, atomF, atomw);
  k_adaln16<<<dim3(Bc * Nc / 4), dim3(256), 0, stream>>>(atomw, idx, Tg, Tb,
                                                         (unsigned*)act16);
  k_gemm_mid<<<dim3(Bc * Nc / 64, 4), dim3(256), 0, stream>>>(act16, midWt, bmid16);
  k_gemm_out<<<dim3(Bc * Nc / 64), dim3(256), 0, stream>>>(bmid16, WoT, atomw, idx, Tc,
                                                           pmask, (float*)d_out);
}

// Round 14
// 218.200 us; speedup vs baseline: 1.4417x; 1.0194x over previous
//
#include <hip/hip_runtime.h>
#include <hip/hip_bf16.h>
#include <string.h>

namespace {

constexpr int Bc  = 2;
constexpr int Nc  = 16384;
constexpr int Rc  = 2048;
constexpr int CAc = 128;
constexpr int CSc = 256;
constexpr int CPc = 16;
constexpr int Hc  = 4;
constexpr int WQc = 32;
constexpr int WKc = 128;
constexpr int NWc = 512;
constexpr float EPSf     = 1e-5f;
constexpr float NEG_INF  = -1e8f;
constexpr float QK_SCALE = 0.17677669529663687f;  // 1/sqrt(32)

constexpr int VT_STRIDE = 16512;          // 64 pad + 16384 + 64 pad
constexpr int VT_BATCH  = 128 * VT_STRIDE;

typedef short bf16x8 __attribute__((ext_vector_type(8)));
typedef float f32x4 __attribute__((ext_vector_type(4)));
typedef unsigned int u32x4 __attribute__((ext_vector_type(4)));

__device__ __forceinline__ float wsum(float v) {
#pragma unroll
  for (int m = 1; m < 64; m <<= 1) v += __shfl_xor(v, m, 64);
  return v;
}
__device__ __forceinline__ float sigm(float x) { return 1.0f / (1.0f + __expf(-x)); }
__device__ __forceinline__ float f4c(const float4& v, int i) {
  return i == 0 ? v.x : i == 1 ? v.y : i == 2 ? v.z : v.w;
}
__device__ __forceinline__ unsigned short bfx(float v) {
  __hip_bfloat16 h = __float2bfloat16(v);
  unsigned short u;
  memcpy(&u, &h, 2);
  return u;
}
__device__ __forceinline__ unsigned pk2(float a, float b) {
  return (unsigned)bfx(a) | ((unsigned)bfx(b) << 16);
}
__device__ __forceinline__ float ubf(unsigned us) {
  unsigned v = us << 16;
  float f;
  memcpy(&f, &v, 4);
  return f;
}
__device__ __forceinline__ bf16x8 ldfrag(const ushort* p) {
  return __builtin_bit_cast(bf16x8, *(const u32x4*)p);
}

// ---------------- K0+K1a merged: weight pack (+vT pads) | res LN -----------
__global__ void k_pack_resln(const float* __restrict__ q_W, const float* __restrict__ kv_W,
                             const float* __restrict__ t_W1, const float* __restrict__ t_W2,
                             const float* __restrict__ t_Wo,
                             ushort* __restrict__ qWt, ushort* __restrict__ kvWt,
                             ushort* __restrict__ midWt, ushort* __restrict__ WoT,
                             ushort* __restrict__ vT,
                             const float* __restrict__ res, const float* __restrict__ a_ln_w,
                             const float* __restrict__ t_ln_w, float* __restrict__ lnA,
                             float* __restrict__ lnT) {
  if (blockIdx.x < 704) {
    const int i = blockIdx.x * 256 + threadIdx.x;
    if (i < 16384) {
      const int n = i >> 7, k = i & 127;
      qWt[i] = bfx(q_W[k * 128 + n]);
    } else if (i < 49152) {
      const int i2 = i - 16384;
      const int n = i2 >> 7, k = i2 & 127;
      kvWt[i2] = bfx(kv_W[k * 256 + n]);
    } else if (i < 114688) {
      const int i3 = i - 49152;
      const int n = i3 >> 7, k = i3 & 127;
      midWt[i3] = bfx(n < 256 ? t_W1[k * 256 + n] : t_W2[k * 256 + (n - 256)]);
    } else if (i < 147456) {
      const int i4 = i - 114688;
      const int n = i4 >> 8, k = i4 & 255;
      WoT[i4] = bfx(t_Wo[k * 128 + n]);
    } else if (i < 180224) {
      const int j = i - 147456;           // vT edge pads -> 0
      const int b = j >> 14, rem = j & 16383;
      const int d = rem >> 7, p = rem & 127;
      const int col = (p < 64) ? p : (16384 + p);
      vT[(size_t)b * VT_BATCH + (size_t)d * VT_STRIDE + col] = 0;
    }
  } else {
    const int wid = threadIdx.x >> 6, lane = threadIdx.x & 63;
    const int row = (blockIdx.x - 704) * 4 + wid;  // B*R rows
    const float* r = res + (size_t)row * CSc;
    float x[4], s = 0.f, sq = 0.f;
#pragma unroll
    for (int i = 0; i < 4; ++i) { x[i] = r[lane + 64 * i]; s += x[i]; sq += x[i] * x[i]; }
    s = wsum(s); sq = wsum(sq);
    const float mn = s * (1.0f / CSc);
    const float var = sq * (1.0f / CSc) - mn * mn;
    const float rs = rsqrtf(var + EPSf);
#pragma unroll
    for (int i = 0; i < 4; ++i) {
      const int c = lane + 64 * i;
      const float y = (x[i] - mn) * rs;
      lnA[(size_t)row * CSc + c] = y * a_ln_w[c];
      lnT[(size_t)row * CSc + c] = y * t_ln_w[c];
    }
  }
}

// ---------------- K1b: 6 res GEMMs (K=256 -> 128 cols), gates sigmoid'd ----
__global__ void k_res_gemm(const float* __restrict__ lnA, const float* __restrict__ lnT,
                           const float* __restrict__ res,
                           const float* __restrict__ a_Wg, const float* __restrict__ a_bg,
                           const float* __restrict__ a_Wb,
                           const float* __restrict__ t_Wg, const float* __restrict__ t_bg,
                           const float* __restrict__ t_Wb,
                           const float* __restrict__ sg_W, const float* __restrict__ sg_b,
                           const float* __restrict__ t_Wc, const float* __restrict__ t_bc,
                           float* __restrict__ Ag, float* __restrict__ Ab,
                           float* __restrict__ Tg, float* __restrict__ Tb,
                           float* __restrict__ Sg, float* __restrict__ Tc) {
  __shared__ float tile[32 * CSc];
  const int m = blockIdx.y;
  const float* in = (m < 2) ? lnA : (m < 4) ? lnT : res;
  const float* W  = (m == 0) ? a_Wg : (m == 1) ? a_Wb : (m == 2) ? t_Wg
                  : (m == 3) ? t_Wb : (m == 4) ? sg_W : t_Wc;
  const float* bias = (m == 0) ? a_bg : (m == 2) ? t_bg : (m == 4) ? sg_b
                    : (m == 5) ? t_bc : nullptr;
  const bool sig = (m == 0) || (m == 2) || (m == 4) || (m == 5);
  float* out = (m == 0) ? Ag : (m == 1) ? Ab : (m == 2) ? Tg
             : (m == 3) ? Tb : (m == 4) ? Sg : Tc;
  const int row0 = blockIdx.x * 32;
  const float4* src = (const float4*)(in + (size_t)row0 * CSc);
  float4* dst = (float4*)tile;
#pragma unroll
  for (int k = 0; k < 8; ++k) dst[threadIdx.x + 256 * k] = src[threadIdx.x + 256 * k];
  __syncthreads();
  const int c0 = (threadIdx.x & 31) * 4;
  const int r0 = (threadIdx.x >> 5) * 4;
  float acc[4][4] = {};
  for (int j = 0; j < CSc; j += 4) {
    float4 a[4];
#pragma unroll
    for (int r = 0; r < 4; ++r) a[r] = *(const float4*)&tile[(r0 + r) * CSc + j];
#pragma unroll
    for (int jj = 0; jj < 4; ++jj) {
      const float4 w = *(const float4*)&W[(size_t)(j + jj) * CAc + c0];
#pragma unroll
      for (int r = 0; r < 4; ++r) {
        const float av = f4c(a[r], jj);
        acc[r][0] += av * w.x; acc[r][1] += av * w.y;
        acc[r][2] += av * w.z; acc[r][3] += av * w.w;
      }
    }
  }
  float4 bv = make_float4(0.f, 0.f, 0.f, 0.f);
  if (bias) bv = *(const float4*)&bias[c0];
#pragma unroll
  for (int r = 0; r < 4; ++r) {
    float4 o;
    o.x = acc[r][0] + bv.x; o.y = acc[r][1] + bv.y;
    o.z = acc[r][2] + bv.z; o.w = acc[r][3] + bv.w;
    if (sig) { o.x = sigm(o.x); o.y = sigm(o.y); o.z = sigm(o.z); o.w = sigm(o.w); }
    *(float4*)&out[(size_t)(row0 + r0 + r) * CAc + c0] = o;
  }
}

// ---------------- K2/K5: adaLN over atoms -> bf16 out ----------------------
__global__ void k_adaln16(const float* __restrict__ in, const int* __restrict__ idxG,
                          const float* __restrict__ G, const float* __restrict__ Bb,
                          unsigned* __restrict__ out32) {
  const int wid = threadIdx.x >> 6, lane = threadIdx.x & 63;
  const int row = blockIdx.x * 4 + wid;  // B*N rows
  const int b = row >> 14;
  const float* r = in + (size_t)row * CAc;
  const float2 xp = *(const float2*)&r[2 * lane];
  const float s = wsum(xp.x + xp.y);
  const float sq = wsum(xp.x * xp.x + xp.y * xp.y);
  const float mn = s * (1.0f / CAc);
  const float var = sq * (1.0f / CAc) - mn * mn;
  const float rs = rsqrtf(var + EPSf);
  const int base = (b * Rc + idxG[row]) * CAc;
  const float2 g2 = *(const float2*)&G[base + 2 * lane];
  const float2 b2 = *(const float2*)&Bb[base + 2 * lane];
  const float y0 = (xp.x - mn) * rs * g2.x + b2.x;
  const float y1 = (xp.y - mn) * rs * g2.y + b2.y;
  out32[(size_t)row * 64 + lane] = pk2(y0, y1);
}

// ---------------- K3: qkv GEMM via MFMA (M=32768, K=128) -------------------
__global__ __launch_bounds__(256) void k_gemm_qkv(
    const ushort* __restrict__ act16, const ushort* __restrict__ qWt,
    const ushort* __restrict__ kvWt, const float* __restrict__ q_b,
    ushort* __restrict__ q16, ushort* __restrict__ k16, ushort* __restrict__ vT) {
  __shared__ ushort vtile[128][72];  // 18.4 KB; stride 144B keeps b128 aligned
  const int ny = blockIdx.y;
  const int wid = threadIdx.x >> 6, lane = threadIdx.x & 63;
  const int c = lane & 15, s = lane >> 4;
  const int wm = wid & 1, wn = wid >> 1;
  const int base = blockIdx.x * 64;
  const int m0 = base + wm * 32;
  const int nb = wn * 64;
  const ushort* Wt = (ny == 0) ? qWt : kvWt + (ny == 2 ? 128 * 128 : 0);
  f32x4 acc[4][2];
#pragma unroll
  for (int nt = 0; nt < 4; ++nt)
#pragma unroll
    for (int mt = 0; mt < 2; ++mt) { acc[nt][mt][0]=0.f; acc[nt][mt][1]=0.f; acc[nt][mt][2]=0.f; acc[nt][mt][3]=0.f; }
#pragma unroll
  for (int kk = 0; kk < 4; ++kk) {
    const int k0 = kk * 32 + 8 * s;
    bf16x8 bA[2];
#pragma unroll
    for (int mt = 0; mt < 2; ++mt)
      bA[mt] = ldfrag(&act16[(size_t)(m0 + mt * 16 + c) * 128 + k0]);
#pragma unroll
    for (int nt = 0; nt < 4; ++nt) {
      const bf16x8 aW = ldfrag(&Wt[(size_t)(nb + nt * 16 + c) * 128 + k0]);
#pragma unroll
      for (int mt = 0; mt < 2; ++mt)
        acc[nt][mt] = __builtin_amdgcn_mfma_f32_16x16x32_bf16(aW, bA[mt], acc[nt][mt], 0, 0, 0);
    }
  }
#pragma unroll
  for (int nt = 0; nt < 4; ++nt) {
    const int colb = nb + nt * 16 + 4 * s;
    float4 qb4 = make_float4(0.f, 0.f, 0.f, 0.f);
    if (ny == 0) qb4 = *(const float4*)&q_b[colb];
#pragma unroll
    for (int mt = 0; mt < 2; ++mt) {
      const int m = m0 + mt * 16 + c;
      const f32x4 a = acc[nt][mt];
      if (ny == 0) {
        ushort4 u4;
        u4.x = bfx((a[0] + qb4.x) * QK_SCALE); u4.y = bfx((a[1] + qb4.y) * QK_SCALE);
        u4.z = bfx((a[2] + qb4.z) * QK_SCALE); u4.w = bfx((a[3] + qb4.w) * QK_SCALE);
        *(ushort4*)&q16[(size_t)m * 128 + colb] = u4;
      } else if (ny == 1) {
        ushort4 u4;
        u4.x = bfx(a[0]); u4.y = bfx(a[1]); u4.z = bfx(a[2]); u4.w = bfx(a[3]);
        *(ushort4*)&k16[(size_t)m * 128 + colb] = u4;
      } else {
        const int rowl = wm * 32 + mt * 16 + c;
#pragma unroll
        for (int r = 0; r < 4; ++r)
          vtile[colb + r][rowl] = bfx(a[r]);
      }
    }
  }
  if (ny == 2) {
    __syncthreads();
    const int bb2 = base >> 14, nn0 = base & 16383;
    const int t = threadIdx.x;
    const int d = t >> 1, half = t & 1;
    ushort* dst = vT + (size_t)bb2 * VT_BATCH + (size_t)d * VT_STRIDE + 64 + nn0 + half * 32;
    const ushort* srcl = &vtile[d][half * 32];
#pragma unroll
    for (int u = 0; u < 4; ++u)
      *(uint4*)(dst + u * 8) = *(const uint4*)(srcl + u * 8);
  }
}

// ---------------- K4: FUSED bias + attention -------------------------------
// Block = half-window (16 q x 128 k), 256 threads = 4 waves (wave == head).
// Phase A (all threads): k_bias2's folded-LN bias -> LDS planes [4][2048]
// (per-head MFMA layout, XOR-swizzled cols). Phase B (per wave): attn6's
// pipeline with ntq fixed to this half.
__global__ __launch_bounds__(256) void k_battn(
    const float* __restrict__ ap, const float* __restrict__ bw,
    const float* __restrict__ bb, const float* __restrict__ bW,
    const ushort* __restrict__ qG, const ushort* __restrict__ kG,
    const ushort* __restrict__ vT,
    const int* __restrict__ idxG, const float* __restrict__ SgG,
    const float* __restrict__ pmask, const float* __restrict__ atomF,
    float* __restrict__ atomO) {
  __shared__ ushort biasL[8192];       // 16 KB: [h][mt][col][r]
  __shared__ float w2s[64], W2sh[4], Cbh[4];
  const int tid = threadIdx.x;
  const int bwid = blockIdx.x >> 1;
  const int half = blockIdx.x & 1;
  const int b = bwid >> 9, w = bwid & 511;
  const size_t bN = (size_t)b * Nc;

  // ---- Phase A: folded-LN bias (verbatim k_bias2) ----
  if (tid < 64) w2s[tid] = bw[tid >> 2] * bW[tid];
  __syncthreads();
  if (tid < 4) {
    float a = 0.f, b2 = 0.f;
#pragma unroll
    for (int cp = 0; cp < 16; ++cp) { a += w2s[cp * 4 + tid]; b2 += bb[cp] * bW[cp * 4 + tid]; }
    W2sh[tid] = a; Cbh[tid] = b2;
  }
  __syncthreads();
  const float* apw = ap + (size_t)bwid * (WQc * WKc * CPc) + (size_t)half * (16 * 128 * CPc);
#pragma unroll 2
  for (int u = 0; u < 8; ++u) {
    const int p = tid + 256 * u;         // 2048 pairs (16 q x 128 k)
    const int qql = p >> 7, kk = p & 127;
    const float* src = apw + (size_t)p * CPc;
    float sum = 0.f, sq = 0.f, d0 = 0.f, d1 = 0.f, d2 = 0.f, d3 = 0.f;
#pragma unroll
    for (int t = 0; t < 4; ++t) {
      const float4 v4 = *(const float4*)&src[t * 4];
#pragma unroll
      for (int e = 0; e < 4; ++e) {
        const float x = f4c(v4, e);
        const float4 wv = *(const float4*)&w2s[(4 * t + e) * 4];
        sum += x; sq += x * x;
        d0 += x * wv.x; d1 += x * wv.y; d2 += x * wv.z; d3 += x * wv.w;
      }
    }
    const float mn = sum * 0.0625f;
    const float var = sq * 0.0625f - mn * mn;
    const float rs = rsqrtf(var + EPSf);
    const int gk = w * 32 - 48 + kk;
    const float maskt = (gk >= 0 && gk < Nc) ? 0.f : NEG_INF;
    const int mt = kk >> 4, s_ = (kk >> 2) & 3, r_ = kk & 3;
    const int col = s_ * 16 + (qql ^ ((mt & 3) << 2) ^ s_);
    const int base = mt * 256 + col * 4 + r_;
    biasL[base]        = bfx(rs * (d0 - mn * W2sh[0]) + Cbh[0] + maskt);
    biasL[base + 2048] = bfx(rs * (d1 - mn * W2sh[1]) + Cbh[1] + maskt);
    biasL[base + 4096] = bfx(rs * (d2 - mn * W2sh[2]) + Cbh[2] + maskt);
    biasL[base + 6144] = bfx(rs * (d3 - mn * W2sh[3]) + Cbh[3] + maskt);
  }
  __syncthreads();

  // ---- Phase B: per-wave attention (wave == head) ----
  const int h = tid >> 6;
  const int lane = tid & 63;
  const int c = lane & 15, s = lane >> 4;

  f32x4 acc[8];
  {
    const ushort* bh = &biasL[h * 2048];
#pragma unroll
    for (int mt = 0; mt < 8; ++mt) {
      const int col = s * 16 + (c ^ ((mt & 3) << 2) ^ s);
      const uint2 pk = *(const uint2*)&bh[mt * 256 + col * 4];
      acc[mt][0] = ubf(pk.x & 0xffff);
      acc[mt][1] = ubf(pk.x >> 16);
      acc[mt][2] = ubf(pk.y & 0xffff);
      acc[mt][3] = ubf(pk.y >> 16);
    }
  }

  const int qq = w * 32 + half * 16 + c;
  const bf16x8 bfragQ = ldfrag(&qG[(bN + qq) * CAc + h * 32 + 8 * s]);
#pragma unroll
  for (int mt = 0; mt < 8; ++mt) {
    int gk = w * 32 - 48 + mt * 16 + c;
    gk = min(max(gk, 0), Nc - 1);
    const bf16x8 afragK = ldfrag(&kG[(bN + gk) * CAc + h * 32 + 8 * s]);
    acc[mt] = __builtin_amdgcn_mfma_f32_16x16x32_bf16(afragK, bfragQ, acc[mt], 0, 0, 0);
  }

  int ppk[8][2];
  {
    float mx = -3e38f;
#pragma unroll
    for (int mt = 0; mt < 8; ++mt)
#pragma unroll
      for (int r = 0; r < 4; ++r) mx = fmaxf(mx, acc[mt][r]);
    mx = fmaxf(mx, __shfl_xor(mx, 16, 64));
    mx = fmaxf(mx, __shfl_xor(mx, 32, 64));
    float sm = 0.f;
#pragma unroll
    for (int mt = 0; mt < 8; ++mt)
#pragma unroll
      for (int r = 0; r < 4; ++r) {
        const float e = __expf(acc[mt][r] - mx);
        acc[mt][r] = e;
        sm += e;
      }
    sm += __shfl_xor(sm, 16, 64);
    sm += __shfl_xor(sm, 32, 64);
    const float inv = 1.0f / sm;
#pragma unroll
    for (int mt = 0; mt < 8; ++mt) {
      ppk[mt][0] = (int)pk2(acc[mt][0] * inv, acc[mt][1] * inv);
      ppk[mt][1] = (int)pk2(acc[mt][2] * inv, acc[mt][3] * inv);
    }
  }

  f32x4 opv[2];
  opv[0][0]=0.f; opv[0][1]=0.f; opv[0][2]=0.f; opv[0][3]=0.f;
  opv[1][0]=0.f; opv[1][1]=0.f; opv[1][2]=0.f; opv[1][3]=0.f;
  const int idxA = 4 * ((((2 * s) & 3) << 4) | c);
  const int idxB = 4 * ((((2 * s + 1) & 3) << 4) | c);
  const ushort* vTb = vT + (size_t)b * VT_BATCH;
#pragma unroll
  for (int ks = 0; ks < 4; ++ks) {
    const int vbase = 64 + w * 32 - 48 + ks * 32 + 8 * s;
    bf16x8 bV[2];
#pragma unroll
    for (int ntd = 0; ntd < 2; ++ntd) {
      const int d = h * 32 + ntd * 16 + c;
      bV[ntd] = ldfrag(&vTb[(size_t)d * VT_STRIDE + vbase]);
    }
    int atv[4];
    {
      const int a0 = __builtin_amdgcn_ds_bpermute(idxA, ppk[2 * ks][0]);
      const int b0 = __builtin_amdgcn_ds_bpermute(idxA, ppk[2 * ks + 1][0]);
      atv[0] = (s < 2) ? a0 : b0;
      const int a1 = __builtin_amdgcn_ds_bpermute(idxA, ppk[2 * ks][1]);
      const int b1 = __builtin_amdgcn_ds_bpermute(idxA, ppk[2 * ks + 1][1]);
      atv[1] = (s < 2) ? a1 : b1;
      const int a2 = __builtin_amdgcn_ds_bpermute(idxB, ppk[2 * ks][0]);
      const int b2 = __builtin_amdgcn_ds_bpermute(idxB, ppk[2 * ks + 1][0]);
      atv[2] = (s < 2) ? a2 : b2;
      const int a3 = __builtin_amdgcn_ds_bpermute(idxB, ppk[2 * ks][1]);
      const int b3 = __builtin_amdgcn_ds_bpermute(idxB, ppk[2 * ks + 1][1]);
      atv[3] = (s < 2) ? a3 : b3;
    }
    const bf16x8 afragP = __builtin_bit_cast(bf16x8, *(const u32x4*)atv);
#pragma unroll
    for (int ntd = 0; ntd < 2; ++ntd)
      opv[ntd] = __builtin_amdgcn_mfma_f32_16x16x32_bf16(afragP, bV[ntd], opv[ntd], 0, 0, 0);
  }

#pragma unroll
  for (int r = 0; r < 4; ++r) {
    const int qr = w * 32 + half * 16 + 4 * s + r;
    const size_t rowg = bN + qr;
    const int residx = idxG[rowg];
    const float pm = pmask[rowg];
    const size_t gbase = ((size_t)b * Rc + residx) * CAc;
#pragma unroll
    for (int ntd = 0; ntd < 2; ++ntd) {
      const int d = h * 32 + ntd * 16 + c;
      const float g = SgG[gbase + d];
      const float af = atomF[rowg * CAc + d];
      atomO[rowg * CAc + d] = af + opv[ntd][r] * g * pm;
    }
  }
}

// ---------------- K6: transition mid GEMM (W1||W2 paired, silu-mul) --------
__global__ __launch_bounds__(256) void k_gemm_mid(
    const ushort* __restrict__ act16, const ushort* __restrict__ midWt,
    ushort* __restrict__ bmid16) {
  const int wid = threadIdx.x >> 6, lane = threadIdx.x & 63;
  const int c = lane & 15, s = lane >> 4;
  const int wm = wid & 1, wn = wid >> 1;
  const int m0 = blockIdx.x * 64 + wm * 32;
  const int nb = blockIdx.y * 64 + wn * 32;
  f32x4 acc1[2][2], acc2[2][2];
#pragma unroll
  for (int nt = 0; nt < 2; ++nt)
#pragma unroll
    for (int mt = 0; mt < 2; ++mt) {
      acc1[nt][mt][0]=0.f; acc1[nt][mt][1]=0.f; acc1[nt][mt][2]=0.f; acc1[nt][mt][3]=0.f;
      acc2[nt][mt][0]=0.f; acc2[nt][mt][1]=0.f; acc2[nt][mt][2]=0.f; acc2[nt][mt][3]=0.f;
    }
#pragma unroll
  for (int kk = 0; kk < 4; ++kk) {
    const int k0 = kk * 32 + 8 * s;
    bf16x8 bA[2];
#pragma unroll
    for (int mt = 0; mt < 2; ++mt)
      bA[mt] = ldfrag(&act16[(size_t)(m0 + mt * 16 + c) * 128 + k0]);
#pragma unroll
    for (int nt = 0; nt < 2; ++nt) {
      const bf16x8 aW1 = ldfrag(&midWt[(size_t)(nb + nt * 16 + c) * 128 + k0]);
      const bf16x8 aW2 = ldfrag(&midWt[(size_t)(256 + nb + nt * 16 + c) * 128 + k0]);
#pragma unroll
      for (int mt = 0; mt < 2; ++mt) {
        acc1[nt][mt] = __builtin_amdgcn_mfma_f32_16x16x32_bf16(aW1, bA[mt], acc1[nt][mt], 0, 0, 0);
        acc2[nt][mt] = __builtin_amdgcn_mfma_f32_16x16x32_bf16(aW2, bA[mt], acc2[nt][mt], 0, 0, 0);
      }
    }
  }
#pragma unroll
  for (int nt = 0; nt < 2; ++nt) {
    const int colb = nb + nt * 16 + 4 * s;
#pragma unroll
    for (int mt = 0; mt < 2; ++mt) {
      const int m = m0 + mt * 16 + c;
      ushort4 u4;
#pragma unroll
      for (int r = 0; r < 4; ++r) {
        const float a1 = acc1[nt][mt][r];
        const float v = a1 * sigm(a1) * acc2[nt][mt][r];
        ((unsigned short*)&u4)[r] = bfx(v);
      }
      *(ushort4*)&bmid16[(size_t)m * 256 + colb] = u4;
    }
  }
}

// ---------------- K7: out GEMM (K=256) + gated residual --------------------
__global__ __launch_bounds__(256) void k_gemm_out(
    const ushort* __restrict__ bmid16, const ushort* __restrict__ WoT,
    const float* __restrict__ atomw, const int* __restrict__ idxG,
    const float* __restrict__ TcG, const float* __restrict__ pmask,
    float* __restrict__ outG) {
  const int wid = threadIdx.x >> 6, lane = threadIdx.x & 63;
  const int c = lane & 15, s = lane >> 4;
  const int wm = wid & 1, wn = wid >> 1;
  const int m0 = blockIdx.x * 64 + wm * 32;
  const int nb = wn * 64;
  f32x4 acc[4][2];
#pragma unroll
  for (int nt = 0; nt < 4; ++nt)
#pragma unroll
    for (int mt = 0; mt < 2; ++mt) { acc[nt][mt][0]=0.f; acc[nt][mt][1]=0.f; acc[nt][mt][2]=0.f; acc[nt][mt][3]=0.f; }
#pragma unroll
  for (int kk = 0; kk < 8; ++kk) {
    const int k0 = kk * 32 + 8 * s;
    bf16x8 bA[2];
#pragma unroll
    for (int mt = 0; mt < 2; ++mt)
      bA[mt] = ldfrag(&bmid16[(size_t)(m0 + mt * 16 + c) * 256 + k0]);
#pragma unroll
    for (int nt = 0; nt < 4; ++nt) {
      const bf16x8 aW = ldfrag(&WoT[(size_t)(nb + nt * 16 + c) * 256 + k0]);
#pragma unroll
      for (int mt = 0; mt < 2; ++mt)
        acc[nt][mt] = __builtin_amdgcn_mfma_f32_16x16x32_bf16(aW, bA[mt], acc[nt][mt], 0, 0, 0);
    }
  }
#pragma unroll
  for (int mt = 0; mt < 2; ++mt) {
    const int m = m0 + mt * 16 + c;
    const int b = m >> 14;
    const int idx = idxG[m];
    const float pm = pmask[m];
    const size_t tcb = ((size_t)(b * Rc) + idx) * CAc;
#pragma unroll
    for (int nt = 0; nt < 4; ++nt) {
      const int colb = nb + nt * 16 + 4 * s;
      const float4 tc = *(const float4*)&TcG[tcb + colb];
      const float4 at = *(const float4*)&atomw[(size_t)m * CAc + colb];
      float4 o;
      o.x = at.x + tc.x * acc[nt][mt][0] * pm;
      o.y = at.y + tc.y * acc[nt][mt][1] * pm;
      o.z = at.z + tc.z * acc[nt][mt][2] * pm;
      o.w = at.w + tc.w * acc[nt][mt][3] * pm;
      *(float4*)&outG[(size_t)m * CAc + colb] = o;
    }
  }
}

}  // namespace

extern "C" void kernel_launch(void* const* d_in, const int* in_sizes, int n_in,
                              void* d_out, int out_size, void* d_ws, size_t ws_size,
                              hipStream_t stream) {
  (void)in_sizes; (void)n_in; (void)out_size; (void)ws_size;
  const float* atomF   = (const float*)d_in[0];
  const float* resF    = (const float*)d_in[1];
  const float* apF     = (const float*)d_in[2];
  const int*   idx     = (const int*)d_in[3];
  const float* pmask   = (const float*)d_in[4];
  const float* a_ln_w  = (const float*)d_in[6];
  const float* a_Wg    = (const float*)d_in[7];
  const float* a_bg    = (const float*)d_in[8];
  const float* a_Wb    = (const float*)d_in[9];
  const float* q_W     = (const float*)d_in[10];
  const float* q_b     = (const float*)d_in[11];
  const float* kv_W    = (const float*)d_in[12];
  const float* bij_ln_w= (const float*)d_in[13];
  const float* bij_ln_b= (const float*)d_in[14];
  const float* bij_W   = (const float*)d_in[15];
  const float* sg_W    = (const float*)d_in[16];
  const float* sg_b    = (const float*)d_in[17];
  const float* t_ln_w  = (const float*)d_in[18];
  const float* t_Wg    = (const float*)d_in[19];
  const float* t_bg    = (const float*)d_in[20];
  const float* t_Wb    = (const float*)d_in[21];
  const float* t_W1    = (const float*)d_in[22];
  const float* t_W2    = (const float*)d_in[23];
  const float* t_Wc    = (const float*)d_in[24];
  const float* t_bc    = (const float*)d_in[25];
  const float* t_Wo    = (const float*)d_in[26];

  float* ws = (float*)d_ws;
  float* Ag    = ws;                          // 6 x 524288
  float* Ab    = Ag + 524288;
  float* Tg    = Ab + 524288;
  float* Tb    = Tg + 524288;
  float* Sg    = Tb + 524288;
  float* Tc    = Sg + 524288;
  float* lnA   = Tc + 524288;                 // 1048576
  float* lnT   = lnA + 1048576;               // 1048576
  ushort* act16  = (ushort*)(lnT + 1048576);  // 4194304 ushorts (s, then t)
  ushort* q16    = act16 + 4194304;           // 4194304 ushorts
  ushort* k16    = q16 + 4194304;             // 4194304 ushorts
  ushort* bmid16 = k16 + 4194304;             // 8388608 ushorts
  float* atomw   = (float*)(bmid16 + 8388608);// 4194304 floats
  ushort* qWt    = (ushort*)(atomw + 4194304);// 16384
  ushort* kvWt   = qWt + 16384;               // 32768
  ushort* midWt  = kvWt + 32768;              // 65536
  ushort* WoT    = midWt + 65536;             // 32768
  ushort* vT     = WoT + 32768;               // 2 x 128 x 16512 = 4227072 ushorts

  k_pack_resln<<<dim3(1728), dim3(256), 0, stream>>>(
      q_W, kv_W, t_W1, t_W2, t_Wo, qWt, kvWt, midWt, WoT, vT,
      resF, a_ln_w, t_ln_w, lnA, lnT);
  k_res_gemm<<<dim3(Bc * Rc / 32, 6), dim3(256), 0, stream>>>(
      lnA, lnT, resF, a_Wg, a_bg, a_Wb, t_Wg, t_bg, t_Wb, sg_W, sg_b, t_Wc, t_bc,
      Ag, Ab, Tg, Tb, Sg, Tc);
  k_adaln16<<<dim3(Bc * Nc / 4), dim3(256), 0, stream>>>(atomF, idx, Ag, Ab,
                                                         (unsigned*)act16);
  k_gemm_qkv<<<dim3(Bc * Nc / 64, 3), dim3(256), 0, stream>>>(act16, qWt, kvWt, q_b,
                                                              q16, k16, vT);
  k_battn<<<dim3(Bc * NWc * 2), dim3(256), 0, stream>>>(
      apF, bij_ln_w, bij_ln_b, bij_W, q16, k16, vT, idx, Sg, pmask, atomF, atomw);
  k_adaln16<<<dim3(Bc * Nc / 4), dim3(256), 0, stream>>>(atomw, idx, Tg, Tb,
                                                         (unsigned*)act16);
  k_gemm_mid<<<dim3(Bc * Nc / 64, 4), dim3(256), 0, stream>>>(act16, midWt, bmid16);
  k_gemm_out<<<dim3(Bc * Nc / 64), dim3(256), 0, stream>>>(bmid16, WoT, atomw, idx, Tc,
                                                           pmask, (float*)d_out);
}

// Round 15
// 206.667 us; speedup vs baseline: 1.5221x; 1.0558x over previous
//
#include <hip/hip_runtime.h>
#include <hip/hip_bf16.h>
#include <string.h>

namespace {

constexpr int Bc  = 2;
constexpr int Nc  = 16384;
constexpr int Rc  = 2048;
constexpr int CAc = 128;
constexpr int CSc = 256;
constexpr int CPc = 16;
constexpr int Hc  = 4;
constexpr int WQc = 32;
constexpr int WKc = 128;
constexpr int NWc = 512;
constexpr float EPSf     = 1e-5f;
constexpr float NEG_INF  = -1e8f;
constexpr float QK_SCALE = 0.17677669529663687f;  // 1/sqrt(32)

constexpr int VT_STRIDE = 16512;          // 64 pad + 16384 + 64 pad
constexpr int VT_BATCH  = 128 * VT_STRIDE;

typedef short bf16x8 __attribute__((ext_vector_type(8)));
typedef float f32x4 __attribute__((ext_vector_type(4)));
typedef unsigned int u32x4 __attribute__((ext_vector_type(4)));

__device__ __forceinline__ float wsum(float v) {
#pragma unroll
  for (int m = 1; m < 64; m <<= 1) v += __shfl_xor(v, m, 64);
  return v;
}
__device__ __forceinline__ float sigm(float x) { return 1.0f / (1.0f + __expf(-x)); }
__device__ __forceinline__ float f4c(const float4& v, int i) {
  return i == 0 ? v.x : i == 1 ? v.y : i == 2 ? v.z : v.w;
}
__device__ __forceinline__ unsigned short bfx(float v) {
  __hip_bfloat16 h = __float2bfloat16(v);
  unsigned short u;
  memcpy(&u, &h, 2);
  return u;
}
__device__ __forceinline__ unsigned pk2(float a, float b) {
  return (unsigned)bfx(a) | ((unsigned)bfx(b) << 16);
}
__device__ __forceinline__ float ubf(unsigned us) {
  unsigned v = us << 16;
  float f;
  memcpy(&f, &v, 4);
  return f;
}
__device__ __forceinline__ bf16x8 ldfrag(const ushort* p) {
  return __builtin_bit_cast(bf16x8, *(const u32x4*)p);
}

// ---------------- K0+K1a merged: weight pack (+vT pads) | res LN -----------
__global__ void k_pack_resln(const float* __restrict__ q_W, const float* __restrict__ kv_W,
                             const float* __restrict__ t_W1, const float* __restrict__ t_W2,
                             const float* __restrict__ t_Wo,
                             ushort* __restrict__ qWt, ushort* __restrict__ kvWt,
                             ushort* __restrict__ midWt, ushort* __restrict__ WoT,
                             ushort* __restrict__ vT,
                             const float* __restrict__ res, const float* __restrict__ a_ln_w,
                             const float* __restrict__ t_ln_w, float* __restrict__ lnA,
                             float* __restrict__ lnT) {
  if (blockIdx.x < 704) {
    const int i = blockIdx.x * 256 + threadIdx.x;
    if (i < 16384) {
      const int n = i >> 7, k = i & 127;
      qWt[i] = bfx(q_W[k * 128 + n]);
    } else if (i < 49152) {
      const int i2 = i - 16384;
      const int n = i2 >> 7, k = i2 & 127;
      kvWt[i2] = bfx(kv_W[k * 256 + n]);
    } else if (i < 114688) {
      const int i3 = i - 49152;
      const int n = i3 >> 7, k = i3 & 127;
      midWt[i3] = bfx(n < 256 ? t_W1[k * 256 + n] : t_W2[k * 256 + (n - 256)]);
    } else if (i < 147456) {
      const int i4 = i - 114688;
      const int n = i4 >> 8, k = i4 & 255;
      WoT[i4] = bfx(t_Wo[k * 128 + n]);
    } else if (i < 180224) {
      const int j = i - 147456;           // vT edge pads -> 0
      const int b = j >> 14, rem = j & 16383;
      const int d = rem >> 7, p = rem & 127;
      const int col = (p < 64) ? p : (16384 + p);
      vT[(size_t)b * VT_BATCH + (size_t)d * VT_STRIDE + col] = 0;
    }
  } else {
    const int wid = threadIdx.x >> 6, lane = threadIdx.x & 63;
    const int row = (blockIdx.x - 704) * 4 + wid;  // B*R rows
    const float* r = res + (size_t)row * CSc;
    float x[4], s = 0.f, sq = 0.f;
#pragma unroll
    for (int i = 0; i < 4; ++i) { x[i] = r[lane + 64 * i]; s += x[i]; sq += x[i] * x[i]; }
    s = wsum(s); sq = wsum(sq);
    const float mn = s * (1.0f / CSc);
    const float var = sq * (1.0f / CSc) - mn * mn;
    const float rs = rsqrtf(var + EPSf);
#pragma unroll
    for (int i = 0; i < 4; ++i) {
      const int c = lane + 64 * i;
      const float y = (x[i] - mn) * rs;
      lnA[(size_t)row * CSc + c] = y * a_ln_w[c];
      lnT[(size_t)row * CSc + c] = y * t_ln_w[c];
    }
  }
}

// ---------------- K1b: 6 res GEMMs (K=256 -> 128 cols), gates sigmoid'd ----
__global__ void k_res_gemm(const float* __restrict__ lnA, const float* __restrict__ lnT,
                           const float* __restrict__ res,
                           const float* __restrict__ a_Wg, const float* __restrict__ a_bg,
                           const float* __restrict__ a_Wb,
                           const float* __restrict__ t_Wg, const float* __restrict__ t_bg,
                           const float* __restrict__ t_Wb,
                           const float* __restrict__ sg_W, const float* __restrict__ sg_b,
                           const float* __restrict__ t_Wc, const float* __restrict__ t_bc,
                           float* __restrict__ Ag, float* __restrict__ Ab,
                           float* __restrict__ Tg, float* __restrict__ Tb,
                           float* __restrict__ Sg, float* __restrict__ Tc) {
  __shared__ float tile[32 * CSc];
  const int m = blockIdx.y;
  const float* in = (m < 2) ? lnA : (m < 4) ? lnT : res;
  const float* W  = (m == 0) ? a_Wg : (m == 1) ? a_Wb : (m == 2) ? t_Wg
                  : (m == 3) ? t_Wb : (m == 4) ? sg_W : t_Wc;
  const float* bias = (m == 0) ? a_bg : (m == 2) ? t_bg : (m == 4) ? sg_b
                    : (m == 5) ? t_bc : nullptr;
  const bool sig = (m == 0) || (m == 2) || (m == 4) || (m == 5);
  float* out = (m == 0) ? Ag : (m == 1) ? Ab : (m == 2) ? Tg
             : (m == 3) ? Tb : (m == 4) ? Sg : Tc;
  const int row0 = blockIdx.x * 32;
  const float4* src = (const float4*)(in + (size_t)row0 * CSc);
  float4* dst = (float4*)tile;
#pragma unroll
  for (int k = 0; k < 8; ++k) dst[threadIdx.x + 256 * k] = src[threadIdx.x + 256 * k];
  __syncthreads();
  const int c0 = (threadIdx.x & 31) * 4;
  const int r0 = (threadIdx.x >> 5) * 4;
  float acc[4][4] = {};
  for (int j = 0; j < CSc; j += 4) {
    float4 a[4];
#pragma unroll
    for (int r = 0; r < 4; ++r) a[r] = *(const float4*)&tile[(r0 + r) * CSc + j];
#pragma unroll
    for (int jj = 0; jj < 4; ++jj) {
      const float4 w = *(const float4*)&W[(size_t)(j + jj) * CAc + c0];
#pragma unroll
      for (int r = 0; r < 4; ++r) {
        const float av = f4c(a[r], jj);
        acc[r][0] += av * w.x; acc[r][1] += av * w.y;
        acc[r][2] += av * w.z; acc[r][3] += av * w.w;
      }
    }
  }
  float4 bv = make_float4(0.f, 0.f, 0.f, 0.f);
  if (bias) bv = *(const float4*)&bias[c0];
#pragma unroll
  for (int r = 0; r < 4; ++r) {
    float4 o;
    o.x = acc[r][0] + bv.x; o.y = acc[r][1] + bv.y;
    o.z = acc[r][2] + bv.z; o.w = acc[r][3] + bv.w;
    if (sig) { o.x = sigm(o.x); o.y = sigm(o.y); o.z = sigm(o.z); o.w = sigm(o.w); }
    *(float4*)&out[(size_t)(row0 + r0 + r) * CAc + c0] = o;
  }
}

// ---------------- K2: adaLN over atoms (f32 in) -> bf16 out ----------------
__global__ void k_adaln16(const float* __restrict__ in, const int* __restrict__ idxG,
                          const float* __restrict__ G, const float* __restrict__ Bb,
                          unsigned* __restrict__ out32) {
  const int wid = threadIdx.x >> 6, lane = threadIdx.x & 63;
  const int row = blockIdx.x * 4 + wid;  // B*N rows
  const int b = row >> 14;
  const float* r = in + (size_t)row * CAc;
  const float2 xp = *(const float2*)&r[2 * lane];
  const float s = wsum(xp.x + xp.y);
  const float sq = wsum(xp.x * xp.x + xp.y * xp.y);
  const float mn = s * (1.0f / CAc);
  const float var = sq * (1.0f / CAc) - mn * mn;
  const float rs = rsqrtf(var + EPSf);
  const int base = (b * Rc + idxG[row]) * CAc;
  const float2 g2 = *(const float2*)&G[base + 2 * lane];
  const float2 b2 = *(const float2*)&Bb[base + 2 * lane];
  const float y0 = (xp.x - mn) * rs * g2.x + b2.x;
  const float y1 = (xp.y - mn) * rs * g2.y + b2.y;
  out32[(size_t)row * 64 + lane] = pk2(y0, y1);
}

// ---------------- K5: adaLN over atoms (bf16 in) -> bf16 out ---------------
__global__ void k_adaln16b(const unsigned* __restrict__ in32, const int* __restrict__ idxG,
                           const float* __restrict__ G, const float* __restrict__ Bb,
                           unsigned* __restrict__ out32) {
  const int wid = threadIdx.x >> 6, lane = threadIdx.x & 63;
  const int row = blockIdx.x * 4 + wid;  // B*N rows
  const int b = row >> 14;
  const unsigned pkx = in32[(size_t)row * 64 + lane];
  const float x0 = ubf(pkx & 0xffff), x1 = ubf(pkx >> 16);
  const float s = wsum(x0 + x1);
  const float sq = wsum(x0 * x0 + x1 * x1);
  const float mn = s * (1.0f / CAc);
  const float var = sq * (1.0f / CAc) - mn * mn;
  const float rs = rsqrtf(var + EPSf);
  const int base = (b * Rc + idxG[row]) * CAc;
  const float2 g2 = *(const float2*)&G[base + 2 * lane];
  const float2 b2 = *(const float2*)&Bb[base + 2 * lane];
  const float y0 = (x0 - mn) * rs * g2.x + b2.x;
  const float y1 = (x1 - mn) * rs * g2.y + b2.y;
  out32[(size_t)row * 64 + lane] = pk2(y0, y1);
}

// ---------------- K3: qkv GEMM via MFMA (M=32768, K=128) -------------------
__global__ __launch_bounds__(256) void k_gemm_qkv(
    const ushort* __restrict__ act16, const ushort* __restrict__ qWt,
    const ushort* __restrict__ kvWt, const float* __restrict__ q_b,
    ushort* __restrict__ q16, ushort* __restrict__ k16, ushort* __restrict__ vT) {
  __shared__ ushort vtile[128][72];  // 18.4 KB; stride 144B keeps b128 aligned
  const int ny = blockIdx.y;
  const int wid = threadIdx.x >> 6, lane = threadIdx.x & 63;
  const int c = lane & 15, s = lane >> 4;
  const int wm = wid & 1, wn = wid >> 1;
  const int base = blockIdx.x * 64;
  const int m0 = base + wm * 32;
  const int nb = wn * 64;
  const ushort* Wt = (ny == 0) ? qWt : kvWt + (ny == 2 ? 128 * 128 : 0);
  f32x4 acc[4][2];
#pragma unroll
  for (int nt = 0; nt < 4; ++nt)
#pragma unroll
    for (int mt = 0; mt < 2; ++mt) { acc[nt][mt][0]=0.f; acc[nt][mt][1]=0.f; acc[nt][mt][2]=0.f; acc[nt][mt][3]=0.f; }
#pragma unroll
  for (int kk = 0; kk < 4; ++kk) {
    const int k0 = kk * 32 + 8 * s;
    bf16x8 bA[2];
#pragma unroll
    for (int mt = 0; mt < 2; ++mt)
      bA[mt] = ldfrag(&act16[(size_t)(m0 + mt * 16 + c) * 128 + k0]);
#pragma unroll
    for (int nt = 0; nt < 4; ++nt) {
      const bf16x8 aW = ldfrag(&Wt[(size_t)(nb + nt * 16 + c) * 128 + k0]);
#pragma unroll
      for (int mt = 0; mt < 2; ++mt)
        acc[nt][mt] = __builtin_amdgcn_mfma_f32_16x16x32_bf16(aW, bA[mt], acc[nt][mt], 0, 0, 0);
    }
  }
#pragma unroll
  for (int nt = 0; nt < 4; ++nt) {
    const int colb = nb + nt * 16 + 4 * s;
    float4 qb4 = make_float4(0.f, 0.f, 0.f, 0.f);
    if (ny == 0) qb4 = *(const float4*)&q_b[colb];
#pragma unroll
    for (int mt = 0; mt < 2; ++mt) {
      const int m = m0 + mt * 16 + c;
      const f32x4 a = acc[nt][mt];
      if (ny == 0) {
        ushort4 u4;
        u4.x = bfx((a[0] + qb4.x) * QK_SCALE); u4.y = bfx((a[1] + qb4.y) * QK_SCALE);
        u4.z = bfx((a[2] + qb4.z) * QK_SCALE); u4.w = bfx((a[3] + qb4.w) * QK_SCALE);
        *(ushort4*)&q16[(size_t)m * 128 + colb] = u4;
      } else if (ny == 1) {
        ushort4 u4;
        u4.x = bfx(a[0]); u4.y = bfx(a[1]); u4.z = bfx(a[2]); u4.w = bfx(a[3]);
        *(ushort4*)&k16[(size_t)m * 128 + colb] = u4;
      } else {
        const int rowl = wm * 32 + mt * 16 + c;
#pragma unroll
        for (int r = 0; r < 4; ++r)
          vtile[colb + r][rowl] = bfx(a[r]);
      }
    }
  }
  if (ny == 2) {
    __syncthreads();
    const int bb2 = base >> 14, nn0 = base & 16383;
    const int t = threadIdx.x;
    const int d = t >> 1, half = t & 1;
    ushort* dst = vT + (size_t)bb2 * VT_BATCH + (size_t)d * VT_STRIDE + 64 + nn0 + half * 32;
    const ushort* srcl = &vtile[d][half * 32];
#pragma unroll
    for (int u = 0; u < 4; ++u)
      *(uint4*)(dst + u * 8) = *(const uint4*)(srcl + u * 8);
  }
}

// ---------------- K4: FUSED bias + attention (atomw out = bf16) ------------
__global__ __launch_bounds__(256) void k_battn(
    const float* __restrict__ ap, const float* __restrict__ bw,
    const float* __restrict__ bb, const float* __restrict__ bW,
    const ushort* __restrict__ qG, const ushort* __restrict__ kG,
    const ushort* __restrict__ vT,
    const int* __restrict__ idxG, const float* __restrict__ SgG,
    const float* __restrict__ pmask, const float* __restrict__ atomF,
    ushort* __restrict__ atomO16) {
  __shared__ ushort biasL[8192];       // 16 KB: [h][mt][col][r]
  __shared__ float w2s[64], W2sh[4], Cbh[4];
  const int tid = threadIdx.x;
  const int bwid = blockIdx.x >> 1;
  const int half = blockIdx.x & 1;
  const int b = bwid >> 9, w = bwid & 511;
  const size_t bN = (size_t)b * Nc;

  // ---- Phase A: folded-LN bias ----
  if (tid < 64) w2s[tid] = bw[tid >> 2] * bW[tid];
  __syncthreads();
  if (tid < 4) {
    float a = 0.f, b2 = 0.f;
#pragma unroll
    for (int cp = 0; cp < 16; ++cp) { a += w2s[cp * 4 + tid]; b2 += bb[cp] * bW[cp * 4 + tid]; }
    W2sh[tid] = a; Cbh[tid] = b2;
  }
  __syncthreads();
  const float* apw = ap + (size_t)bwid * (WQc * WKc * CPc) + (size_t)half * (16 * 128 * CPc);
#pragma unroll 2
  for (int u = 0; u < 8; ++u) {
    const int p = tid + 256 * u;         // 2048 pairs (16 q x 128 k)
    const int qql = p >> 7, kk = p & 127;
    const float* src = apw + (size_t)p * CPc;
    float sum = 0.f, sq = 0.f, d0 = 0.f, d1 = 0.f, d2 = 0.f, d3 = 0.f;
#pragma unroll
    for (int t = 0; t < 4; ++t) {
      const float4 v4 = *(const float4*)&src[t * 4];
#pragma unroll
      for (int e = 0; e < 4; ++e) {
        const float x = f4c(v4, e);
        const float4 wv = *(const float4*)&w2s[(4 * t + e) * 4];
        sum += x; sq += x * x;
        d0 += x * wv.x; d1 += x * wv.y; d2 += x * wv.z; d3 += x * wv.w;
      }
    }
    const float mn = sum * 0.0625f;
    const float var = sq * 0.0625f - mn * mn;
    const float rs = rsqrtf(var + EPSf);
    const int gk = w * 32 - 48 + kk;
    const float maskt = (gk >= 0 && gk < Nc) ? 0.f : NEG_INF;
    const int mt = kk >> 4, s_ = (kk >> 2) & 3, r_ = kk & 3;
    const int col = s_ * 16 + (qql ^ ((mt & 3) << 2) ^ s_);
    const int base = mt * 256 + col * 4 + r_;
    biasL[base]        = bfx(rs * (d0 - mn * W2sh[0]) + Cbh[0] + maskt);
    biasL[base + 2048] = bfx(rs * (d1 - mn * W2sh[1]) + Cbh[1] + maskt);
    biasL[base + 4096] = bfx(rs * (d2 - mn * W2sh[2]) + Cbh[2] + maskt);
    biasL[base + 6144] = bfx(rs * (d3 - mn * W2sh[3]) + Cbh[3] + maskt);
  }
  __syncthreads();

  // ---- Phase B: per-wave attention (wave == head) ----
  const int h = tid >> 6;
  const int lane = tid & 63;
  const int c = lane & 15, s = lane >> 4;

  f32x4 acc[8];
  {
    const ushort* bh = &biasL[h * 2048];
#pragma unroll
    for (int mt = 0; mt < 8; ++mt) {
      const int col = s * 16 + (c ^ ((mt & 3) << 2) ^ s);
      const uint2 pk = *(const uint2*)&bh[mt * 256 + col * 4];
      acc[mt][0] = ubf(pk.x & 0xffff);
      acc[mt][1] = ubf(pk.x >> 16);
      acc[mt][2] = ubf(pk.y & 0xffff);
      acc[mt][3] = ubf(pk.y >> 16);
    }
  }

  const int qq = w * 32 + half * 16 + c;
  const bf16x8 bfragQ = ldfrag(&qG[(bN + qq) * CAc + h * 32 + 8 * s]);
#pragma unroll
  for (int mt = 0; mt < 8; ++mt) {
    int gk = w * 32 - 48 + mt * 16 + c;
    gk = min(max(gk, 0), Nc - 1);
    const bf16x8 afragK = ldfrag(&kG[(bN + gk) * CAc + h * 32 + 8 * s]);
    acc[mt] = __builtin_amdgcn_mfma_f32_16x16x32_bf16(afragK, bfragQ, acc[mt], 0, 0, 0);
  }

  int ppk[8][2];
  {
    float mx = -3e38f;
#pragma unroll
    for (int mt = 0; mt < 8; ++mt)
#pragma unroll
      for (int r = 0; r < 4; ++r) mx = fmaxf(mx, acc[mt][r]);
    mx = fmaxf(mx, __shfl_xor(mx, 16, 64));
    mx = fmaxf(mx, __shfl_xor(mx, 32, 64));
    float sm = 0.f;
#pragma unroll
    for (int mt = 0; mt < 8; ++mt)
#pragma unroll
      for (int r = 0; r < 4; ++r) {
        const float e = __expf(acc[mt][r] - mx);
        acc[mt][r] = e;
        sm += e;
      }
    sm += __shfl_xor(sm, 16, 64);
    sm += __shfl_xor(sm, 32, 64);
    const float inv = 1.0f / sm;
#pragma unroll
    for (int mt = 0; mt < 8; ++mt) {
      ppk[mt][0] = (int)pk2(acc[mt][0] * inv, acc[mt][1] * inv);
      ppk[mt][1] = (int)pk2(acc[mt][2] * inv, acc[mt][3] * inv);
    }
  }

  f32x4 opv[2];
  opv[0][0]=0.f; opv[0][1]=0.f; opv[0][2]=0.f; opv[0][3]=0.f;
  opv[1][0]=0.f; opv[1][1]=0.f; opv[1][2]=0.f; opv[1][3]=0.f;
  const int idxA = 4 * ((((2 * s) & 3) << 4) | c);
  const int idxB = 4 * ((((2 * s + 1) & 3) << 4) | c);
  const ushort* vTb = vT + (size_t)b * VT_BATCH;
#pragma unroll
  for (int ks = 0; ks < 4; ++ks) {
    const int vbase = 64 + w * 32 - 48 + ks * 32 + 8 * s;
    bf16x8 bV[2];
#pragma unroll
    for (int ntd = 0; ntd < 2; ++ntd) {
      const int d = h * 32 + ntd * 16 + c;
      bV[ntd] = ldfrag(&vTb[(size_t)d * VT_STRIDE + vbase]);
    }
    int atv[4];
    {
      const int a0 = __builtin_amdgcn_ds_bpermute(idxA, ppk[2 * ks][0]);
      const int b0 = __builtin_amdgcn_ds_bpermute(idxA, ppk[2 * ks + 1][0]);
      atv[0] = (s < 2) ? a0 : b0;
      const int a1 = __builtin_amdgcn_ds_bpermute(idxA, ppk[2 * ks][1]);
      const int b1 = __builtin_amdgcn_ds_bpermute(idxA, ppk[2 * ks + 1][1]);
      atv[1] = (s < 2) ? a1 : b1;
      const int a2 = __builtin_amdgcn_ds_bpermute(idxB, ppk[2 * ks][0]);
      const int b2 = __builtin_amdgcn_ds_bpermute(idxB, ppk[2 * ks + 1][0]);
      atv[2] = (s < 2) ? a2 : b2;
      const int a3 = __builtin_amdgcn_ds_bpermute(idxB, ppk[2 * ks][1]);
      const int b3 = __builtin_amdgcn_ds_bpermute(idxB, ppk[2 * ks + 1][1]);
      atv[3] = (s < 2) ? a3 : b3;
    }
    const bf16x8 afragP = __builtin_bit_cast(bf16x8, *(const u32x4*)atv);
#pragma unroll
    for (int ntd = 0; ntd < 2; ++ntd)
      opv[ntd] = __builtin_amdgcn_mfma_f32_16x16x32_bf16(afragP, bV[ntd], opv[ntd], 0, 0, 0);
  }

#pragma unroll
  for (int r = 0; r < 4; ++r) {
    const int qr = w * 32 + half * 16 + 4 * s + r;
    const size_t rowg = bN + qr;
    const int residx = idxG[rowg];
    const float pm = pmask[rowg];
    const size_t gbase = ((size_t)b * Rc + residx) * CAc;
#pragma unroll
    for (int ntd = 0; ntd < 2; ++ntd) {
      const int d = h * 32 + ntd * 16 + c;
      const float g = SgG[gbase + d];
      const float af = atomF[rowg * CAc + d];
      atomO16[rowg * CAc + d] = bfx(af + opv[ntd][r] * g * pm);
    }
  }
}

// ---------------- K6+K7 FUSED: transition (mid in LDS) + out + residual ----
// Block = 32 rows. Phase 1: mid GEMM (silu(t@W1)*(t@W2)) -> bf16 LDS tile
// [32][264] (padded). Phase 2: out GEMM K=256 from LDS + gated residual.
__global__ __launch_bounds__(256) void k_gemm_trans(
    const ushort* __restrict__ act16, const ushort* __restrict__ midWt,
    const ushort* __restrict__ WoT, const ushort* __restrict__ atomw16,
    const int* __restrict__ idxG, const float* __restrict__ TcG,
    const float* __restrict__ pmask, float* __restrict__ outG) {
  __shared__ ushort smid[32 * 264];    // 16.9 KB
  const int wid = threadIdx.x >> 6, lane = threadIdx.x & 63;
  const int c = lane & 15, s = lane >> 4;
  const int m0 = blockIdx.x * 32;

  // ---- Phase 1: mid GEMM; wave wid covers mid-cols wid*64..+63 ----
  {
    const int nb = wid * 64;
    f32x4 acc1[4][2], acc2[4][2];
#pragma unroll
    for (int nt = 0; nt < 4; ++nt)
#pragma unroll
      for (int mt = 0; mt < 2; ++mt) {
        acc1[nt][mt][0]=0.f; acc1[nt][mt][1]=0.f; acc1[nt][mt][2]=0.f; acc1[nt][mt][3]=0.f;
        acc2[nt][mt][0]=0.f; acc2[nt][mt][1]=0.f; acc2[nt][mt][2]=0.f; acc2[nt][mt][3]=0.f;
      }
#pragma unroll
    for (int kk = 0; kk < 4; ++kk) {
      const int k0 = kk * 32 + 8 * s;
      bf16x8 bA[2];
#pragma unroll
      for (int mt = 0; mt < 2; ++mt)
        bA[mt] = ldfrag(&act16[(size_t)(m0 + mt * 16 + c) * 128 + k0]);
#pragma unroll
      for (int nt = 0; nt < 4; ++nt) {
        const bf16x8 aW1 = ldfrag(&midWt[(size_t)(nb + nt * 16 + c) * 128 + k0]);
        const bf16x8 aW2 = ldfrag(&midWt[(size_t)(256 + nb + nt * 16 + c) * 128 + k0]);
#pragma unroll
        for (int mt = 0; mt < 2; ++mt) {
          acc1[nt][mt] = __builtin_amdgcn_mfma_f32_16x16x32_bf16(aW1, bA[mt], acc1[nt][mt], 0, 0, 0);
          acc2[nt][mt] = __builtin_amdgcn_mfma_f32_16x16x32_bf16(aW2, bA[mt], acc2[nt][mt], 0, 0, 0);
        }
      }
    }
#pragma unroll
    for (int nt = 0; nt < 4; ++nt) {
      const int colb = nb + nt * 16 + 4 * s;
#pragma unroll
      for (int mt = 0; mt < 2; ++mt) {
        const int ml = mt * 16 + c;
        ushort4 u4;
#pragma unroll
        for (int r = 0; r < 4; ++r) {
          const float a1 = acc1[nt][mt][r];
          const float v = a1 * sigm(a1) * acc2[nt][mt][r];
          ((unsigned short*)&u4)[r] = bfx(v);
        }
        *(ushort4*)&smid[ml * 264 + colb] = u4;
      }
    }
  }
  __syncthreads();

  // ---- Phase 2: out GEMM (K=256 from LDS); wave wid covers out-cols wid*32 ----
  {
    const int nbo = wid * 32;
    f32x4 acc[2][2];
#pragma unroll
    for (int nt = 0; nt < 2; ++nt)
#pragma unroll
      for (int mt = 0; mt < 2; ++mt) { acc[nt][mt][0]=0.f; acc[nt][mt][1]=0.f; acc[nt][mt][2]=0.f; acc[nt][mt][3]=0.f; }
#pragma unroll
    for (int kk = 0; kk < 8; ++kk) {
      const int k0 = kk * 32 + 8 * s;
      bf16x8 bA[2];
#pragma unroll
      for (int mt = 0; mt < 2; ++mt)
        bA[mt] = ldfrag(&smid[(mt * 16 + c) * 264 + k0]);
#pragma unroll
      for (int nt = 0; nt < 2; ++nt) {
        const bf16x8 aW = ldfrag(&WoT[(size_t)(nbo + nt * 16 + c) * 256 + k0]);
#pragma unroll
        for (int mt = 0; mt < 2; ++mt)
          acc[nt][mt] = __builtin_amdgcn_mfma_f32_16x16x32_bf16(aW, bA[mt], acc[nt][mt], 0, 0, 0);
      }
    }
#pragma unroll
    for (int mt = 0; mt < 2; ++mt) {
      const int m = m0 + mt * 16 + c;
      const int b = m >> 14;
      const int idx = idxG[m];
      const float pm = pmask[m];
      const size_t tcb = ((size_t)(b * Rc) + idx) * CAc;
#pragma unroll
      for (int nt = 0; nt < 2; ++nt) {
        const int colb = nbo + nt * 16 + 4 * s;
        const float4 tc = *(const float4*)&TcG[tcb + colb];
        const ushort4 at4 = *(const ushort4*)&atomw16[(size_t)m * CAc + colb];
        float4 o;
        o.x = ubf(at4.x) + tc.x * acc[nt][mt][0] * pm;
        o.y = ubf(at4.y) + tc.y * acc[nt][mt][1] * pm;
        o.z = ubf(at4.z) + tc.z * acc[nt][mt][2] * pm;
        o.w = ubf(at4.w) + tc.w * acc[nt][mt][3] * pm;
        *(float4*)&outG[(size_t)m * CAc + colb] = o;
      }
    }
  }
}

}  // namespace

extern "C" void kernel_launch(void* const* d_in, const int* in_sizes, int n_in,
                              void* d_out, int out_size, void* d_ws, size_t ws_size,
                              hipStream_t stream) {
  (void)in_sizes; (void)n_in; (void)out_size; (void)ws_size;
  const float* atomF   = (const float*)d_in[0];
  const float* resF    = (const float*)d_in[1];
  const float* apF     = (const float*)d_in[2];
  const int*   idx     = (const int*)d_in[3];
  const float* pmask   = (const float*)d_in[4];
  const float* a_ln_w  = (const float*)d_in[6];
  const float* a_Wg    = (const float*)d_in[7];
  const float* a_bg    = (const float*)d_in[8];
  const float* a_Wb    = (const float*)d_in[9];
  const float* q_W     = (const float*)d_in[10];
  const float* q_b     = (const float*)d_in[11];
  const float* kv_W    = (const float*)d_in[12];
  const float* bij_ln_w= (const float*)d_in[13];
  const float* bij_ln_b= (const float*)d_in[14];
  const float* bij_W   = (const float*)d_in[15];
  const float* sg_W    = (const float*)d_in[16];
  const float* sg_b    = (const float*)d_in[17];
  const float* t_ln_w  = (const float*)d_in[18];
  const float* t_Wg    = (const float*)d_in[19];
  const float* t_bg    = (const float*)d_in[20];
  const float* t_Wb    = (const float*)d_in[21];
  const float* t_W1    = (const float*)d_in[22];
  const float* t_W2    = (const float*)d_in[23];
  const float* t_Wc    = (const float*)d_in[24];
  const float* t_bc    = (const float*)d_in[25];
  const float* t_Wo    = (const float*)d_in[26];

  float* ws = (float*)d_ws;
  float* Ag    = ws;                          // 6 x 524288
  float* Ab    = Ag + 524288;
  float* Tg    = Ab + 524288;
  float* Tb    = Tg + 524288;
  float* Sg    = Tb + 524288;
  float* Tc    = Sg + 524288;
  float* lnA   = Tc + 524288;                 // 1048576
  float* lnT   = lnA + 1048576;               // 1048576
  ushort* act16  = (ushort*)(lnT + 1048576);  // 4194304 ushorts (s, then t)
  ushort* q16    = act16 + 4194304;           // 4194304 ushorts
  ushort* k16    = q16 + 4194304;             // 4194304 ushorts
  ushort* atomw16= k16 + 4194304;             // 4194304 ushorts (bf16 atom)
  ushort* qWt    = atomw16 + 4194304;         // 16384
  ushort* kvWt   = qWt + 16384;               // 32768
  ushort* midWt  = kvWt + 32768;              // 65536
  ushort* WoT    = midWt + 65536;             // 32768
  ushort* vT     = WoT + 32768;               // 2 x 128 x 16512 = 4227072 ushorts

  k_pack_resln<<<dim3(1728), dim3(256), 0, stream>>>(
      q_W, kv_W, t_W1, t_W2, t_Wo, qWt, kvWt, midWt, WoT, vT,
      resF, a_ln_w, t_ln_w, lnA, lnT);
  k_res_gemm<<<dim3(Bc * Rc / 32, 6), dim3(256), 0, stream>>>(
      lnA, lnT, resF, a_Wg, a_bg, a_Wb, t_Wg, t_bg, t_Wb, sg_W, sg_b, t_Wc, t_bc,
      Ag, Ab, Tg, Tb, Sg, Tc);
  k_adaln16<<<dim3(Bc * Nc / 4), dim3(256), 0, stream>>>(atomF, idx, Ag, Ab,
                                                         (unsigned*)act16);
  k_gemm_qkv<<<dim3(Bc * Nc / 64, 3), dim3(256), 0, stream>>>(act16, qWt, kvWt, q_b,
                                                              q16, k16, vT);
  k_battn<<<dim3(Bc * NWc * 2), dim3(256), 0, stream>>>(
      apF, bij_ln_w, bij_ln_b, bij_W, q16, k16, vT, idx, Sg, pmask, atomF, atomw16);
  k_adaln16b<<<dim3(Bc * Nc / 4), dim3(256), 0, stream>>>((unsigned*)atomw16, idx, Tg, Tb,
                                                          (unsigned*)act16);
  k_gemm_trans<<<dim3(Bc * Nc / 32), dim3(256), 0, stream>>>(
      act16, midWt, WoT, atomw16, idx, Tc, pmask, (float*)d_out);
}

// Round 16
// 206.237 us; speedup vs baseline: 1.5253x; 1.0021x over previous
//
#include <hip/hip_runtime.h>
#include <hip/hip_bf16.h>
#include <string.h>

namespace {

constexpr int Bc  = 2;
constexpr int Nc  = 16384;
constexpr int Rc  = 2048;
constexpr int CAc = 128;
constexpr int CSc = 256;
constexpr int CPc = 16;
constexpr int Hc  = 4;
constexpr int WQc = 32;
constexpr int WKc = 128;
constexpr int NWc = 512;
constexpr float EPSf     = 1e-5f;
constexpr float NEG_INF  = -1e8f;
constexpr float QK_SCALE = 0.17677669529663687f;  // 1/sqrt(32)

constexpr int VT_STRIDE = 16512;          // 64 pad + 16384 + 64 pad
constexpr int VT_BATCH  = 128 * VT_STRIDE;

typedef short bf16x8 __attribute__((ext_vector_type(8)));
typedef float f32x4 __attribute__((ext_vector_type(4)));
typedef unsigned int u32x4 __attribute__((ext_vector_type(4)));

__device__ __forceinline__ float wsum(float v) {
#pragma unroll
  for (int m = 1; m < 64; m <<= 1) v += __shfl_xor(v, m, 64);
  return v;
}
__device__ __forceinline__ float sigm(float x) { return 1.0f / (1.0f + __expf(-x)); }
__device__ __forceinline__ float f4c(const float4& v, int i) {
  return i == 0 ? v.x : i == 1 ? v.y : i == 2 ? v.z : v.w;
}
__device__ __forceinline__ unsigned short bfx(float v) {
  __hip_bfloat16 h = __float2bfloat16(v);
  unsigned short u;
  memcpy(&u, &h, 2);
  return u;
}
__device__ __forceinline__ unsigned pk2(float a, float b) {
  return (unsigned)bfx(a) | ((unsigned)bfx(b) << 16);
}
__device__ __forceinline__ float ubf(unsigned us) {
  unsigned v = us << 16;
  float f;
  memcpy(&f, &v, 4);
  return f;
}
__device__ __forceinline__ bf16x8 ldfrag(const ushort* p) {
  return __builtin_bit_cast(bf16x8, *(const u32x4*)p);
}

// ---------------- K0+K1a merged: weight pack (+vT pads) | res LN -----------
__global__ void k_pack_resln(const float* __restrict__ q_W, const float* __restrict__ kv_W,
                             const float* __restrict__ t_W1, const float* __restrict__ t_W2,
                             const float* __restrict__ t_Wo,
                             ushort* __restrict__ qWt, ushort* __restrict__ kvWt,
                             ushort* __restrict__ midWt, ushort* __restrict__ WoT,
                             ushort* __restrict__ vT,
                             const float* __restrict__ res, const float* __restrict__ a_ln_w,
                             const float* __restrict__ t_ln_w, float* __restrict__ lnA,
                             float* __restrict__ lnT) {
  if (blockIdx.x < 704) {
    const int i = blockIdx.x * 256 + threadIdx.x;
    if (i < 16384) {
      const int n = i >> 7, k = i & 127;
      qWt[i] = bfx(q_W[k * 128 + n]);
    } else if (i < 49152) {
      const int i2 = i - 16384;
      const int n = i2 >> 7, k = i2 & 127;
      kvWt[i2] = bfx(kv_W[k * 256 + n]);
    } else if (i < 114688) {
      const int i3 = i - 49152;
      const int n = i3 >> 7, k = i3 & 127;
      midWt[i3] = bfx(n < 256 ? t_W1[k * 256 + n] : t_W2[k * 256 + (n - 256)]);
    } else if (i < 147456) {
      const int i4 = i - 114688;
      const int n = i4 >> 8, k = i4 & 255;
      WoT[i4] = bfx(t_Wo[k * 128 + n]);
    } else if (i < 180224) {
      const int j = i - 147456;           // vT edge pads -> 0
      const int b = j >> 14, rem = j & 16383;
      const int d = rem >> 7, p = rem & 127;
      const int col = (p < 64) ? p : (16384 + p);
      vT[(size_t)b * VT_BATCH + (size_t)d * VT_STRIDE + col] = 0;
    }
  } else {
    const int wid = threadIdx.x >> 6, lane = threadIdx.x & 63;
    const int row = (blockIdx.x - 704) * 4 + wid;  // B*R rows
    const float* r = res + (size_t)row * CSc;
    float x[4], s = 0.f, sq = 0.f;
#pragma unroll
    for (int i = 0; i < 4; ++i) { x[i] = r[lane + 64 * i]; s += x[i]; sq += x[i] * x[i]; }
    s = wsum(s); sq = wsum(sq);
    const float mn = s * (1.0f / CSc);
    const float var = sq * (1.0f / CSc) - mn * mn;
    const float rs = rsqrtf(var + EPSf);
#pragma unroll
    for (int i = 0; i < 4; ++i) {
      const int c = lane + 64 * i;
      const float y = (x[i] - mn) * rs;
      lnA[(size_t)row * CSc + c] = y * a_ln_w[c];
      lnT[(size_t)row * CSc + c] = y * t_ln_w[c];
    }
  }
}

// ---------------- K1b: 6 res GEMMs (K=256 -> 128 cols), gates sigmoid'd ----
__global__ void k_res_gemm(const float* __restrict__ lnA, const float* __restrict__ lnT,
                           const float* __restrict__ res,
                           const float* __restrict__ a_Wg, const float* __restrict__ a_bg,
                           const float* __restrict__ a_Wb,
                           const float* __restrict__ t_Wg, const float* __restrict__ t_bg,
                           const float* __restrict__ t_Wb,
                           const float* __restrict__ sg_W, const float* __restrict__ sg_b,
                           const float* __restrict__ t_Wc, const float* __restrict__ t_bc,
                           float* __restrict__ Ag, float* __restrict__ Ab,
                           float* __restrict__ Tg, float* __restrict__ Tb,
                           float* __restrict__ Sg, float* __restrict__ Tc) {
  __shared__ float tile[32 * CSc];
  const int m = blockIdx.y;
  const float* in = (m < 2) ? lnA : (m < 4) ? lnT : res;
  const float* W  = (m == 0) ? a_Wg : (m == 1) ? a_Wb : (m == 2) ? t_Wg
                  : (m == 3) ? t_Wb : (m == 4) ? sg_W : t_Wc;
  const float* bias = (m == 0) ? a_bg : (m == 2) ? t_bg : (m == 4) ? sg_b
                    : (m == 5) ? t_bc : nullptr;
  const bool sig = (m == 0) || (m == 2) || (m == 4) || (m == 5);
  float* out = (m == 0) ? Ag : (m == 1) ? Ab : (m == 2) ? Tg
             : (m == 3) ? Tb : (m == 4) ? Sg : Tc;
  const int row0 = blockIdx.x * 32;
  const float4* src = (const float4*)(in + (size_t)row0 * CSc);
  float4* dst = (float4*)tile;
#pragma unroll
  for (int k = 0; k < 8; ++k) dst[threadIdx.x + 256 * k] = src[threadIdx.x + 256 * k];
  __syncthreads();
  const int c0 = (threadIdx.x & 31) * 4;
  const int r0 = (threadIdx.x >> 5) * 4;
  float acc[4][4] = {};
  for (int j = 0; j < CSc; j += 4) {
    float4 a[4];
#pragma unroll
    for (int r = 0; r < 4; ++r) a[r] = *(const float4*)&tile[(r0 + r) * CSc + j];
#pragma unroll
    for (int jj = 0; jj < 4; ++jj) {
      const float4 w = *(const float4*)&W[(size_t)(j + jj) * CAc + c0];
#pragma unroll
      for (int r = 0; r < 4; ++r) {
        const float av = f4c(a[r], jj);
        acc[r][0] += av * w.x; acc[r][1] += av * w.y;
        acc[r][2] += av * w.z; acc[r][3] += av * w.w;
      }
    }
  }
  float4 bv = make_float4(0.f, 0.f, 0.f, 0.f);
  if (bias) bv = *(const float4*)&bias[c0];
#pragma unroll
  for (int r = 0; r < 4; ++r) {
    float4 o;
    o.x = acc[r][0] + bv.x; o.y = acc[r][1] + bv.y;
    o.z = acc[r][2] + bv.z; o.w = acc[r][3] + bv.w;
    if (sig) { o.x = sigm(o.x); o.y = sigm(o.y); o.z = sigm(o.z); o.w = sigm(o.w); }
    *(float4*)&out[(size_t)(row0 + r0 + r) * CAc + c0] = o;
  }
}

// ---------------- K2: adaLN over atoms (f32 in) -> bf16 out ----------------
__global__ void k_adaln16(const float* __restrict__ in, const int* __restrict__ idxG,
                          const float* __restrict__ G, const float* __restrict__ Bb,
                          unsigned* __restrict__ out32) {
  const int wid = threadIdx.x >> 6, lane = threadIdx.x & 63;
  const int row = blockIdx.x * 4 + wid;  // B*N rows
  const int b = row >> 14;
  const float* r = in + (size_t)row * CAc;
  const float2 xp = *(const float2*)&r[2 * lane];
  const float s = wsum(xp.x + xp.y);
  const float sq = wsum(xp.x * xp.x + xp.y * xp.y);
  const float mn = s * (1.0f / CAc);
  const float var = sq * (1.0f / CAc) - mn * mn;
  const float rs = rsqrtf(var + EPSf);
  const int base = (b * Rc + idxG[row]) * CAc;
  const float2 g2 = *(const float2*)&G[base + 2 * lane];
  const float2 b2 = *(const float2*)&Bb[base + 2 * lane];
  const float y0 = (xp.x - mn) * rs * g2.x + b2.x;
  const float y1 = (xp.y - mn) * rs * g2.y + b2.y;
  out32[(size_t)row * 64 + lane] = pk2(y0, y1);
}

// ---------------- K5: adaLN over atoms (bf16 in) -> bf16 out ---------------
__global__ void k_adaln16b(const unsigned* __restrict__ in32, const int* __restrict__ idxG,
                           const float* __restrict__ G, const float* __restrict__ Bb,
                           unsigned* __restrict__ out32) {
  const int wid = threadIdx.x >> 6, lane = threadIdx.x & 63;
  const int row = blockIdx.x * 4 + wid;  // B*N rows
  const int b = row >> 14;
  const unsigned pkx = in32[(size_t)row * 64 + lane];
  const float x0 = ubf(pkx & 0xffff), x1 = ubf(pkx >> 16);
  const float s = wsum(x0 + x1);
  const float sq = wsum(x0 * x0 + x1 * x1);
  const float mn = s * (1.0f / CAc);
  const float var = sq * (1.0f / CAc) - mn * mn;
  const float rs = rsqrtf(var + EPSf);
  const int base = (b * Rc + idxG[row]) * CAc;
  const float2 g2 = *(const float2*)&G[base + 2 * lane];
  const float2 b2 = *(const float2*)&Bb[base + 2 * lane];
  const float y0 = (x0 - mn) * rs * g2.x + b2.x;
  const float y1 = (x1 - mn) * rs * g2.y + b2.y;
  out32[(size_t)row * 64 + lane] = pk2(y0, y1);
}

// ---------------- K3: qkv GEMM via MFMA (M=32768, K=128) -------------------
__global__ __launch_bounds__(256) void k_gemm_qkv(
    const ushort* __restrict__ act16, const ushort* __restrict__ qWt,
    const ushort* __restrict__ kvWt, const float* __restrict__ q_b,
    ushort* __restrict__ q16, ushort* __restrict__ k16, ushort* __restrict__ vT) {
  __shared__ ushort vtile[128][72];  // 18.4 KB; stride 144B keeps b128 aligned
  const int ny = blockIdx.y;
  const int wid = threadIdx.x >> 6, lane = threadIdx.x & 63;
  const int c = lane & 15, s = lane >> 4;
  const int wm = wid & 1, wn = wid >> 1;
  const int base = blockIdx.x * 64;
  const int m0 = base + wm * 32;
  const int nb = wn * 64;
  const ushort* Wt = (ny == 0) ? qWt : kvWt + (ny == 2 ? 128 * 128 : 0);
  f32x4 acc[4][2];
#pragma unroll
  for (int nt = 0; nt < 4; ++nt)
#pragma unroll
    for (int mt = 0; mt < 2; ++mt) { acc[nt][mt][0]=0.f; acc[nt][mt][1]=0.f; acc[nt][mt][2]=0.f; acc[nt][mt][3]=0.f; }
#pragma unroll
  for (int kk = 0; kk < 4; ++kk) {
    const int k0 = kk * 32 + 8 * s;
    bf16x8 bA[2];
#pragma unroll
    for (int mt = 0; mt < 2; ++mt)
      bA[mt] = ldfrag(&act16[(size_t)(m0 + mt * 16 + c) * 128 + k0]);
#pragma unroll
    for (int nt = 0; nt < 4; ++nt) {
      const bf16x8 aW = ldfrag(&Wt[(size_t)(nb + nt * 16 + c) * 128 + k0]);
#pragma unroll
      for (int mt = 0; mt < 2; ++mt)
        acc[nt][mt] = __builtin_amdgcn_mfma_f32_16x16x32_bf16(aW, bA[mt], acc[nt][mt], 0, 0, 0);
    }
  }
#pragma unroll
  for (int nt = 0; nt < 4; ++nt) {
    const int colb = nb + nt * 16 + 4 * s;
    float4 qb4 = make_float4(0.f, 0.f, 0.f, 0.f);
    if (ny == 0) qb4 = *(const float4*)&q_b[colb];
#pragma unroll
    for (int mt = 0; mt < 2; ++mt) {
      const int m = m0 + mt * 16 + c;
      const f32x4 a = acc[nt][mt];
      if (ny == 0) {
        ushort4 u4;
        u4.x = bfx((a[0] + qb4.x) * QK_SCALE); u4.y = bfx((a[1] + qb4.y) * QK_SCALE);
        u4.z = bfx((a[2] + qb4.z) * QK_SCALE); u4.w = bfx((a[3] + qb4.w) * QK_SCALE);
        *(ushort4*)&q16[(size_t)m * 128 + colb] = u4;
      } else if (ny == 1) {
        ushort4 u4;
        u4.x = bfx(a[0]); u4.y = bfx(a[1]); u4.z = bfx(a[2]); u4.w = bfx(a[3]);
        *(ushort4*)&k16[(size_t)m * 128 + colb] = u4;
      } else {
        const int rowl = wm * 32 + mt * 16 + c;
#pragma unroll
        for (int r = 0; r < 4; ++r)
          vtile[colb + r][rowl] = bfx(a[r]);
      }
    }
  }
  if (ny == 2) {
    __syncthreads();
    const int bb2 = base >> 14, nn0 = base & 16383;
    const int t = threadIdx.x;
    const int d = t >> 1, half = t & 1;
    ushort* dst = vT + (size_t)bb2 * VT_BATCH + (size_t)d * VT_STRIDE + 64 + nn0 + half * 32;
    const ushort* srcl = &vtile[d][half * 32];
#pragma unroll
    for (int u = 0; u < 4; ++u)
      *(uint4*)(dst + u * 8) = *(const uint4*)(srcl + u * 8);
  }
}

// ---------------- K4: FUSED bias + attention (atomw out = bf16) ------------
// Phase A unroll raised 2 -> 4: phase B already pins VGPR (~100+), so wider
// unroll adds memory-level parallelism to the 268 MB stream for free.
__global__ __launch_bounds__(256) void k_battn(
    const float* __restrict__ ap, const float* __restrict__ bw,
    const float* __restrict__ bb, const float* __restrict__ bW,
    const ushort* __restrict__ qG, const ushort* __restrict__ kG,
    const ushort* __restrict__ vT,
    const int* __restrict__ idxG, const float* __restrict__ SgG,
    const float* __restrict__ pmask, const float* __restrict__ atomF,
    ushort* __restrict__ atomO16) {
  __shared__ ushort biasL[8192];       // 16 KB: [h][mt][col][r]
  __shared__ float w2s[64], W2sh[4], Cbh[4];
  const int tid = threadIdx.x;
  const int bwid = blockIdx.x >> 1;
  const int half = blockIdx.x & 1;
  const int b = bwid >> 9, w = bwid & 511;
  const size_t bN = (size_t)b * Nc;

  // ---- Phase A: folded-LN bias ----
  if (tid < 64) w2s[tid] = bw[tid >> 2] * bW[tid];
  __syncthreads();
  if (tid < 4) {
    float a = 0.f, b2 = 0.f;
#pragma unroll
    for (int cp = 0; cp < 16; ++cp) { a += w2s[cp * 4 + tid]; b2 += bb[cp] * bW[cp * 4 + tid]; }
    W2sh[tid] = a; Cbh[tid] = b2;
  }
  __syncthreads();
  const float* apw = ap + (size_t)bwid * (WQc * WKc * CPc) + (size_t)half * (16 * 128 * CPc);
#pragma unroll 4
  for (int u = 0; u < 8; ++u) {
    const int p = tid + 256 * u;         // 2048 pairs (16 q x 128 k)
    const int qql = p >> 7, kk = p & 127;
    const float* src = apw + (size_t)p * CPc;
    float sum = 0.f, sq = 0.f, d0 = 0.f, d1 = 0.f, d2 = 0.f, d3 = 0.f;
#pragma unroll
    for (int t = 0; t < 4; ++t) {
      const float4 v4 = *(const float4*)&src[t * 4];
#pragma unroll
      for (int e = 0; e < 4; ++e) {
        const float x = f4c(v4, e);
        const float4 wv = *(const float4*)&w2s[(4 * t + e) * 4];
        sum += x; sq += x * x;
        d0 += x * wv.x; d1 += x * wv.y; d2 += x * wv.z; d3 += x * wv.w;
      }
    }
    const float mn = sum * 0.0625f;
    const float var = sq * 0.0625f - mn * mn;
    const float rs = rsqrtf(var + EPSf);
    const int gk = w * 32 - 48 + kk;
    const float maskt = (gk >= 0 && gk < Nc) ? 0.f : NEG_INF;
    const int mt = kk >> 4, s_ = (kk >> 2) & 3, r_ = kk & 3;
    const int col = s_ * 16 + (qql ^ ((mt & 3) << 2) ^ s_);
    const int base = mt * 256 + col * 4 + r_;
    biasL[base]        = bfx(rs * (d0 - mn * W2sh[0]) + Cbh[0] + maskt);
    biasL[base + 2048] = bfx(rs * (d1 - mn * W2sh[1]) + Cbh[1] + maskt);
    biasL[base + 4096] = bfx(rs * (d2 - mn * W2sh[2]) + Cbh[2] + maskt);
    biasL[base + 6144] = bfx(rs * (d3 - mn * W2sh[3]) + Cbh[3] + maskt);
  }
  __syncthreads();

  // ---- Phase B: per-wave attention (wave == head) ----
  const int h = tid >> 6;
  const int lane = tid & 63;
  const int c = lane & 15, s = lane >> 4;

  f32x4 acc[8];
  {
    const ushort* bh = &biasL[h * 2048];
#pragma unroll
    for (int mt = 0; mt < 8; ++mt) {
      const int col = s * 16 + (c ^ ((mt & 3) << 2) ^ s);
      const uint2 pk = *(const uint2*)&bh[mt * 256 + col * 4];
      acc[mt][0] = ubf(pk.x & 0xffff);
      acc[mt][1] = ubf(pk.x >> 16);
      acc[mt][2] = ubf(pk.y & 0xffff);
      acc[mt][3] = ubf(pk.y >> 16);
    }
  }

  const int qq = w * 32 + half * 16 + c;
  const bf16x8 bfragQ = ldfrag(&qG[(bN + qq) * CAc + h * 32 + 8 * s]);
#pragma unroll
  for (int mt = 0; mt < 8; ++mt) {
    int gk = w * 32 - 48 + mt * 16 + c;
    gk = min(max(gk, 0), Nc - 1);
    const bf16x8 afragK = ldfrag(&kG[(bN + gk) * CAc + h * 32 + 8 * s]);
    acc[mt] = __builtin_amdgcn_mfma_f32_16x16x32_bf16(afragK, bfragQ, acc[mt], 0, 0, 0);
  }

  int ppk[8][2];
  {
    float mx = -3e38f;
#pragma unroll
    for (int mt = 0; mt < 8; ++mt)
#pragma unroll
      for (int r = 0; r < 4; ++r) mx = fmaxf(mx, acc[mt][r]);
    mx = fmaxf(mx, __shfl_xor(mx, 16, 64));
    mx = fmaxf(mx, __shfl_xor(mx, 32, 64));
    float sm = 0.f;
#pragma unroll
    for (int mt = 0; mt < 8; ++mt)
#pragma unroll
      for (int r = 0; r < 4; ++r) {
        const float e = __expf(acc[mt][r] - mx);
        acc[mt][r] = e;
        sm += e;
      }
    sm += __shfl_xor(sm, 16, 64);
    sm += __shfl_xor(sm, 32, 64);
    const float inv = 1.0f / sm;
#pragma unroll
    for (int mt = 0; mt < 8; ++mt) {
      ppk[mt][0] = (int)pk2(acc[mt][0] * inv, acc[mt][1] * inv);
      ppk[mt][1] = (int)pk2(acc[mt][2] * inv, acc[mt][3] * inv);
    }
  }

  f32x4 opv[2];
  opv[0][0]=0.f; opv[0][1]=0.f; opv[0][2]=0.f; opv[0][3]=0.f;
  opv[1][0]=0.f; opv[1][1]=0.f; opv[1][2]=0.f; opv[1][3]=0.f;
  const int idxA = 4 * ((((2 * s) & 3) << 4) | c);
  const int idxB = 4 * ((((2 * s + 1) & 3) << 4) | c);
  const ushort* vTb = vT + (size_t)b * VT_BATCH;
#pragma unroll
  for (int ks = 0; ks < 4; ++ks) {
    const int vbase = 64 + w * 32 - 48 + ks * 32 + 8 * s;
    bf16x8 bV[2];
#pragma unroll
    for (int ntd = 0; ntd < 2; ++ntd) {
      const int d = h * 32 + ntd * 16 + c;
      bV[ntd] = ldfrag(&vTb[(size_t)d * VT_STRIDE + vbase]);
    }
    int atv[4];
    {
      const int a0 = __builtin_amdgcn_ds_bpermute(idxA, ppk[2 * ks][0]);
      const int b0 = __builtin_amdgcn_ds_bpermute(idxA, ppk[2 * ks + 1][0]);
      atv[0] = (s < 2) ? a0 : b0;
      const int a1 = __builtin_amdgcn_ds_bpermute(idxA, ppk[2 * ks][1]);
      const int b1 = __builtin_amdgcn_ds_bpermute(idxA, ppk[2 * ks + 1][1]);
      atv[1] = (s < 2) ? a1 : b1;
      const int a2 = __builtin_amdgcn_ds_bpermute(idxB, ppk[2 * ks][0]);
      const int b2 = __builtin_amdgcn_ds_bpermute(idxB, ppk[2 * ks + 1][0]);
      atv[2] = (s < 2) ? a2 : b2;
      const int a3 = __builtin_amdgcn_ds_bpermute(idxB, ppk[2 * ks][1]);
      const int b3 = __builtin_amdgcn_ds_bpermute(idxB, ppk[2 * ks + 1][1]);
      atv[3] = (s < 2) ? a3 : b3;
    }
    const bf16x8 afragP = __builtin_bit_cast(bf16x8, *(const u32x4*)atv);
#pragma unroll
    for (int ntd = 0; ntd < 2; ++ntd)
      opv[ntd] = __builtin_amdgcn_mfma_f32_16x16x32_bf16(afragP, bV[ntd], opv[ntd], 0, 0, 0);
  }

#pragma unroll
  for (int r = 0; r < 4; ++r) {
    const int qr = w * 32 + half * 16 + 4 * s + r;
    const size_t rowg = bN + qr;
    const int residx = idxG[rowg];
    const float pm = pmask[rowg];
    const size_t gbase = ((size_t)b * Rc + residx) * CAc;
#pragma unroll
    for (int ntd = 0; ntd < 2; ++ntd) {
      const int d = h * 32 + ntd * 16 + c;
      const float g = SgG[gbase + d];
      const float af = atomF[rowg * CAc + d];
      atomO16[rowg * CAc + d] = bfx(af + opv[ntd][r] * g * pm);
    }
  }
}

// ---------------- K6+K7 FUSED: transition (mid in LDS) + out + residual ----
__global__ __launch_bounds__(256) void k_gemm_trans(
    const ushort* __restrict__ act16, const ushort* __restrict__ midWt,
    const ushort* __restrict__ WoT, const ushort* __restrict__ atomw16,
    const int* __restrict__ idxG, const float* __restrict__ TcG,
    const float* __restrict__ pmask, float* __restrict__ outG) {
  __shared__ ushort smid[32 * 264];    // 16.9 KB
  const int wid = threadIdx.x >> 6, lane = threadIdx.x & 63;
  const int c = lane & 15, s = lane >> 4;
  const int m0 = blockIdx.x * 32;

  // ---- Phase 1: mid GEMM; wave wid covers mid-cols wid*64..+63 ----
  {
    const int nb = wid * 64;
    f32x4 acc1[4][2], acc2[4][2];
#pragma unroll
    for (int nt = 0; nt < 4; ++nt)
#pragma unroll
      for (int mt = 0; mt < 2; ++mt) {
        acc1[nt][mt][0]=0.f; acc1[nt][mt][1]=0.f; acc1[nt][mt][2]=0.f; acc1[nt][mt][3]=0.f;
        acc2[nt][mt][0]=0.f; acc2[nt][mt][1]=0.f; acc2[nt][mt][2]=0.f; acc2[nt][mt][3]=0.f;
      }
#pragma unroll
    for (int kk = 0; kk < 4; ++kk) {
      const int k0 = kk * 32 + 8 * s;
      bf16x8 bA[2];
#pragma unroll
      for (int mt = 0; mt < 2; ++mt)
        bA[mt] = ldfrag(&act16[(size_t)(m0 + mt * 16 + c) * 128 + k0]);
#pragma unroll
      for (int nt = 0; nt < 4; ++nt) {
        const bf16x8 aW1 = ldfrag(&midWt[(size_t)(nb + nt * 16 + c) * 128 + k0]);
        const bf16x8 aW2 = ldfrag(&midWt[(size_t)(256 + nb + nt * 16 + c) * 128 + k0]);
#pragma unroll
        for (int mt = 0; mt < 2; ++mt) {
          acc1[nt][mt] = __builtin_amdgcn_mfma_f32_16x16x32_bf16(aW1, bA[mt], acc1[nt][mt], 0, 0, 0);
          acc2[nt][mt] = __builtin_amdgcn_mfma_f32_16x16x32_bf16(aW2, bA[mt], acc2[nt][mt], 0, 0, 0);
        }
      }
    }
#pragma unroll
    for (int nt = 0; nt < 4; ++nt) {
      const int colb = nb + nt * 16 + 4 * s;
#pragma unroll
      for (int mt = 0; mt < 2; ++mt) {
        const int ml = mt * 16 + c;
        ushort4 u4;
#pragma unroll
        for (int r = 0; r < 4; ++r) {
          const float a1 = acc1[nt][mt][r];
          const float v = a1 * sigm(a1) * acc2[nt][mt][r];
          ((unsigned short*)&u4)[r] = bfx(v);
        }
        *(ushort4*)&smid[ml * 264 + colb] = u4;
      }
    }
  }
  __syncthreads();

  // ---- Phase 2: out GEMM (K=256 from LDS); wave wid covers out-cols wid*32 ----
  {
    const int nbo = wid * 32;
    f32x4 acc[2][2];
#pragma unroll
    for (int nt = 0; nt < 2; ++nt)
#pragma unroll
      for (int mt = 0; mt < 2; ++mt) { acc[nt][mt][0]=0.f; acc[nt][mt][1]=0.f; acc[nt][mt][2]=0.f; acc[nt][mt][3]=0.f; }
#pragma unroll
    for (int kk = 0; kk < 8; ++kk) {
      const int k0 = kk * 32 + 8 * s;
      bf16x8 bA[2];
#pragma unroll
      for (int mt = 0; mt < 2; ++mt)
        bA[mt] = ldfrag(&smid[(mt * 16 + c) * 264 + k0]);
#pragma unroll
      for (int nt = 0; nt < 2; ++nt) {
        const bf16x8 aW = ldfrag(&WoT[(size_t)(nbo + nt * 16 + c) * 256 + k0]);
#pragma unroll
        for (int mt = 0; mt < 2; ++mt)
          acc[nt][mt] = __builtin_amdgcn_mfma_f32_16x16x32_bf16(aW, bA[mt], acc[nt][mt], 0, 0, 0);
      }
    }
#pragma unroll
    for (int mt = 0; mt < 2; ++mt) {
      const int m = m0 + mt * 16 + c;
      const int b = m >> 14;
      const int idx = idxG[m];
      const float pm = pmask[m];
      const size_t tcb = ((size_t)(b * Rc) + idx) * CAc;
#pragma unroll
      for (int nt = 0; nt < 2; ++nt) {
        const int colb = nbo + nt * 16 + 4 * s;
        const float4 tc = *(const float4*)&TcG[tcb + colb];
        const ushort4 at4 = *(const ushort4*)&atomw16[(size_t)m * CAc + colb];
        float4 o;
        o.x = ubf(at4.x) + tc.x * acc[nt][mt][0] * pm;
        o.y = ubf(at4.y) + tc.y * acc[nt][mt][1] * pm;
        o.z = ubf(at4.z) + tc.z * acc[nt][mt][2] * pm;
        o.w = ubf(at4.w) + tc.w * acc[nt][mt][3] * pm;
        *(float4*)&outG[(size_t)m * CAc + colb] = o;
      }
    }
  }
}

}  // namespace

extern "C" void kernel_launch(void* const* d_in, const int* in_sizes, int n_in,
                              void* d_out, int out_size, void* d_ws, size_t ws_size,
                              hipStream_t stream) {
  (void)in_sizes; (void)n_in; (void)out_size; (void)ws_size;
  const float* atomF   = (const float*)d_in[0];
  const float* resF    = (const float*)d_in[1];
  const float* apF     = (const float*)d_in[2];
  const int*   idx     = (const int*)d_in[3];
  const float* pmask   = (const float*)d_in[4];
  const float* a_ln_w  = (const float*)d_in[6];
  const float* a_Wg    = (const float*)d_in[7];
  const float* a_bg    = (const float*)d_in[8];
  const float* a_Wb    = (const float*)d_in[9];
  const float* q_W     = (const float*)d_in[10];
  const float* q_b     = (const float*)d_in[11];
  const float* kv_W    = (const float*)d_in[12];
  const float* bij_ln_w= (const float*)d_in[13];
  const float* bij_ln_b= (const float*)d_in[14];
  const float* bij_W   = (const float*)d_in[15];
  const float* sg_W    = (const float*)d_in[16];
  const float* sg_b    = (const float*)d_in[17];
  const float* t_ln_w  = (const float*)d_in[18];
  const float* t_Wg    = (const float*)d_in[19];
  const float* t_bg    = (const float*)d_in[20];
  const float* t_Wb    = (const float*)d_in[21];
  const float* t_W1    = (const float*)d_in[22];
  const float* t_W2    = (const float*)d_in[23];
  const float* t_Wc    = (const float*)d_in[24];
  const float* t_bc    = (const float*)d_in[25];
  const float* t_Wo    = (const float*)d_in[26];

  float* ws = (float*)d_ws;
  float* Ag    = ws;                          // 6 x 524288
  float* Ab    = Ag + 524288;
  float* Tg    = Ab + 524288;
  float* Tb    = Tg + 524288;
  float* Sg    = Tb + 524288;
  float* Tc    = Sg + 524288;
  float* lnA   = Tc + 524288;                 // 1048576
  float* lnT   = lnA + 1048576;               // 1048576
  ushort* act16  = (ushort*)(lnT + 1048576);  // 4194304 ushorts (s, then t)
  ushort* q16    = act16 + 4194304;           // 4194304 ushorts
  ushort* k16    = q16 + 4194304;             // 4194304 ushorts
  ushort* atomw16= k16 + 4194304;             // 4194304 ushorts (bf16 atom)
  ushort* qWt    = atomw16 + 4194304;         // 16384
  ushort* kvWt   = qWt + 16384;               // 32768
  ushort* midWt  = kvWt + 32768;              // 65536
  ushort* WoT    = midWt + 65536;             // 32768
  ushort* vT     = WoT + 32768;               // 2 x 128 x 16512 = 4227072 ushorts

  k_pack_resln<<<dim3(1728), dim3(256), 0, stream>>>(
      q_W, kv_W, t_W1, t_W2, t_Wo, qWt, kvWt, midWt, WoT, vT,
      resF, a_ln_w, t_ln_w, lnA, lnT);
  k_res_gemm<<<dim3(Bc * Rc / 32, 6), dim3(256), 0, stream>>>(
      lnA, lnT, resF, a_Wg, a_bg, a_Wb, t_Wg, t_bg, t_Wb, sg_W, sg_b, t_Wc, t_bc,
      Ag, Ab, Tg, Tb, Sg, Tc);
  k_adaln16<<<dim3(Bc * Nc / 4), dim3(256), 0, stream>>>(atomF, idx, Ag, Ab,
                                                         (unsigned*)act16);
  k_gemm_qkv<<<dim3(Bc * Nc / 64, 3), dim3(256), 0, stream>>>(act16, qWt, kvWt, q_b,
                                                              q16, k16, vT);
  k_battn<<<dim3(Bc * NWc * 2), dim3(256), 0, stream>>>(
      apF, bij_ln_w, bij_ln_b, bij_W, q16, k16, vT, idx, Sg, pmask, atomF, atomw16);
  k_adaln16b<<<dim3(Bc * Nc / 4), dim3(256), 0, stream>>>((unsigned*)atomw16, idx, Tg, Tb,
                                                          (unsigned*)act16);
  k_gemm_trans<<<dim3(Bc * Nc / 32), dim3(256), 0, stream>>>(
      act16, midWt, WoT, atomw16, idx, Tc, pmask, (float*)d_out);
}